// Round 8
// baseline (17996.918 us; speedup 1.0000x reference)
//
#include <hip/hip_runtime.h>
#include <math.h>

#define FH 384
#define KF 193
#define KP 768          // stacked real K' = 2*FH
#define SP 208          // padded complex cols per plane (mult of 16)
#define SPW 147456      // spatial plane elements (384*384)

typedef __attribute__((ext_vector_type(8))) short short8;
typedef __attribute__((ext_vector_type(4))) float f32x4;
typedef unsigned short u16;
typedef unsigned int u32;

static __device__ __forceinline__ float softt(float v, float b) {
    return copysignf(fmaxf(fabsf(v) - b, 0.f), v);
}
static __device__ __forceinline__ u16 bf16_rn(float v) {
    u32 u = __float_as_uint(v);
    return (u16)((u + 0x7FFFu + ((u >> 16) & 1u)) >> 16);
}
static __device__ __forceinline__ float bf2f(u16 h) {
    return __uint_as_float(((u32)h) << 16);
}
static __device__ __forceinline__ float2 ldc(const u32* H, const u32* L, size_t i) {
    u32 h = H[i], l = L[i];
    float2 r;
    r.x = __uint_as_float((h & 0xffffu) << 16) + __uint_as_float((l & 0xffffu) << 16);
    r.y = __uint_as_float(h & 0xffff0000u) + __uint_as_float(l & 0xffff0000u);
    return r;
}
static __device__ __forceinline__ void stc(u32* H, u32* L, size_t i, float2 v) {
    u16 hr = bf16_rn(v.x), hi = bf16_rn(v.y);
    u16 lr = bf16_rn(v.x - bf2f(hr)), li = bf16_rn(v.y - bf2f(hi));
    H[i] = (u32)hr | ((u32)hi << 16);
    L[i] = (u32)lr | ((u32)li << 16);
}

// ---------------- tables ----------------
__global__ void init_estack(u16* __restrict__ H, u16* __restrict__ L, int inv)
{
    int idx = blockIdx.x * 256 + threadIdx.x;
    if (idx >= KP * KP) return;
    int gm = idx / KP, kp = idx % KP;
    int m = gm >> 1, comp = gm & 1;
    int t = kp >> 1, ri = kp & 1;
    int mm = (m * t) % FH;
    float th = (float)(6.283185307179586 / FH) * (float)mm;
    float c = cosf(th), s = sinf(th);
    float er, ei;
    if (inv) { er = c * (1.f/FH); ei = s * (1.f/FH); }
    else     { er = c;            ei = -s; }
    float v;
    if (comp == 0) v = (ri == 0) ? er : -ei;
    else           v = (ri == 0) ? ei :  er;
    u16 h = bf16_rn(v);
    H[idx] = h;
    L[idx] = bf16_rn(v - bf2f(h));
}
__global__ void init_tt(u16* __restrict__ H, u16* __restrict__ L)
{
    int idx = blockIdx.x * 256 + threadIdx.x;
    if (idx >= 448 * FH) return;
    int n = idx / FH, w = idx % FH;
    float v = 0.f;
    if (n < 2*KF) {
        int kf = n >> 1, ri = n & 1;
        int m = (w * kf) % FH;
        float th = (float)(6.283185307179586 / FH) * (float)m;
        v = ri ? -sinf(th) : cosf(th);
    }
    u16 h = bf16_rn(v);
    H[idx] = h;
    L[idx] = bf16_rn(v - bf2f(h));
}
__global__ void init_ut(u16* __restrict__ H, u16* __restrict__ L)
{
    int idx = blockIdx.x * 256 + threadIdx.x;
    if (idx >= FH * 416) return;
    int x = idx / 416, kp = idx % 416;
    float v = 0.f;
    if (kp < 2*KF) {
        int k = kp >> 1, ri = kp & 1;
        float ck = (k == 0 || k == FH/2) ? (1.f/FH) : (2.f/FH);
        int m = (k * x) % FH;
        float th = (float)(6.283185307179586 / FH) * (float)m;
        v = ri ? -ck*sinf(th) : ck*cosf(th);
    }
    u16 h = bf16_rn(v);
    H[idx] = h;
    L[idx] = bf16_rn(v - bf2f(h));
}

__global__ void w0c_kernel(const float* __restrict__ w0, float* __restrict__ w0c) {
    int t = threadIdx.x;
    if (t < 48) {
        float m = 0.f;
        for (int d = 0; d < 9; ++d) m += w0[t*9+d];
        m *= (1.f/9.f);
        for (int d = 0; d < 9; ++d) w0c[t*9+d] = w0[t*9+d] - m;
    }
}

// ---------------- 3x3 conv, fp32 in -> fp32 out + bf16 checkpoint ----------------
__global__ __launch_bounds__(256) void conv3x3_kernel(
    const float* __restrict__ inp0, const float* __restrict__ w,
    float* __restrict__ outF0, u16* __restrict__ outCk0, int Cin, int flip,
    size_t inImgStride)
{
    const float* inp  = inp0  + (size_t)blockIdx.z * inImgStride;
    float*       outF = outF0 + (size_t)blockIdx.z * 16*65536;
    u16*         outC = outCk0 + (size_t)blockIdx.z * 16*65536;
    __shared__ float tile[18][19];
    __shared__ float wl[16*16*9];
    int x0 = blockIdx.x * 16, y0 = blockIdx.y * 16;
    int t = threadIdx.x;
    int tx = t & 15, ty = t >> 4;
    int nw = 16 * Cin * 9;
    for (int i = t; i < nw; i += 256) {
        int d = i % 9;
        wl[i] = flip ? w[i + 8 - 2*d] : w[i];
    }
    float acc[16];
#pragma unroll
    for (int co = 0; co < 16; ++co) acc[co] = 0.f;
    for (int ci = 0; ci < Cin; ++ci) {
        __syncthreads();
        for (int i = t; i < 18*18; i += 256) {
            int yy = i / 18, xx = i % 18;
            int gy = y0 - 1 + yy, gx = x0 - 1 + xx;
            float v = 0.f;
            if (gy >= 0 && gy < 256 && gx >= 0 && gx < 256)
                v = inp[((size_t)ci*256 + gy)*256 + gx];
            tile[yy][xx] = v;
        }
        __syncthreads();
        float v[9];
#pragma unroll
        for (int dy = 0; dy < 3; dy++)
#pragma unroll
            for (int dx = 0; dx < 3; dx++) v[dy*3+dx] = tile[ty+dy][tx+dx];
#pragma unroll
        for (int co = 0; co < 16; co++) {
            const float* wp = &wl[(co*Cin+ci)*9];
            acc[co] += v[0]*wp[0]+v[1]*wp[1]+v[2]*wp[2]
                     + v[3]*wp[3]+v[4]*wp[4]+v[5]*wp[5]
                     + v[6]*wp[6]+v[7]*wp[7]+v[8]*wp[8];
        }
    }
#pragma unroll
    for (int co = 0; co < 16; co++) {
        size_t o = ((size_t)co*256 + (y0+ty))*256 + (x0+tx);
        outF[o] = acc[co];
        outC[o] = bf16_rn(acc[co]);
    }
}

// ---------------- spatial split kernels ----------------
// zinit: circshift(22,22) of padded bf16 ck layer9 + softt -> padded H/L planes
__global__ void zinit_split(const u16* __restrict__ fy9, const float* __restrict__ b0,
                            u32* __restrict__ H, u32* __restrict__ L, int total)
{
    int idx = blockIdx.x*256 + threadIdx.x;
    if (idx >= total) return;
    int x2 = idx % 192; int r = idx / 192; int y = r % FH; int plane = r / FH;
    float b = b0[plane & 15];
    u32 hp = 0, lp = 0;
#pragma unroll
    for (int d = 0; d < 2; ++d) {
        int x = x2*2 + d;
        int Y = y + 22; if (Y >= FH) Y -= FH;
        int X = x + 22; if (X >= FH) X -= FH;
        int yy = Y - 44, xx = X - 44;
        float v = 0.f;
        if (yy >= 0 && yy < 256 && xx >= 0 && xx < 256)
            v = bf2f(fy9[((size_t)plane*256 + yy)*256 + xx]);
        v = softt(v, b);
        u16 h = bf16_rn(v), l = bf16_rn(v - bf2f(h));
        hp |= ((u32)h) << (16*d); lp |= ((u32)l) << (16*d);
    }
    H[idx] = hp; L[idx] = lp;
}

// fp32 source (kful / zsp / blurred), full hi/lo split into padded planes
__global__ void split_pad(const float* __restrict__ src, int inH, int inW, int offY, int offX,
                          const float* __restrict__ thr,
                          u32* __restrict__ H, u32* __restrict__ L, int total)
{
    int idx = blockIdx.x*256 + threadIdx.x;
    if (idx >= total) return;
    int x2 = idx % 192; int r = idx / 192; int y = r % FH; int plane = r / FH;
    float b = thr ? thr[plane & 15] : 0.f;
    int yy = y - offY;
    u32 hp = 0, lp = 0;
#pragma unroll
    for (int d = 0; d < 2; ++d) {
        int xx = x2*2 + d - offX;
        float v = 0.f;
        if (yy >= 0 && yy < inH && xx >= 0 && xx < inW)
            v = src[((size_t)plane*inH + yy)*inW + xx];
        if (thr) v = softt(v, b);
        u16 h = bf16_rn(v), l = bf16_rn(v - bf2f(h));
        hp |= ((u32)h) << (16*d); lp |= ((u32)l) << (16*d);
    }
    H[idx] = hp; L[idx] = lp;
}

// bf16 source (fy checkpoints): value exact in bf16 -> H only
__global__ void split_bf16(const u16* __restrict__ src, u32* __restrict__ H, int total)
{
    int idx = blockIdx.x*256 + threadIdx.x;
    if (idx >= total) return;
    int x2 = idx % 192; int r = idx / 192; int y = r % FH; int plane = r / FH;
    int yy = y - 44;
    u32 hp = 0;
#pragma unroll
    for (int d = 0; d < 2; ++d) {
        int xx = x2*2 + d - 44;
        u16 v = 0;
        if (yy >= 0 && yy < 256 && xx >= 0 && xx < 256)
            v = src[((size_t)plane*256 + yy)*256 + xx];
        hp |= ((u32)v) << (16*d);
    }
    H[idx] = hp;
}

// ---------------- MFMA row pass R2C: unified M = B*384 rows, mi=4 ----------------
__global__ __launch_bounds__(256) void r2c_mfma(
    const u16* __restrict__ Hs, const u16* __restrict__ Ls, int ktlo, int kthi,
    const u16* __restrict__ TtH, const u16* __restrict__ TtL,
    u16* __restrict__ outH, u16* __restrict__ outL, int Mtot)
{
    int col0 = blockIdx.x * 64;
    int m0   = blockIdx.y * 256;
    int tid = threadIdx.x;
    int wave = tid >> 6, lane = tid & 63;
    int lm = lane & 15, lq = lane >> 4;
    f32x4 acc[4][4];
#pragma unroll
    for (int mi = 0; mi < 4; ++mi)
#pragma unroll
        for (int nj = 0; nj < 4; ++nj) acc[mi][nj] = (f32x4){0.f,0.f,0.f,0.f};
    int wbase = m0 + wave*64;
    for (int kt = ktlo; kt < kthi; kt += 32) {
        short8 Ah[4], Al[4];
#pragma unroll
        for (int mi = 0; mi < 4; ++mi) {
            int arow = wbase + mi*16 + lm;
            if (wbase + mi*16 < Mtot) {
                size_t off = (size_t)arow*FH + kt + lq*8;
                Ah[mi] = *(const short8*)(Hs + off);
                if (Ls) Al[mi] = *(const short8*)(Ls + off);
            } else {
                Ah[mi] = (short8){0,0,0,0,0,0,0,0};
                if (Ls) Al[mi] = (short8){0,0,0,0,0,0,0,0};
            }
        }
#pragma unroll
        for (int nj = 0; nj < 4; ++nj) {
            size_t toff = (size_t)(col0 + nj*16 + lm)*FH + kt + lq*8;
            short8 Bh = *(const short8*)(TtH + toff);
            short8 Bl = *(const short8*)(TtL + toff);
#pragma unroll
            for (int mi = 0; mi < 4; ++mi) {
                acc[mi][nj] = __builtin_amdgcn_mfma_f32_16x16x32_bf16(Ah[mi], Bh, acc[mi][nj], 0, 0, 0);
                acc[mi][nj] = __builtin_amdgcn_mfma_f32_16x16x32_bf16(Ah[mi], Bl, acc[mi][nj], 0, 0, 0);
                if (Ls)
                    acc[mi][nj] = __builtin_amdgcn_mfma_f32_16x16x32_bf16(Al[mi], Bh, acc[mi][nj], 0, 0, 0);
            }
        }
    }
#pragma unroll
    for (int mi = 0; mi < 4; ++mi) {
        int tbase = wbase + mi*16;
        if (tbase >= Mtot) continue;
        int plane = tbase / FH;
        int ybase = tbase - plane*FH + lq*4;
#pragma unroll
        for (int nj = 0; nj < 4; ++nj) {
            int n = col0 + nj*16 + lm;
            int k = n >> 1;
            u16 h[4], l[4];
#pragma unroll
            for (int rr = 0; rr < 4; ++rr) {
                float v = acc[mi][nj][rr];
                h[rr] = bf16_rn(v);
                l[rr] = bf16_rn(v - bf2f(h[rr]));
            }
            u32 hx = (u32)h[0] | ((u32)h[1]<<16), hy = (u32)h[2] | ((u32)h[3]<<16);
            u32 lx = (u32)l[0] | ((u32)l[1]<<16), ly = (u32)l[2] | ((u32)l[3]<<16);
            u32 phx = __shfl_xor((int)hx, 1), phy = __shfl_xor((int)hy, 1);
            u32 plx = __shfl_xor((int)lx, 1), ply = __shfl_xor((int)ly, 1);
            if (((lm & 1) == 0) && k < SP) {
                uint4 hv, lv;
                hv.x = (hx & 0xffffu) | (phx << 16);
                hv.y = (hx >> 16)     | (phx & 0xffff0000u);
                hv.z = (hy & 0xffffu) | (phy << 16);
                hv.w = (hy >> 16)     | (phy & 0xffff0000u);
                lv.x = (lx & 0xffffu) | (plx << 16);
                lv.y = (lx >> 16)     | (plx & 0xffff0000u);
                lv.z = (ly & 0xffffu) | (ply << 16);
                lv.w = (ly >> 16)     | (ply & 0xffff0000u);
                size_t dst = ((size_t)plane*SP + k)*KP + 2*ybase;
                *(uint4*)(outH + dst) = hv;
                *(uint4*)(outL + dst) = lv;
            }
        }
    }
}

// ---------------- MFMA col pass: C = E·B, mi=4, grid ((N+63)/64, 3) ----------------
__global__ __launch_bounds__(256) void zg_mfma(
    const u16* __restrict__ EH, const u16* __restrict__ EL,
    const u16* __restrict__ SH, const u16* __restrict__ SL,
    u16* __restrict__ outH, u16* __restrict__ outL, int N)
{
    int col0 = blockIdx.x * 64;
    int row0 = blockIdx.y * 256;
    int tid = threadIdx.x;
    int wave = tid >> 6, lane = tid & 63;
    int lm = lane & 15, lq = lane >> 4;
    f32x4 acc[4][4];
#pragma unroll
    for (int mi = 0; mi < 4; ++mi)
#pragma unroll
        for (int nj = 0; nj < 4; ++nj) acc[mi][nj] = (f32x4){0.f,0.f,0.f,0.f};
    int arow = row0 + wave*64 + lm;
    for (int kt = 0; kt < KP; kt += 32) {
        short8 Ah[4], Al[4];
#pragma unroll
        for (int mi = 0; mi < 4; ++mi) {
            size_t aoff = (size_t)(arow + mi*16)*KP + kt + lq*8;
            Ah[mi] = *(const short8*)(EH + aoff);
            Al[mi] = *(const short8*)(EL + aoff);
        }
#pragma unroll
        for (int nj = 0; nj < 4; ++nj) {
            if (col0 + nj*16 >= N) continue;
            size_t boff = (size_t)(col0 + nj*16 + lm)*KP + kt + lq*8;
            short8 Bh = *(const short8*)(SH + boff);
            short8 Bl = *(const short8*)(SL + boff);
#pragma unroll
            for (int mi = 0; mi < 4; ++mi) {
                acc[mi][nj] = __builtin_amdgcn_mfma_f32_16x16x32_bf16(Ah[mi], Bh, acc[mi][nj], 0, 0, 0);
                acc[mi][nj] = __builtin_amdgcn_mfma_f32_16x16x32_bf16(Ah[mi], Bl, acc[mi][nj], 0, 0, 0);
                acc[mi][nj] = __builtin_amdgcn_mfma_f32_16x16x32_bf16(Al[mi], Bh, acc[mi][nj], 0, 0, 0);
            }
        }
    }
#pragma unroll
    for (int mi = 0; mi < 4; ++mi) {
#pragma unroll
        for (int nj = 0; nj < 4; ++nj) {
            if (col0 + nj*16 >= N) continue;
            int col = col0 + nj*16 + lm;
            int r0 = row0 + wave*64 + mi*16 + lq*4;
            u16 h[4], l[4];
#pragma unroll
            for (int rr = 0; rr < 4; ++rr) {
                float v = acc[mi][nj][rr];
                h[rr] = bf16_rn(v);
                l[rr] = bf16_rn(v - bf2f(h[rr]));
            }
            uint2 hv, lv;
            hv.x = (u32)h[0] | ((u32)h[1]<<16); hv.y = (u32)h[2] | ((u32)h[3]<<16);
            lv.x = (u32)l[0] | ((u32)l[1]<<16); lv.y = (u32)l[2] | ((u32)l[3]<<16);
            size_t dst = (size_t)col*KP + r0;
            *(uint2*)(outH + dst) = hv;
            *(uint2*)(outL + dst) = lv;
        }
    }
}

// ---------------- MFMA row pass C2R: unified M, mi=4, optional softt-split side-out ------
__global__ __launch_bounds__(256) void c2r_mfma(
    const u32* __restrict__ SH32, const u32* __restrict__ SL32,
    const u16* __restrict__ UtH, const u16* __restrict__ UtL,
    float* __restrict__ outp, const float* __restrict__ thr,
    u16* __restrict__ spH, u16* __restrict__ spL, int Mtot)
{
    int col0 = blockIdx.x * 64;
    int m0   = blockIdx.y * 256;
    int tid = threadIdx.x;
    int wave = tid >> 6, lane = tid & 63;
    int lm = lane & 15, lq = lane >> 4;
    f32x4 acc[4][4];
#pragma unroll
    for (int mi = 0; mi < 4; ++mi)
#pragma unroll
        for (int nj = 0; nj < 4; ++nj) acc[mi][nj] = (f32x4){0.f,0.f,0.f,0.f};
    int wbase = m0 + wave*64;
    for (int kt = 0; kt < 2*SP; kt += 32) {
        int k0 = (kt + lq*8) >> 1;
        union { short8 s; u32 u[4]; } ah[4], al[4];
#pragma unroll
        for (int mi = 0; mi < 4; ++mi) {
            int tbase = wbase + mi*16;
            if (tbase < Mtot) {
                int plane = tbase / FH;
                int ym = tbase - plane*FH + lm;
                size_t cb = (size_t)plane*SP + k0;
#pragma unroll
                for (int j = 0; j < 4; ++j) {
                    ah[mi].u[j] = SH32[(cb + j)*FH + ym];
                    al[mi].u[j] = SL32[(cb + j)*FH + ym];
                }
            } else {
#pragma unroll
                for (int j = 0; j < 4; ++j) { ah[mi].u[j] = 0; al[mi].u[j] = 0; }
            }
        }
#pragma unroll
        for (int nj = 0; nj < 4; ++nj) {
            size_t toff = (size_t)(col0 + nj*16 + lm)*416 + kt + lq*8;
            short8 Bh = *(const short8*)(UtH + toff);
            short8 Bl = *(const short8*)(UtL + toff);
#pragma unroll
            for (int mi = 0; mi < 4; ++mi) {
                acc[mi][nj] = __builtin_amdgcn_mfma_f32_16x16x32_bf16(ah[mi].s, Bh, acc[mi][nj], 0, 0, 0);
                acc[mi][nj] = __builtin_amdgcn_mfma_f32_16x16x32_bf16(ah[mi].s, Bl, acc[mi][nj], 0, 0, 0);
                acc[mi][nj] = __builtin_amdgcn_mfma_f32_16x16x32_bf16(al[mi].s, Bh, acc[mi][nj], 0, 0, 0);
            }
        }
    }
#pragma unroll
    for (int mi = 0; mi < 4; ++mi) {
        int tbase = wbase + mi*16;
        if (tbase >= Mtot) continue;
        int plane = tbase / FH;
        int ybase = tbase - plane*FH + lq*4;
        float bthr = thr ? thr[plane & 15] : 0.f;
#pragma unroll
        for (int nj = 0; nj < 4; ++nj) {
            int x = col0 + nj*16 + lm;
#pragma unroll
            for (int rr = 0; rr < 4; ++rr) {
                int y = ybase + rr;
                float v = acc[mi][nj][rr];
                outp[((size_t)plane*FH + y)*FH + x] = v;
                if (spH) {
                    float s = softt(v, bthr);
                    u16 h = bf16_rn(s), l = bf16_rn(s - bf2f(h));
                    size_t d = (size_t)plane*SPW + (size_t)y*FH + x;
                    spH[d] = h; spL[d] = l;
                }
            }
        }
    }
}

// ---------------- elementwise frequency-domain updates ----------------
__global__ void fg_kernel(const u32* __restrict__ FfyH, const u32* __restrict__ FfyL,
                          u32* __restrict__ FzH, u32* __restrict__ FzL,
                          const u32* __restrict__ FkH, const u32* __restrict__ FkL,
                          const float* __restrict__ zetas, int L, int total)
{
    int idx = blockIdx.x*256 + threadIdx.x;
    if (idx >= total) return;
    int h = idx % FH; int r = idx / FH;
    int k = r % SP; int plane = r / SP;
    int c = plane & 15; int img = plane >> 4;
    float zeta = 10.f * zetas[L*16 + c];
    size_t sidx = (size_t)r*FH + h;
    size_t fidx = ((size_t)img*SP + k)*FH + h;
    float2 fk = ldc(FkH, FkL, fidx);
    float2 fy = ldc(FfyH, FfyL, sidx);
    float2 fz = ldc(FzH, FzL, sidx);
    float nx = zeta*(fk.x*fy.x + fk.y*fy.y) + fz.x;
    float ny = zeta*(fk.x*fy.y - fk.y*fy.x) + fz.y;
    float den = zeta*(fk.x*fk.x + fk.y*fk.y) + 1.f + 1e-8f;
    float inv = 1.f/den;
    float2 o; o.x = nx*inv; o.y = ny*inv;
    stc(FzH, FzL, sidx, o);
}

__global__ void knum_kernel(const u32* __restrict__ FzH, const u32* __restrict__ FzL,
                            const u32* __restrict__ FfyH, const u32* __restrict__ FfyL,
                            const u32* __restrict__ FkH, const u32* __restrict__ FkL,
                            const float* __restrict__ kprox, int L, int total,
                            u32* __restrict__ outH, u32* __restrict__ outL)
{
    int idx = blockIdx.x*256 + threadIdx.x;
    if (idx >= total) return;
    int h = idx % FH; int r = idx / FH;
    int k = r % SP; int img = r / SP;
    float zk = kprox[L];
    float s1x = 0.f, s1y = 0.f, s2 = 0.f;
    for (int c = 0; c < 16; ++c) {
        size_t si = ((size_t)(img*16 + c)*SP + k)*FH + h;
        float2 fz = ldc(FzH, FzL, si);
        float2 fy = ldc(FfyH, FfyL, si);
        s1x += fz.x*fy.x + fz.y*fy.y;
        s1y += fz.x*fy.y - fz.y*fy.x;
        s2  += fz.x*fz.x + fz.y*fz.y;
    }
    size_t fi = (size_t)r*FH + h;
    float2 fk = ldc(FkH, FkL, fi);
    float nx = zk*s1x + fk.x, ny = zk*s1y + fk.y;
    float den = zk*s2 + 1.f + 1e-8f;
    float inv = 1.f/den;
    float2 o; o.x = nx*inv; o.y = ny*inv;
    stc(outH, outL, fi, o);
}

// ---------------- fused blur-kernel update: LSE + threshold + renorm ----------------
__device__ __forceinline__ void lse_comb(float& m, float& s, float m2, float s2)
{
    if (m2 > m) { s = s * expf(m - m2) + s2; m = m2; }
    else        { s = s + s2 * expf(m2 - m); }
}

__global__ __launch_bounds__(256) void kupdate_kernel(const float* __restrict__ kraw0,
    const float* __restrict__ kb, int L, float* __restrict__ kful0)
{
    int img = blockIdx.x, t = threadIdx.x;
    const float* kraw = kraw0 + (size_t)img*SPW;
    float*       kful = kful0 + (size_t)img*SPW;
    float m = -1e30f, s = 0.f;
    for (int i = t; i < SPW; i += 256) {
        lse_comb(m, s, 100.f * kraw[i], 1.f);
    }
    __shared__ float sm[256], ss[256];
    __shared__ float kmaxS;
    sm[t] = m; ss[t] = s;
    __syncthreads();
    for (int st = 128; st > 0; st >>= 1) {
        if (t < st) {
            float mm = sm[t], sc = ss[t];
            lse_comb(mm, sc, sm[t+st], ss[t+st]);
            sm[t] = mm; ss[t] = sc;
        }
        __syncthreads();
    }
    if (t == 0) kmaxS = (sm[0] + logf(ss[0])) * 0.01f;
    __syncthreads();
    float thr = 0.01f * kb[L] * kmaxS;
    float vs[8]; float loc = 0.f;
#pragma unroll
    for (int ii = 0; ii < 8; ++ii) {
        int i = t + ii*256;
        float v = 0.f;
        if (i < 45*45) {
            int y = i/45, x = i - y*45;
            v = fmaxf(kraw[y*FH + x] - thr, 0.f);
        }
        vs[ii] = v; loc += v;
    }
    __syncthreads();
    sm[t] = loc; __syncthreads();
    for (int st = 128; st > 0; st >>= 1) { if (t < st) sm[t] += sm[t+st]; __syncthreads(); }
    float den = sm[0] + 1e-8f;
#pragma unroll
    for (int ii = 0; ii < 8; ++ii) {
        int i = t + ii*256;
        if (i < 45*45) {
            int y = i/45, x = i - y*45;
            float v = vs[ii] + ((y == 22 && x == 22) ? 1e-8f : 0.f);
            kful[y*FH + x] = v / den;
        }
    }
}

__global__ void zero_kernel(float* __restrict__ p, int n)
{
    int i = blockIdx.x*256 + threadIdx.x;
    if (i < n) p[i] = 0.f;
}
__global__ void kdelta_kernel(float* __restrict__ kful, int G)
{
    int t = threadIdx.x;
    if (t < G) kful[(size_t)t*SPW + 22*FH + 22] = 1.f;
}

// ---------------- Fw0 (direct 9-term DFT, inline twiddles) ----------------
__global__ void fw0_kernel(const float* __restrict__ w0c, float2* __restrict__ Fw0)
{
    int idx = blockIdx.x*256 + threadIdx.x;
    if (idx >= 48*FH*KF) return;
    int k = idx % KF; int r = idx / KF;
    int c = r & 15; int r2 = r >> 4;
    int ci = r2 % 3; int h = r2 / 3;
    const float w2pi = (float)(6.283185307179586 / FH);
    float accx = 0.f, accy = 0.f;
#pragma unroll
    for (int ky = 0; ky < 3; ++ky) {
        int a1 = ky - 1; if (a1 < 0) a1 += FH;
        int m1 = (h * a1) % FH;
        float e1x = cosf(w2pi*m1), e1y = -sinf(w2pi*m1);
#pragma unroll
        for (int kx = 0; kx < 3; ++kx) {
            int a2 = kx - 1; if (a2 < 0) a2 += FH;
            int m2 = (k * a2) % FH;
            float e2x = cosf(w2pi*m2), e2y = -sinf(w2pi*m2);
            float wv = w0c[((c*3 + ci)*3 + ky)*3 + kx];
            accx += wv*(e1x*e2x - e1y*e2y);
            accy += wv*(e1x*e2y + e1y*e2x);
        }
    }
    float2 o; o.x = accx; o.y = accy;
    Fw0[idx] = o;
}

// ---------------- final per-bin 3x3 Hermitian Wiener solve ----------------
__global__ void wiener_kernel(const u32* __restrict__ FkH, const u32* __restrict__ FkL,
    const u32* __restrict__ FyH, const u32* __restrict__ FyL,
    const float2* __restrict__ Fw0,
    const u32* __restrict__ FgH, const u32* __restrict__ FgL,
    const float* __restrict__ eta, int total,
    u32* __restrict__ FxH, u32* __restrict__ FxL)
{
    int idx = blockIdx.x*256 + threadIdx.x;
    if (idx >= total) return;
    int h = idx % FH; int r = idx / FH;
    int k = r % SP; int img = r / SP;
    float2 zo; zo.x = 0.f; zo.y = 0.f;
    if (k >= KF) {
#pragma unroll
        for (int ch = 0; ch < 3; ++ch)
            stc(FxH, FxL, ((size_t)(img*3+ch)*SP + k)*FH + h, zo);
        return;
    }
    float2 fk = ldc(FkH, FkL, (size_t)r*FH + h);
    float fksq = fk.x*fk.x + fk.y*fk.y;
    float2 fyr = ldc(FyH, FyL, ((size_t)(img*3+0)*SP + k)*FH + h);
    float2 fyg = ldc(FyH, FyL, ((size_t)(img*3+1)*SP + k)*FH + h);
    float2 fyb = ldc(FyH, FyL, ((size_t)(img*3+2)*SP + k)*FH + h);
    float Crr = fksq, Cgg = fksq, Cbb = fksq;
    float2 Crg, Crb, Cgb;
    Crg.x = Crg.y = Crb.x = Crb.y = Cgb.x = Cgb.y = 0.f;
    float2 Br, Bg, Bb;
    Br.x = fk.x*fyr.x + fk.y*fyr.y; Br.y = fk.x*fyr.y - fk.y*fyr.x;
    Bg.x = fk.x*fyg.x + fk.y*fyg.y; Bg.y = fk.x*fyg.y - fk.y*fyg.x;
    Bb.x = fk.x*fyb.x + fk.y*fyb.y; Bb.y = fk.x*fyb.y - fk.y*fyb.x;
    for (int c = 0; c < 16; ++c) {
        float es = 10.f * eta[c];
        float2 wr = Fw0[((size_t)h*48 +  0 + c)*KF + k];
        float2 wg = Fw0[((size_t)h*48 + 16 + c)*KF + k];
        float2 wb = Fw0[((size_t)h*48 + 32 + c)*KF + k];
        float2 g  = ldc(FgH, FgL, ((size_t)(img*16+c)*SP + k)*FH + h);
        Crr += es*(wr.x*wr.x + wr.y*wr.y);
        Cgg += es*(wg.x*wg.x + wg.y*wg.y);
        Cbb += es*(wb.x*wb.x + wb.y*wb.y);
        Crg.x += es*(wr.x*wg.x + wr.y*wg.y); Crg.y += es*(wr.x*wg.y - wr.y*wg.x);
        Crb.x += es*(wr.x*wb.x + wr.y*wb.y); Crb.y += es*(wr.x*wb.y - wr.y*wb.x);
        Cgb.x += es*(wg.x*wb.x + wg.y*wb.y); Cgb.y += es*(wg.x*wb.y - wg.y*wb.x);
        Br.x += es*(wr.x*g.x + wr.y*g.y); Br.y += es*(wr.x*g.y - wr.y*g.x);
        Bg.x += es*(wg.x*g.x + wg.y*g.y); Bg.y += es*(wg.x*g.y - wg.y*g.x);
        Bb.x += es*(wb.x*g.x + wb.y*g.y); Bb.y += es*(wb.x*g.y - wb.y*g.x);
    }
    float Crg_sq = Crg.x*Crg.x + Crg.y*Crg.y;
    float Crb_sq = Crb.x*Crb.x + Crb.y*Crb.y;
    float Cgb_sq = Cgb.x*Cgb.x + Cgb.y*Cgb.y;
    float Irr = Cgg*Cbb - Cgb_sq;
    float Igg = Crr*Cbb - Crb_sq;
    float Ibb = Crr*Cgg - Crg_sq;
    float2 Irg, Irb, Igb;
    Irg.x = (Cgb.x*Crb.x + Cgb.y*Crb.y) - Cbb*Crg.x;
    Irg.y = (Cgb.x*Crb.y - Cgb.y*Crb.x) - Cbb*Crg.y;
    Irb.x = (Crg.x*Cgb.x - Crg.y*Cgb.y) - Cgg*Crb.x;
    Irb.y = (Crg.x*Cgb.y + Crg.y*Cgb.x) - Cgg*Crb.y;
    Igb.x = (Crg.x*Crb.x + Crg.y*Crb.y) - Crr*Cgb.x;
    Igb.y = (Crg.x*Crb.y - Crg.y*Crb.x) - Crr*Cgb.y;
    float tx_ = Crg.x*Cgb.x - Crg.y*Cgb.y;
    float ty_ = Crg.x*Cgb.y + Crg.y*Cgb.x;
    float den = Crr*Irr - Cgg*Crb_sq - Cbb*Crg_sq + 2.f*(tx_*Crb.x + ty_*Crb.y) + 1e-8f;
    float inv = 1.f/den;
    float2 o;
    o.x = (Irr*Br.x + (Irg.x*Bg.x - Irg.y*Bg.y) + (Irb.x*Bb.x - Irb.y*Bb.y))*inv;
    o.y = (Irr*Br.y + (Irg.x*Bg.y + Irg.y*Bg.x) + (Irb.x*Bb.y + Irb.y*Bb.x))*inv;
    stc(FxH, FxL, ((size_t)(img*3+0)*SP + k)*FH + h, o);
    o.x = ((Irg.x*Br.x + Irg.y*Br.y) + Igg*Bg.x + (Igb.x*Bb.x - Igb.y*Bb.y))*inv;
    o.y = ((Irg.x*Br.y - Irg.y*Br.x) + Igg*Bg.y + (Igb.x*Bb.y + Igb.y*Bb.x))*inv;
    stc(FxH, FxL, ((size_t)(img*3+1)*SP + k)*FH + h, o);
    o.x = ((Irb.x*Br.x + Irb.y*Br.y) + (Igb.x*Bg.x + Igb.y*Bg.y) + Ibb*Bb.x)*inv;
    o.y = ((Irb.x*Br.y - Irb.y*Br.x) + (Igb.x*Bg.y - Igb.y*Bg.x) + Ibb*Bb.y)*inv;
    stc(FxH, FxL, ((size_t)(img*3+2)*SP + k)*FH + h, o);
}

// ---------------- output assembly ----------------
__global__ void crop_kernel(const float* __restrict__ sp, float* __restrict__ outp, int total)
{
    int idx = blockIdx.x*256 + threadIdx.x;
    if (idx >= total) return;
    int x = idx & 255; int r = idx >> 8; int y = r & 255; int plane = r >> 8;
    outp[idx] = sp[((size_t)plane*FH + (y+22))*FH + (x+22)];
}

__global__ void kcopy_kernel(const float* __restrict__ kful, float* __restrict__ outp, int total)
{
    int idx = blockIdx.x*256 + threadIdx.x;
    if (idx >= total) return;
    int rem = idx % 2025; int img = idx / 2025;
    int x = rem % 45; int y = rem / 45;
    outp[idx] = kful[(size_t)img*SPW + y*FH + x];
}

// =====================================================================
extern "C" void kernel_launch(void* const* d_in, const int* in_sizes, int n_in,
                              void* d_out, int out_size, void* d_ws, size_t ws_size,
                              hipStream_t stream)
{
    (void)in_sizes; (void)n_in; (void)out_size;
    const float* blurred = (const float*)d_in[0];
    const float* w0      = (const float*)d_in[1];
    const float* wsw     = (const float*)d_in[2];
    const float* biases  = (const float*)d_in[3];
    const float* kbias   = (const float*)d_in[4];
    const float* kprox   = (const float*)d_in[5];
    const float* zetas   = (const float*)d_in[6];
    const float* eta     = (const float*)d_in[7];
    float* outp = (float*)d_out;

    auto al = [](size_t b) { return (b + 255) & ~(size_t)255; };
    const size_t SPEC1h = (size_t)16*SP*KP*2;     // one image, 16 planes, one half
    const size_t SPECKh = (size_t)SP*KP*2;
    auto fyRegion = [&](int G) -> size_t {
        size_t ck = (size_t)10*G*16*65536*2;
        size_t ov = al((size_t)48*FH*KF*8) + 4*al((size_t)G*3*SP*KP*2);
        return ck > ov ? ck : ov;
    };
    auto need = [&](int G) -> size_t {
        size_t s = 0;
        s += 4*al((size_t)KP*KP*2);
        s += 2*al((size_t)448*FH*2) + 2*al((size_t)FH*416*2);
        s += al(432*4);
        s += 2*al((size_t)G*16*65536*4);          // ping/pong fp32
        s += al(fyRegion(G));                     // bf16 checkpoints (+final overlays)
        s += al((size_t)G*16*SPW*4);              // zsp fp32
        s += 2*al((size_t)G*16*SPW*2);            // spS H/L
        s += 6*al((size_t)G*SPEC1h);              // mid/Fz/Ffy H/L
        s += 6*al((size_t)G*SPECKh);              // Fk/kfA/kfB H/L
        s += 2*al((size_t)G*SPW*4);               // kraw/kful
        s += al(256);
        return s;
    };
    int G = 4;
    while (G > 1 && need(G) > ws_size) G >>= 1;

    char* base = (char*)d_ws;
    size_t off = 0;
    auto alloc = [&](size_t bytes) -> void* {
        void* p = (void*)(base + off);
        off += (bytes + 255) & ~(size_t)255;
        return p;
    };
    u16* EfH = (u16*)alloc((size_t)KP*KP*2);
    u16* EfL = (u16*)alloc((size_t)KP*KP*2);
    u16* EiH = (u16*)alloc((size_t)KP*KP*2);
    u16* EiL = (u16*)alloc((size_t)KP*KP*2);
    u16* TtH = (u16*)alloc((size_t)448*FH*2);
    u16* TtL = (u16*)alloc((size_t)448*FH*2);
    u16* UtH = (u16*)alloc((size_t)FH*416*2);
    u16* UtL = (u16*)alloc((size_t)FH*416*2);
    float* w0cB = (float*)alloc(432*4);
    float* pingA = (float*)alloc((size_t)G*16*65536*4);
    float* pingB = (float*)alloc((size_t)G*16*65536*4);
    u16*   fyCk  = (u16*)alloc(fyRegion(G));
    float* zsp   = (float*)alloc((size_t)G*16*SPW*4);
    u16* spSH = (u16*)alloc((size_t)G*16*SPW*2);
    u16* spSL = (u16*)alloc((size_t)G*16*SPW*2);
    u16* midH = (u16*)alloc(G*SPEC1h); u16* midL = (u16*)alloc(G*SPEC1h);
    u16* FzH  = (u16*)alloc(G*SPEC1h); u16* FzL  = (u16*)alloc(G*SPEC1h);
    u16* FfyH = (u16*)alloc(G*SPEC1h); u16* FfyL = (u16*)alloc(G*SPEC1h);
    u16* FkH  = (u16*)alloc(G*SPECKh); u16* FkL  = (u16*)alloc(G*SPECKh);
    u16* kfAH = (u16*)alloc(G*SPECKh); u16* kfAL = (u16*)alloc(G*SPECKh);
    u16* kfBH = (u16*)alloc(G*SPECKh); u16* kfBL = (u16*)alloc(G*SPECKh);
    float* kraw = (float*)alloc((size_t)G*SPW*4);
    float* kful = (float*)alloc((size_t)G*SPW*4);
    float* kmaxB = (float*)alloc(256);
    (void)kmaxB;
    // overlays inside fyCk (dead by final stage)
    char* ovl = (char*)fyCk;
    float2* Fw0B = (float2*)ovl;
    size_t o2 = al((size_t)48*FH*KF*8);
    u16* FyBH = (u16*)(ovl + o2); o2 += al((size_t)G*3*SP*KP*2);
    u16* FyBL = (u16*)(ovl + o2); o2 += al((size_t)G*3*SP*KP*2);
    u16* FxBH = (u16*)(ovl + o2); o2 += al((size_t)G*3*SP*KP*2);
    u16* FxBL = (u16*)(ovl + o2);

    init_estack<<<(KP*KP+255)/256, 256, 0, stream>>>(EfH, EfL, 0);
    init_estack<<<(KP*KP+255)/256, 256, 0, stream>>>(EiH, EiL, 1);
    init_tt<<<(448*FH+255)/256, 256, 0, stream>>>(TtH, TtL);
    init_ut<<<(FH*416+255)/256, 256, 0, stream>>>(UtH, UtL);
    w0c_kernel<<<1, 64, 0, stream>>>(w0, w0cB);

    auto r2c = [&](const u16* H, const u16* L, int ktlo, int kthi, u16* oH, u16* oL, int B) {
        int M = B*FH;
        r2c_mfma<<<dim3(7, (M+255)/256), 256, 0, stream>>>(H, L, ktlo, kthi, TtH, TtL, oH, oL, M);
    };
    auto zg = [&](const u16* EH, const u16* EL, const u16* SH, const u16* SL,
                  u16* oH, u16* oL, int N) {
        zg_mfma<<<dim3((N+63)/64, 3), 256, 0, stream>>>(EH, EL, SH, SL, oH, oL, N);
    };
    auto c2r = [&](const u16* SH, const u16* SL, float* o, int B,
                   const float* thr, u16* sH, u16* sL) {
        int M = B*FH;
        c2r_mfma<<<dim3(6, (M+255)/256), 256, 0, stream>>>(
            (const u32*)SH, (const u32*)SL, UtH, UtL, o, thr, sH, sL, M);
    };
    auto splitp = [&](const float* src, int inH, int inW, int oY, int oX,
                      const float* thr, int planes) {
        int tot = planes*FH*192;
        split_pad<<<(tot+255)/256, 256, 0, stream>>>(src, inH, inW, oY, oX, thr,
                                                     (u32*)spSH, (u32*)spSL, tot);
    };

    const size_t CKL = (size_t)G*16*65536;        // one ck layer (u16 elements)
    const int N1 = G*16*SP, N2 = G*SP, N3 = G*3*SP;
    const int tot1 = N1*FH, tot2 = N2*FH;

    for (int g0 = 0; g0 < 4; g0 += G) {
        const float* img = blurred + (size_t)g0*3*65536;

        // forward conv chain: fp32 ping-pong + bf16 checkpoints
        conv3x3_kernel<<<dim3(16,16,G), 256, 0, stream>>>(
            img, w0cB, pingA, fyCk, 3, 1, (size_t)3*65536);
        float* cur = pingA; float* nxt = pingB;
        for (int l = 1; l < 10; ++l) {
            conv3x3_kernel<<<dim3(16,16,G), 256, 0, stream>>>(
                cur, wsw + (size_t)(l-1)*2304, nxt, fyCk + (size_t)l*CKL, 16,
                0, (size_t)16*65536);
            float* t = cur; cur = nxt; nxt = t;
        }

        // z init from ck layer 9
        int totZ = G*16*FH*192;
        zinit_split<<<(totZ+255)/256, 256, 0, stream>>>(fyCk + 9*CKL, biases,
                                                        (u32*)spSH, (u32*)spSL, totZ);
        r2c(spSH, spSL, 0, FH, midH, midL, G*16);
        zg(EfH, EfL, midH, midL, FzH, FzL, N1);

        zero_kernel<<<(G*SPW+255)/256, 256, 0, stream>>>(kful, G*SPW);
        kdelta_kernel<<<1, 64, 0, stream>>>(kful, G);

        for (int it = 0; it < 10; ++it) {
            int Lfy = 9 - it;
            split_bf16<<<(totZ+255)/256, 256, 0, stream>>>(fyCk + (size_t)Lfy*CKL,
                                                           (u32*)spSH, totZ);
            r2c(spSH, nullptr, 32, 320, midH, midL, G*16);      // fy is exact bf16
            zg(EfH, EfL, midH, midL, FfyH, FfyL, N1);
            splitp(kful, FH, FH, 0, 0, nullptr, G);
            r2c(spSH, spSL, 0, FH, kfAH, kfAL, G);
            zg(EfH, EfL, kfAH, kfAL, FkH, FkL, N2);
            fg_kernel<<<(tot1+255)/256, 256, 0, stream>>>(
                (u32*)FfyH, (u32*)FfyL, (u32*)FzH, (u32*)FzL,
                (u32*)FkH, (u32*)FkL, zetas, it, tot1);
            zg(EiH, EiL, FzH, FzL, midH, midL, N1);
            c2r(midH, midL, zsp, G*16, biases + (it+1)*16, spSH, spSL);
            r2c(spSH, spSL, 0, FH, midH, midL, G*16);
            zg(EfH, EfL, midH, midL, FzH, FzL, N1);
            knum_kernel<<<(tot2+255)/256, 256, 0, stream>>>(
                (u32*)FzH, (u32*)FzL, (u32*)FfyH, (u32*)FfyL,
                (u32*)FkH, (u32*)FkL, kprox, it, tot2, (u32*)kfBH, (u32*)kfBL);
            zg(EiH, EiL, kfBH, kfBL, kfAH, kfAL, N2);
            c2r(kfAH, kfAL, kraw, G, nullptr, nullptr, nullptr);
            kupdate_kernel<<<G, 256, 0, stream>>>(kraw, kbias, it, kful);
        }

        // ---- final stage (fyCk dead; overlays live) ----
        splitp(img, 256, 256, 44, 44, nullptr, 3*G);
        r2c(spSH, spSL, 32, 320, midH, midL, 3*G);
        zg(EfH, EfL, midH, midL, FyBH, FyBL, N3);
        splitp(kful, FH, FH, 0, 0, nullptr, G);
        r2c(spSH, spSL, 0, FH, kfAH, kfAL, G);
        zg(EfH, EfL, kfAH, kfAL, FkH, FkL, N2);
        splitp(zsp, FH, FH, 0, 0, biases + 11*16, G*16);
        r2c(spSH, spSL, 0, FH, midH, midL, G*16);
        zg(EfH, EfL, midH, midL, FzH, FzL, N1);           // Fg2
        fw0_kernel<<<(48*FH*KF+255)/256, 256, 0, stream>>>(w0cB, Fw0B);
        wiener_kernel<<<(tot2+255)/256, 256, 0, stream>>>(
            (u32*)FkH, (u32*)FkL, (u32*)FyBH, (u32*)FyBL, Fw0B,
            (u32*)FzH, (u32*)FzL, eta, tot2, (u32*)FxBH, (u32*)FxBL);
        zg(EiH, EiL, FxBH, FxBL, midH, midL, N3);
        c2r(midH, midL, zsp, 3*G, nullptr, nullptr, nullptr);
        int totC = G*3*65536;
        crop_kernel<<<(totC+255)/256, 256, 0, stream>>>(zsp, outp + (size_t)g0*3*65536, totC);
        int totKC = G*2025;
        kcopy_kernel<<<(totKC+255)/256, 256, 0, stream>>>(kful, outp + 786432 + g0*2025, totKC);
    }
}

// Round 9
// 17618.295 us; speedup vs baseline: 1.0215x; 1.0215x over previous
//
#include <hip/hip_runtime.h>
#include <math.h>

#define FH 384
#define KF 193
#define KP 768    // stacked real K' = 2*FH (col pass)
#define NR 386    // real row-spectrum width = 2*KF

typedef __attribute__((ext_vector_type(8))) short short8;
typedef __attribute__((ext_vector_type(4))) float f32x4;
typedef unsigned short u16;
typedef unsigned int u32;

static __device__ __forceinline__ float softt(float v, float b) {
    return copysignf(fmaxf(fabsf(v) - b, 0.f), v);
}
static __device__ __forceinline__ u16 bf16_rn(float v) {
    u32 u = __float_as_uint(v);
    return (u16)((u + 0x7FFFu + ((u >> 16) & 1u)) >> 16);
}
static __device__ __forceinline__ float bf2f(u16 h) {
    return __uint_as_float(((u32)h) << 16);
}

// ---------------- tables ----------------
__global__ void init_ef_k(float2* Ef) {
    int idx = blockIdx.x * 256 + threadIdx.x;
    if (idx >= FH * FH) return;
    int h = idx / FH, j = idx % FH;
    int m = (h * j) % FH;
    float th = (float)(6.283185307179586 / FH) * (float)m;
    float2 v; v.x = cosf(th); v.y = -sinf(th);
    Ef[idx] = v;
}

// stacked real DFT matrix for MFMA col pass (A-operand), bf16 hi/lo
__global__ void init_estack(u16* __restrict__ H, u16* __restrict__ L, int inv)
{
    int idx = blockIdx.x * 256 + threadIdx.x;
    if (idx >= KP * KP) return;
    int gm = idx / KP, kp = idx % KP;
    int m = gm >> 1, comp = gm & 1;
    int t = kp >> 1, ri = kp & 1;
    int mm = (m * t) % FH;
    float th = (float)(6.283185307179586 / FH) * (float)mm;
    float c = cosf(th), s = sinf(th);
    float er, ei;
    if (inv) { er = c * (1.f/FH); ei = s * (1.f/FH); }
    else     { er = c;            ei = -s; }
    float v;
    if (comp == 0) v = (ri == 0) ? er : -ei;
    else           v = (ri == 0) ? ei :  er;
    u16 h = bf16_rn(v);
    H[idx] = h;
    L[idx] = bf16_rn(v - bf2f(h));
}

// r2c row-pass B-table, transposed: Tt[n][w], n=2*kf+ri (448 rows, zero pad)
__global__ void init_tt(u16* __restrict__ H, u16* __restrict__ L)
{
    int idx = blockIdx.x * 256 + threadIdx.x;
    if (idx >= 448 * FH) return;
    int n = idx / FH, w = idx % FH;
    float v = 0.f;
    if (n < NR) {
        int kf = n >> 1, ri = n & 1;
        int m = (w * kf) % FH;
        float th = (float)(6.283185307179586 / FH) * (float)m;
        v = ri ? -sinf(th) : cosf(th);
    }
    u16 h = bf16_rn(v);
    H[idx] = h;
    L[idx] = bf16_rn(v - bf2f(h));
}

// c2r row-pass B-table, transposed: Ut[x][kp], kp=2*k+ri (416 cols, zero pad)
__global__ void init_ut(u16* __restrict__ H, u16* __restrict__ L)
{
    int idx = blockIdx.x * 256 + threadIdx.x;
    if (idx >= FH * 416) return;
    int x = idx / 416, kp = idx % 416;
    float v = 0.f;
    if (kp < NR) {
        int k = kp >> 1, ri = kp & 1;
        float ck = (k == 0 || k == FH/2) ? (1.f/FH) : (2.f/FH);
        int m = (k * x) % FH;
        float th = (float)(6.283185307179586 / FH) * (float)m;
        v = ri ? -ck*sinf(th) : ck*cosf(th);
    }
    u16 h = bf16_rn(v);
    H[idx] = h;
    L[idx] = bf16_rn(v - bf2f(h));
}

__global__ void w0c_kernel(const float* __restrict__ w0, float* __restrict__ w0c) {
    int t = threadIdx.x;
    if (t < 48) {
        float m = 0.f;
        for (int d = 0; d < 9; ++d) m += w0[t*9+d];
        m *= (1.f/9.f);
        for (int d = 0; d < 9; ++d) w0c[t*9+d] = w0[t*9+d] - m;
    }
}

// ---------------- 3x3 conv: fp32 ping-pong + bf16 checkpoint out ----------------
__global__ __launch_bounds__(256) void conv3x3_kernel(
    const float* __restrict__ inp0, const float* __restrict__ w,
    float* __restrict__ outF0, u16* __restrict__ outCk0, int Cin, int flip,
    size_t inImgStride)
{
    const float* inp  = inp0  + (size_t)blockIdx.z * inImgStride;
    float*       outF = outF0 + (size_t)blockIdx.z * 16*65536;
    u16*         outC = outCk0 + (size_t)blockIdx.z * 16*65536;
    __shared__ float tile[18][19];
    __shared__ float wl[16*16*9];
    int x0 = blockIdx.x * 16, y0 = blockIdx.y * 16;
    int t = threadIdx.x;
    int tx = t & 15, ty = t >> 4;
    int nw = 16 * Cin * 9;
    for (int i = t; i < nw; i += 256) {
        int d = i % 9;
        wl[i] = flip ? w[i + 8 - 2*d] : w[i];
    }
    float acc[16];
#pragma unroll
    for (int co = 0; co < 16; ++co) acc[co] = 0.f;
    for (int ci = 0; ci < Cin; ++ci) {
        __syncthreads();
        for (int i = t; i < 18*18; i += 256) {
            int yy = i / 18, xx = i % 18;
            int gy = y0 - 1 + yy, gx = x0 - 1 + xx;
            float v = 0.f;
            if (gy >= 0 && gy < 256 && gx >= 0 && gx < 256)
                v = inp[((size_t)ci*256 + gy)*256 + gx];
            tile[yy][xx] = v;
        }
        __syncthreads();
        float v[9];
#pragma unroll
        for (int dy = 0; dy < 3; dy++)
#pragma unroll
            for (int dx = 0; dx < 3; dx++) v[dy*3+dx] = tile[ty+dy][tx+dx];
#pragma unroll
        for (int co = 0; co < 16; co++) {
            const float* wp = &wl[(co*Cin+ci)*9];
            acc[co] += v[0]*wp[0]+v[1]*wp[1]+v[2]*wp[2]
                     + v[3]*wp[3]+v[4]*wp[4]+v[5]*wp[5]
                     + v[6]*wp[6]+v[7]*wp[7]+v[8]*wp[8];
        }
    }
#pragma unroll
    for (int co = 0; co < 16; co++) {
        size_t o = ((size_t)co*256 + (y0+ty))*256 + (x0+tx);
        outF[o] = acc[co];
        outC[o] = bf16_rn(acc[co]);
    }
}

// ---------------- z init: circshift(22,22) of padded bf16 ck9 + soft threshold ------
__global__ void zinit_kernel(const u16* __restrict__ fy9, const float* __restrict__ b0,
                             float* __restrict__ z, int total)
{
    int idx = blockIdx.x*256 + threadIdx.x;
    if (idx >= total) return;
    int x = idx % FH; int r = idx / FH; int y = r % FH; int plane = r / FH;
    int c = plane & 15;
    int Y = y + 22; if (Y >= FH) Y -= FH;
    int X = x + 22; if (X >= FH) X -= FH;
    int yy = Y - 44, xx = X - 44;
    float v = 0.f;
    if (yy >= 0 && yy < 256 && xx >= 0 && xx < 256)
        v = bf2f(fy9[((size_t)plane*256 + yy)*256 + xx]);
    z[idx] = softt(v, b0[c]);
}

// ---------------- MFMA row pass R2C (r6 kernel + srcbf16 flag) ----------------
__global__ __launch_bounds__(256) void r2c_row_mfma(
    const void* __restrict__ inpv, int srcbf16, int inH, int inW, int offY, int offX,
    const float* __restrict__ thr,
    const u16* __restrict__ TtH, const u16* __restrict__ TtL,
    float* __restrict__ outp, int B)
{
    __shared__ u16 AhS[8*64*8];
    __shared__ u16 AlS[8*64*8];
    int col0 = blockIdx.x * 64;
    int y0   = blockIdx.y * 128;
    int plane = blockIdx.z;
    int tid = threadIdx.x;
    int wave = tid >> 6, lane = tid & 63;
    int lm = lane & 15, lq = lane >> 4;
    f32x4 acc[2][4];
#pragma unroll
    for (int mi = 0; mi < 2; ++mi)
#pragma unroll
        for (int nj = 0; nj < 4; ++nj) acc[mi][nj] = (f32x4){0.f,0.f,0.f,0.f};
    float bthr = thr ? thr[plane & 15] : 0.f;
    const float* inpF = (const float*)inpv + (srcbf16 ? 0 : (size_t)plane*inH*inW);
    const u16*   inpB = (const u16*)inpv + (srcbf16 ? (size_t)plane*inH*inW : 0);
    int ktlo = (offX >> 5) << 5;
    int kthi = offX + inW;
    for (int kt = ktlo; kt < kthi; kt += 32) {
#pragma unroll
        for (int s = 0; s < 4; ++s) {
            int slot = tid + s*256;
            int r = slot >> 3, kq = slot & 7;
            int yy = y0 + r - offY;
            float v[4];
#pragma unroll
            for (int d = 0; d < 4; ++d) {
                int xx = kt + kq*4 + d - offX;
                float t = 0.f;
                if (yy >= 0 && yy < inH && xx >= 0 && xx < inW)
                    t = srcbf16 ? bf2f(inpB[(size_t)yy*inW + xx])
                                : inpF[(size_t)yy*inW + xx];
                if (thr) t = softt(t, bthr);
                v[d] = t;
            }
            u16 h0 = bf16_rn(v[0]), h1 = bf16_rn(v[1]);
            u16 h2 = bf16_rn(v[2]), h3 = bf16_rn(v[3]);
            u16 l0 = bf16_rn(v[0] - bf2f(h0));
            u16 l1 = bf16_rn(v[1] - bf2f(h1));
            u16 l2 = bf16_rn(v[2] - bf2f(h2));
            u16 l3 = bf16_rn(v[3] - bf2f(h3));
            int base = ((r >> 4)*64 + (r & 15) + 16*(kq >> 1))*8 + (kq & 1)*4;
            uint2 hp, lp;
            hp.x = (u32)h0 | ((u32)h1 << 16);
            hp.y = (u32)h2 | ((u32)h3 << 16);
            lp.x = (u32)l0 | ((u32)l1 << 16);
            lp.y = (u32)l2 | ((u32)l3 << 16);
            *(uint2*)&AhS[base] = hp;
            *(uint2*)&AlS[base] = lp;
        }
        __syncthreads();
        short8 Ah[2], Al[2];
#pragma unroll
        for (int mi = 0; mi < 2; ++mi) {
            Ah[mi] = *(const short8*)&AhS[((wave*2 + mi)*64 + lane)*8];
            Al[mi] = *(const short8*)&AlS[((wave*2 + mi)*64 + lane)*8];
        }
#pragma unroll
        for (int nj = 0; nj < 4; ++nj) {
            size_t toff = (size_t)(col0 + nj*16 + lm)*FH + kt + lq*8;
            short8 Bh = *(const short8*)(TtH + toff);
            short8 Bl = *(const short8*)(TtL + toff);
#pragma unroll
            for (int mi = 0; mi < 2; ++mi) {
                acc[mi][nj] = __builtin_amdgcn_mfma_f32_16x16x32_bf16(Ah[mi], Bh, acc[mi][nj], 0, 0, 0);
                acc[mi][nj] = __builtin_amdgcn_mfma_f32_16x16x32_bf16(Ah[mi], Bl, acc[mi][nj], 0, 0, 0);
                acc[mi][nj] = __builtin_amdgcn_mfma_f32_16x16x32_bf16(Al[mi], Bh, acc[mi][nj], 0, 0, 0);
            }
        }
        __syncthreads();
    }
#pragma unroll
    for (int mi = 0; mi < 2; ++mi) {
#pragma unroll
        for (int nj = 0; nj < 4; ++nj) {
            int n = col0 + nj*16 + lm;
            if (n < NR) {
#pragma unroll
                for (int rr = 0; rr < 4; ++rr) {
                    int y = y0 + wave*32 + mi*16 + lq*4 + rr;
                    outp[((size_t)y*B + plane)*NR + n] = acc[mi][nj][rr];
                }
            }
        }
    }
}

// ---------------- MFMA row pass C2R (r6 kernel, unchanged) ----------------
__global__ __launch_bounds__(256) void c2r_row_mfma(
    const float* __restrict__ Aflat,
    const u16* __restrict__ UtH, const u16* __restrict__ UtL,
    float* __restrict__ outp, int B)
{
    __shared__ u16 AhS[8*64*8];
    __shared__ u16 AlS[8*64*8];
    int col0 = blockIdx.x * 64;
    int y0   = blockIdx.y * 128;
    int plane = blockIdx.z;
    int tid = threadIdx.x;
    int wave = tid >> 6, lane = tid & 63;
    int lm = lane & 15, lq = lane >> 4;
    f32x4 acc[2][4];
#pragma unroll
    for (int mi = 0; mi < 2; ++mi)
#pragma unroll
        for (int nj = 0; nj < 4; ++nj) acc[mi][nj] = (f32x4){0.f,0.f,0.f,0.f};
    for (int kt = 0; kt < 416; kt += 32) {
#pragma unroll
        for (int s = 0; s < 4; ++s) {
            int slot = tid + s*256;
            int r = slot >> 3, kq = slot & 7;
            size_t rowb = ((size_t)(y0 + r)*B + plane)*NR;
            float v[4];
#pragma unroll
            for (int d = 0; d < 4; ++d) {
                int kp = kt + kq*4 + d;
                v[d] = (kp < NR) ? Aflat[rowb + kp] : 0.f;
            }
            u16 h0 = bf16_rn(v[0]), h1 = bf16_rn(v[1]);
            u16 h2 = bf16_rn(v[2]), h3 = bf16_rn(v[3]);
            u16 l0 = bf16_rn(v[0] - bf2f(h0));
            u16 l1 = bf16_rn(v[1] - bf2f(h1));
            u16 l2 = bf16_rn(v[2] - bf2f(h2));
            u16 l3 = bf16_rn(v[3] - bf2f(h3));
            int base = ((r >> 4)*64 + (r & 15) + 16*(kq >> 1))*8 + (kq & 1)*4;
            uint2 hp, lp;
            hp.x = (u32)h0 | ((u32)h1 << 16);
            hp.y = (u32)h2 | ((u32)h3 << 16);
            lp.x = (u32)l0 | ((u32)l1 << 16);
            lp.y = (u32)l2 | ((u32)l3 << 16);
            *(uint2*)&AhS[base] = hp;
            *(uint2*)&AlS[base] = lp;
        }
        __syncthreads();
        short8 Ah[2], Al[2];
#pragma unroll
        for (int mi = 0; mi < 2; ++mi) {
            Ah[mi] = *(const short8*)&AhS[((wave*2 + mi)*64 + lane)*8];
            Al[mi] = *(const short8*)&AlS[((wave*2 + mi)*64 + lane)*8];
        }
#pragma unroll
        for (int nj = 0; nj < 4; ++nj) {
            size_t toff = (size_t)(col0 + nj*16 + lm)*416 + kt + lq*8;
            short8 Bh = *(const short8*)(UtH + toff);
            short8 Bl = *(const short8*)(UtL + toff);
#pragma unroll
            for (int mi = 0; mi < 2; ++mi) {
                acc[mi][nj] = __builtin_amdgcn_mfma_f32_16x16x32_bf16(Ah[mi], Bh, acc[mi][nj], 0, 0, 0);
                acc[mi][nj] = __builtin_amdgcn_mfma_f32_16x16x32_bf16(Ah[mi], Bl, acc[mi][nj], 0, 0, 0);
                acc[mi][nj] = __builtin_amdgcn_mfma_f32_16x16x32_bf16(Al[mi], Bh, acc[mi][nj], 0, 0, 0);
            }
        }
        __syncthreads();
    }
#pragma unroll
    for (int mi = 0; mi < 2; ++mi) {
#pragma unroll
        for (int nj = 0; nj < 4; ++nj) {
            int x = col0 + nj*16 + lm;
#pragma unroll
            for (int rr = 0; rr < 4; ++rr) {
                int y = y0 + wave*32 + mi*16 + lq*4 + rr;
                outp[((size_t)plane*FH + y)*FH + x] = acc[mi][nj][rr];
            }
        }
    }
}

// ---------------- MFMA col pass (r6 kernel, unchanged) ----------------
__global__ __launch_bounds__(256) void zgemm_col_mfma(
    const u16* __restrict__ EH, const u16* __restrict__ EL,
    const float2* __restrict__ Bm, float* __restrict__ Cm, int N)
{
    __shared__ u16 BhS[4*64*8];
    __shared__ u16 BlS[4*64*8];
    int col0 = blockIdx.x * 64;
    int row0 = blockIdx.y * 128;
    int tid = threadIdx.x;
    int wave = tid >> 6, lane = tid & 63;
    int lm = lane & 15, lq = lane >> 4;
    f32x4 acc[2][4];
#pragma unroll
    for (int mi = 0; mi < 2; ++mi)
#pragma unroll
        for (int nj = 0; nj < 4; ++nj) acc[mi][nj] = (f32x4){0.f,0.f,0.f,0.f};
    int arow0 = row0 + wave*32 + lm;
    for (int kt = 0; kt < KP; kt += 32) {
        int tbase = kt >> 1;
#pragma unroll
        for (int s = 0; s < 2; ++s) {
            int slot = tid + s*256;
            int pair = slot >> 6;
            int n    = slot & 63;
            int gn   = col0 + n;
            int t0   = tbase + pair*2;
            float2 v0, v1;
            v0.x = v0.y = v1.x = v1.y = 0.f;
            if (gn < N) {
                v0 = Bm[(size_t)t0*N + gn];
                v1 = Bm[(size_t)(t0+1)*N + gn];
            }
            u16 h0 = bf16_rn(v0.x), h1 = bf16_rn(v0.y);
            u16 h2 = bf16_rn(v1.x), h3 = bf16_rn(v1.y);
            u16 l0 = bf16_rn(v0.x - bf2f(h0));
            u16 l1 = bf16_rn(v0.y - bf2f(h1));
            u16 l2 = bf16_rn(v1.x - bf2f(h2));
            u16 l3 = bf16_rn(v1.y - bf2f(h3));
            int ntile = n >> 4, n0 = n & 15;
            int lrow  = (pair >> 1)*16 + n0;
            int base  = (ntile*64 + lrow)*8 + (pair & 1)*4;
            uint2 hp, lp;
            hp.x = (u32)h0 | ((u32)h1 << 16);
            hp.y = (u32)h2 | ((u32)h3 << 16);
            lp.x = (u32)l0 | ((u32)l1 << 16);
            lp.y = (u32)l2 | ((u32)l3 << 16);
            *(uint2*)&BhS[base] = hp;
            *(uint2*)&BlS[base] = lp;
        }
        __syncthreads();
        short8 Ah[2], Al[2];
#pragma unroll
        for (int mi = 0; mi < 2; ++mi) {
            size_t aoff = (size_t)(arow0 + mi*16)*KP + kt + lq*8;
            Ah[mi] = *(const short8*)(EH + aoff);
            Al[mi] = *(const short8*)(EL + aoff);
        }
#pragma unroll
        for (int nj = 0; nj < 4; ++nj) {
            short8 Bh = *(const short8*)&BhS[(nj*64 + lane)*8];
            short8 Bl = *(const short8*)&BlS[(nj*64 + lane)*8];
#pragma unroll
            for (int mi = 0; mi < 2; ++mi) {
                acc[mi][nj] = __builtin_amdgcn_mfma_f32_16x16x32_bf16(Ah[mi], Bh, acc[mi][nj], 0, 0, 0);
                acc[mi][nj] = __builtin_amdgcn_mfma_f32_16x16x32_bf16(Ah[mi], Bl, acc[mi][nj], 0, 0, 0);
                acc[mi][nj] = __builtin_amdgcn_mfma_f32_16x16x32_bf16(Al[mi], Bh, acc[mi][nj], 0, 0, 0);
            }
        }
        __syncthreads();
    }
#pragma unroll
    for (int mi = 0; mi < 2; ++mi) {
#pragma unroll
        for (int nj = 0; nj < 4; ++nj) {
            int coln = col0 + nj*16 + lm;
            if (coln < N) {
#pragma unroll
                for (int r = 0; r < 4; ++r) {
                    int row = row0 + wave*32 + mi*16 + lq*4 + r;
                    Cm[((size_t)(row >> 1)*N + coln)*2 + (row & 1)] = acc[mi][nj][r];
                }
            }
        }
    }
}

// ---------------- elementwise frequency-domain updates ----------------
__global__ void fg_kernel(const float2* __restrict__ Ffy, const float2* __restrict__ Fz,
                          const float2* __restrict__ Fk, const float* __restrict__ zetas,
                          int L, int total, float2* __restrict__ Fg)
{
    int idx = blockIdx.x*256 + threadIdx.x;
    if (idx >= total) return;
    int k = idx % KF; int r = idx / KF;
    int c = r & 15; int hi = r >> 4;
    float zeta = 10.f * zetas[L*16 + c];
    float2 fk = Fk[(size_t)hi*KF + k];
    float2 fy = Ffy[idx];
    float2 fz = Fz[idx];
    float nx = zeta*(fk.x*fy.x + fk.y*fy.y) + fz.x;
    float ny = zeta*(fk.x*fy.y - fk.y*fy.x) + fz.y;
    float den = zeta*(fk.x*fk.x + fk.y*fk.y) + 1.f + 1e-8f;
    float inv = 1.f/den;
    float2 o; o.x = nx*inv; o.y = ny*inv;
    Fg[idx] = o;
}

__global__ void knum_kernel(const float2* __restrict__ Fz, const float2* __restrict__ Ffy,
                            const float2* __restrict__ Fk, const float* __restrict__ kprox,
                            int L, int total, float2* __restrict__ outk)
{
    int idx = blockIdx.x*256 + threadIdx.x;
    if (idx >= total) return;
    int k = idx % KF; int r = idx / KF;
    float zk = kprox[L];
    float s1x = 0.f, s1y = 0.f, s2 = 0.f;
    for (int c = 0; c < 16; ++c) {
        size_t bi = ((size_t)r*16 + c)*KF + k;
        float2 fz = Fz[bi], fy = Ffy[bi];
        s1x += fz.x*fy.x + fz.y*fy.y;
        s1y += fz.x*fy.y - fz.y*fy.x;
        s2  += fz.x*fz.x + fz.y*fz.y;
    }
    float2 fk = Fk[idx];
    float nx = zk*s1x + fk.x, ny = zk*s1y + fk.y;
    float den = zk*s2 + 1.f + 1e-8f;
    float inv = 1.f/den;
    float2 o; o.x = nx*inv; o.y = ny*inv;
    outk[idx] = o;
}

// ---------------- fused blur-kernel update: LSE + threshold + renorm ----------------
__device__ __forceinline__ void lse_comb(float& m, float& s, float m2, float s2)
{
    if (m2 > m) { s = s * expf(m - m2) + s2; m = m2; }
    else        { s = s + s2 * expf(m2 - m); }
}

__global__ __launch_bounds__(256) void kupdate_kernel(const float* __restrict__ kraw0,
    const float* __restrict__ kb, int L, float* __restrict__ kful0)
{
    int img = blockIdx.x, t = threadIdx.x;
    const float* kraw = kraw0 + (size_t)img*FH*FH;
    float*       kful = kful0 + (size_t)img*FH*FH;
    float m = -1e30f, s = 0.f;
    for (int i = t; i < FH*FH; i += 256) {
        lse_comb(m, s, 100.f * kraw[i], 1.f);
    }
    __shared__ float sm[256], ss[256];
    __shared__ float kmaxS;
    sm[t] = m; ss[t] = s;
    __syncthreads();
    for (int st = 128; st > 0; st >>= 1) {
        if (t < st) {
            float mm = sm[t], sc = ss[t];
            lse_comb(mm, sc, sm[t+st], ss[t+st]);
            sm[t] = mm; ss[t] = sc;
        }
        __syncthreads();
    }
    if (t == 0) kmaxS = (sm[0] + logf(ss[0])) * 0.01f;
    __syncthreads();
    float thr = 0.01f * kb[L] * kmaxS;
    float vs[8]; float loc = 0.f;
#pragma unroll
    for (int ii = 0; ii < 8; ++ii) {
        int i = t + ii*256;
        float v = 0.f;
        if (i < 45*45) {
            int y = i/45, x = i - y*45;
            v = fmaxf(kraw[y*FH + x] - thr, 0.f);
        }
        vs[ii] = v; loc += v;
    }
    __syncthreads();
    sm[t] = loc; __syncthreads();
    for (int st = 128; st > 0; st >>= 1) { if (t < st) sm[t] += sm[t+st]; __syncthreads(); }
    float den = sm[0] + 1e-8f;
#pragma unroll
    for (int ii = 0; ii < 8; ++ii) {
        int i = t + ii*256;
        if (i < 45*45) {
            int y = i/45, x = i - y*45;
            float v = vs[ii] + ((y == 22 && x == 22) ? 1e-8f : 0.f);
            kful[y*FH + x] = v / den;
        }
    }
}

__global__ void zero_kernel(float* __restrict__ p, int n)
{
    int i = blockIdx.x*256 + threadIdx.x;
    if (i < n) p[i] = 0.f;
}

__global__ void kdelta_kernel(float* __restrict__ kful, int G)
{
    int t = threadIdx.x;
    if (t < G) kful[(size_t)t*FH*FH + 22*FH + 22] = 1.f;
}

// ---------------- Fw0 (direct 9-term DFT of shifted 3x3) ----------------
__global__ void fw0_kernel(const float* __restrict__ w0c, const float2* __restrict__ Ef,
                           float2* __restrict__ Fw0)
{
    int idx = blockIdx.x*256 + threadIdx.x;
    if (idx >= 48*FH*KF) return;
    int k = idx % KF; int r = idx / KF;
    int c = r & 15; int r2 = r >> 4;
    int ci = r2 % 3; int h = r2 / 3;
    float accx = 0.f, accy = 0.f;
#pragma unroll
    for (int ky = 0; ky < 3; ++ky) {
        int a1 = ky - 1; if (a1 < 0) a1 += FH;
        float2 e1 = Ef[h*FH + a1];
#pragma unroll
        for (int kx = 0; kx < 3; ++kx) {
            int a2 = kx - 1; if (a2 < 0) a2 += FH;
            float2 e2 = Ef[k*FH + a2];
            float wv = w0c[((c*3 + ci)*3 + ky)*3 + kx];
            float tr = e1.x*e2.x - e1.y*e2.y;
            float ti = e1.x*e2.y + e1.y*e2.x;
            accx += wv*tr; accy += wv*ti;
        }
    }
    float2 o; o.x = accx; o.y = accy;
    Fw0[idx] = o;
}

// ---------------- final per-bin 3x3 Hermitian Wiener solve ----------------
__global__ void wiener_kernel(const float2* __restrict__ Fk, const float2* __restrict__ Fy,
    const float2* __restrict__ Fw0, const float2* __restrict__ Fg2,
    const float* __restrict__ eta, int G, int total, float2* __restrict__ Fx)
{
    int idx = blockIdx.x*256 + threadIdx.x;
    if (idx >= total) return;
    int k = idx % KF; int r = idx / KF;
    int h = r / G;
    float2 fk = Fk[idx];
    float fksq = fk.x*fk.x + fk.y*fk.y;
    float2 fyr = Fy[((size_t)3*r + 0)*KF + k];
    float2 fyg = Fy[((size_t)3*r + 1)*KF + k];
    float2 fyb = Fy[((size_t)3*r + 2)*KF + k];
    float Crr = fksq, Cgg = fksq, Cbb = fksq;
    float2 Crg, Crb, Cgb;
    Crg.x = Crg.y = Crb.x = Crb.y = Cgb.x = Cgb.y = 0.f;
    float2 Br, Bg, Bb;
    Br.x = fk.x*fyr.x + fk.y*fyr.y; Br.y = fk.x*fyr.y - fk.y*fyr.x;
    Bg.x = fk.x*fyg.x + fk.y*fyg.y; Bg.y = fk.x*fyg.y - fk.y*fyg.x;
    Bb.x = fk.x*fyb.x + fk.y*fyb.y; Bb.y = fk.x*fyb.y - fk.y*fyb.x;
    for (int c = 0; c < 16; ++c) {
        float es = 10.f * eta[c];
        float2 wr = Fw0[((size_t)h*48 +  0 + c)*KF + k];
        float2 wg = Fw0[((size_t)h*48 + 16 + c)*KF + k];
        float2 wb = Fw0[((size_t)h*48 + 32 + c)*KF + k];
        float2 g  = Fg2[((size_t)r*16 + c)*KF + k];
        Crr += es*(wr.x*wr.x + wr.y*wr.y);
        Cgg += es*(wg.x*wg.x + wg.y*wg.y);
        Cbb += es*(wb.x*wb.x + wb.y*wb.y);
        Crg.x += es*(wr.x*wg.x + wr.y*wg.y); Crg.y += es*(wr.x*wg.y - wr.y*wg.x);
        Crb.x += es*(wr.x*wb.x + wr.y*wb.y); Crb.y += es*(wr.x*wb.y - wr.y*wb.x);
        Cgb.x += es*(wg.x*wb.x + wg.y*wb.y); Cgb.y += es*(wg.x*wb.y - wg.y*wb.x);
        Br.x += es*(wr.x*g.x + wr.y*g.y); Br.y += es*(wr.x*g.y - wr.y*g.x);
        Bg.x += es*(wg.x*g.x + wg.y*g.y); Bg.y += es*(wg.x*g.y - wg.y*g.x);
        Bb.x += es*(wb.x*g.x + wb.y*g.y); Bb.y += es*(wb.x*g.y - wb.y*g.x);
    }
    float Crg_sq = Crg.x*Crg.x + Crg.y*Crg.y;
    float Crb_sq = Crb.x*Crb.x + Crb.y*Crb.y;
    float Cgb_sq = Cgb.x*Cgb.x + Cgb.y*Cgb.y;
    float Irr = Cgg*Cbb - Cgb_sq;
    float Igg = Crr*Cbb - Crb_sq;
    float Ibb = Crr*Cgg - Crg_sq;
    float2 Irg, Irb, Igb;
    Irg.x = (Cgb.x*Crb.x + Cgb.y*Crb.y) - Cbb*Crg.x;
    Irg.y = (Cgb.x*Crb.y - Cgb.y*Crb.x) - Cbb*Crg.y;
    Irb.x = (Crg.x*Cgb.x - Crg.y*Cgb.y) - Cgg*Crb.x;
    Irb.y = (Crg.x*Cgb.y + Crg.y*Cgb.x) - Cgg*Crb.y;
    Igb.x = (Crg.x*Crb.x + Crg.y*Crb.y) - Crr*Cgb.x;
    Igb.y = (Crg.x*Crb.y - Crg.y*Crb.x) - Crr*Cgb.y;
    float tx_ = Crg.x*Cgb.x - Crg.y*Cgb.y;
    float ty_ = Crg.x*Cgb.y + Crg.y*Cgb.x;
    float den = Crr*Irr - Cgg*Crb_sq - Cbb*Crg_sq + 2.f*(tx_*Crb.x + ty_*Crb.y) + 1e-8f;
    float inv = 1.f/den;
    float2 o;
    o.x = (Irr*Br.x + (Irg.x*Bg.x - Irg.y*Bg.y) + (Irb.x*Bb.x - Irb.y*Bb.y))*inv;
    o.y = (Irr*Br.y + (Irg.x*Bg.y + Irg.y*Bg.x) + (Irb.x*Bb.y + Irb.y*Bb.x))*inv;
    Fx[((size_t)3*r + 0)*KF + k] = o;
    o.x = ((Irg.x*Br.x + Irg.y*Br.y) + Igg*Bg.x + (Igb.x*Bb.x - Igb.y*Bb.y))*inv;
    o.y = ((Irg.x*Br.y - Irg.y*Br.x) + Igg*Bg.y + (Igb.x*Bb.y + Igb.y*Bb.x))*inv;
    Fx[((size_t)3*r + 1)*KF + k] = o;
    o.x = ((Irb.x*Br.x + Irb.y*Br.y) + (Igb.x*Bg.x + Igb.y*Bg.y) + Ibb*Bb.x)*inv;
    o.y = ((Irb.x*Br.y - Irb.y*Br.x) + (Igb.x*Bg.y - Igb.y*Bg.x) + Ibb*Bb.y)*inv;
    Fx[((size_t)3*r + 2)*KF + k] = o;
}

// ---------------- output assembly ----------------
__global__ void crop_kernel(const float* __restrict__ sp, float* __restrict__ outp, int total)
{
    int idx = blockIdx.x*256 + threadIdx.x;
    if (idx >= total) return;
    int x = idx & 255; int r = idx >> 8; int y = r & 255; int plane = r >> 8;
    outp[idx] = sp[((size_t)plane*FH + (y+22))*FH + (x+22)];
}

__global__ void kcopy_kernel(const float* __restrict__ kful, float* __restrict__ outp, int total)
{
    int idx = blockIdx.x*256 + threadIdx.x;
    if (idx >= total) return;
    int rem = idx % 2025; int img = idx / 2025;
    int x = rem % 45; int y = rem / 45;
    outp[idx] = kful[(size_t)img*FH*FH + y*FH + x];
}

// =====================================================================
extern "C" void kernel_launch(void* const* d_in, const int* in_sizes, int n_in,
                              void* d_out, int out_size, void* d_ws, size_t ws_size,
                              hipStream_t stream)
{
    (void)in_sizes; (void)n_in; (void)out_size;
    const float* blurred = (const float*)d_in[0];
    const float* w0      = (const float*)d_in[1];
    const float* wsw     = (const float*)d_in[2];
    const float* biases  = (const float*)d_in[3];
    const float* kbias   = (const float*)d_in[4];
    const float* kprox   = (const float*)d_in[5];
    const float* zetas   = (const float*)d_in[6];
    const float* eta     = (const float*)d_in[7];
    float* outp = (float*)d_out;

    auto al = [](size_t b) { return (b + 255) & ~(size_t)255; };
    auto fyRegion = [&](int G) -> size_t {
        size_t ck = (size_t)10*G*16*65536*2;                         // bf16 checkpoints
        size_t ov = al((size_t)48*FH*KF*8) + 2*al((size_t)G*3*FH*KF*8);  // Fw0+FyB+FxB
        return ck > ov ? ck : ov;
    };
    auto need = [&](int G) -> size_t {
        size_t s = 0;
        s += al((size_t)FH*FH*8);                 // Ef
        s += 4*al((size_t)KP*KP*2);               // estack H/L x2
        s += 2*al((size_t)448*FH*2) + 2*al((size_t)FH*416*2);
        s += al(432*4);
        s += 2*al((size_t)G*16*65536*4);          // ping/pong fp32
        s += al(fyRegion(G));
        s += al((size_t)G*16*FH*FH*4);            // zsp
        s += 3*al((size_t)G*16*FH*KF*8);          // mid, FzFg, Ffy
        s += 3*al((size_t)G*FH*KF*8);             // Fk, kfA, kfB
        s += 2*al((size_t)G*FH*FH*4);             // kraw, kful
        s += al(256);
        return s;
    };
    int G = 4;
    while (G > 1 && need(G) > ws_size) G >>= 1;

    char* base = (char*)d_ws;
    size_t off = 0;
    auto alloc = [&](size_t bytes) -> void* {
        void* p = (void*)(base + off);
        off += (bytes + 255) & ~(size_t)255;
        return p;
    };
    float2* Ef = (float2*)alloc((size_t)FH*FH*8);
    u16* EfH = (u16*)alloc((size_t)KP*KP*2);
    u16* EfL = (u16*)alloc((size_t)KP*KP*2);
    u16* EiH = (u16*)alloc((size_t)KP*KP*2);
    u16* EiL = (u16*)alloc((size_t)KP*KP*2);
    u16* TtH = (u16*)alloc((size_t)448*FH*2);
    u16* TtL = (u16*)alloc((size_t)448*FH*2);
    u16* UtH = (u16*)alloc((size_t)FH*416*2);
    u16* UtL = (u16*)alloc((size_t)FH*416*2);
    float* w0cB = (float*)alloc(432*4);
    float* pingA = (float*)alloc((size_t)G*16*65536*4);
    float* pingB = (float*)alloc((size_t)G*16*65536*4);
    u16*   fyCk  = (u16*)alloc(fyRegion(G));
    float* zsp   = (float*)alloc((size_t)G*16*FH*FH*4);
    float2* mid  = (float2*)alloc((size_t)G*16*FH*KF*8);
    float2* FzFg = (float2*)alloc((size_t)G*16*FH*KF*8);
    float2* Ffy  = (float2*)alloc((size_t)G*16*FH*KF*8);
    float2* Fk   = (float2*)alloc((size_t)G*FH*KF*8);
    float2* kfA  = (float2*)alloc((size_t)G*FH*KF*8);
    float2* kfB  = (float2*)alloc((size_t)G*FH*KF*8);
    float*  kraw = (float*)alloc((size_t)G*FH*FH*4);
    float*  kful = (float*)alloc((size_t)G*FH*FH*4);
    // overlays inside fyCk (dead by final stage)
    char* ovl = (char*)fyCk;
    float2* Fw0B = (float2*)ovl;
    size_t o2 = al((size_t)48*FH*KF*8);
    float2* FyB = (float2*)(ovl + o2); o2 += al((size_t)G*3*FH*KF*8);
    float2* FxB = (float2*)(ovl + o2);

    init_ef_k<<<(FH*FH+255)/256, 256, 0, stream>>>(Ef);
    init_estack<<<(KP*KP+255)/256, 256, 0, stream>>>(EfH, EfL, 0);
    init_estack<<<(KP*KP+255)/256, 256, 0, stream>>>(EiH, EiL, 1);
    init_tt<<<(448*FH+255)/256, 256, 0, stream>>>(TtH, TtL);
    init_ut<<<(FH*416+255)/256, 256, 0, stream>>>(UtH, UtL);
    w0c_kernel<<<1, 64, 0, stream>>>(w0, w0cB);

    auto zg = [&](const u16* EH, const u16* EL, const float2* Bm, float2* Cm, int Ncols) {
        zgemm_col_mfma<<<dim3((Ncols+63)/64, (2*FH)/128), 256, 0, stream>>>(
            EH, EL, Bm, (float*)Cm, Ncols);
    };
    auto r2c = [&](const void* inp, int srcbf16, int inH, int inW, int oY, int oX,
                   const float* thr, float2* o, int B) {
        r2c_row_mfma<<<dim3(7, 3, B), 256, 0, stream>>>(
            inp, srcbf16, inH, inW, oY, oX, thr, TtH, TtL, (float*)o, B);
    };
    auto c2r = [&](const float2* Ain, float* o, int B) {
        c2r_row_mfma<<<dim3(6, 3, B), 256, 0, stream>>>(
            (const float*)Ain, UtH, UtL, o, B);
    };

    const size_t CKL = (size_t)G*16*65536;   // one ck layer (u16 elements)
    const int N1 = G*16*KF, N2 = G*KF, N3 = G*3*KF;
    const int totS = G*16*FH*KF, totK = G*FH*KF;

    for (int g0 = 0; g0 < 4; g0 += G) {
        const float* img = blurred + (size_t)g0*3*65536;

        // forward conv chain: fp32 ping-pong + bf16 checkpoints
        conv3x3_kernel<<<dim3(16,16,G), 256, 0, stream>>>(
            img, w0cB, pingA, fyCk, 3, 1, (size_t)3*65536);
        float* cur = pingA; float* nxt = pingB;
        for (int l = 1; l < 10; ++l) {
            conv3x3_kernel<<<dim3(16,16,G), 256, 0, stream>>>(
                cur, wsw + (size_t)(l-1)*2304, nxt, fyCk + (size_t)l*CKL, 16,
                0, (size_t)16*65536);
            float* t = cur; cur = nxt; nxt = t;
        }

        // z init (circshift + threshold b0), Fz
        int totZ = G*16*FH*FH;
        zinit_kernel<<<(totZ+255)/256, 256, 0, stream>>>(fyCk + 9*CKL, biases, zsp, totZ);
        r2c(zsp, 0, FH, FH, 0, 0, nullptr, mid, G*16);
        zg(EfH, EfL, mid, FzFg, N1);

        zero_kernel<<<(G*FH*FH+255)/256, 256, 0, stream>>>(kful, G*FH*FH);
        kdelta_kernel<<<1, 64, 0, stream>>>(kful, G);

        for (int it = 0; it < 10; ++it) {
            int Lfy = 9 - it;
            r2c(fyCk + (size_t)Lfy*CKL, 1, 256, 256, 44, 44, nullptr, mid, G*16);
            zg(EfH, EfL, mid, Ffy, N1);
            r2c(kful, 0, FH, FH, 0, 0, nullptr, mid, G);
            zg(EfH, EfL, mid, Fk, N2);
            fg_kernel<<<(totS+255)/256, 256, 0, stream>>>(Ffy, FzFg, Fk, zetas, it, totS, FzFg);
            zg(EiH, EiL, FzFg, mid, N1);
            c2r(mid, zsp, G*16);                    // zsp = irfft(Fg) PRE-threshold
            r2c(zsp, 0, FH, FH, 0, 0, biases + (it+1)*16, mid, G*16);  // fused soft-threshold
            zg(EfH, EfL, mid, FzFg, N1);            // Fz_new
            knum_kernel<<<(totK+255)/256, 256, 0, stream>>>(FzFg, Ffy, Fk, kprox, it, totK, kfA);
            zg(EiH, EiL, kfA, kfB, N2);
            c2r(kfB, kraw, G);
            kupdate_kernel<<<G, 256, 0, stream>>>(kraw, kbias, it, kful);
        }

        // ---- final stage (fyCk dead; overlays live) ----
        r2c(img, 0, 256, 256, 44, 44, nullptr, mid, 3*G);
        zg(EfH, EfL, mid, FyB, N3);
        r2c(kful, 0, FH, FH, 0, 0, nullptr, mid, G);
        zg(EfH, EfL, mid, Fk, N2);
        // Fg2 = rfft(softt(zsp, b_final))
        r2c(zsp, 0, FH, FH, 0, 0, biases + 11*16, mid, G*16);
        zg(EfH, EfL, mid, FzFg, N1);
        fw0_kernel<<<(48*FH*KF+255)/256, 256, 0, stream>>>(w0cB, Ef, Fw0B);
        wiener_kernel<<<(totK+255)/256, 256, 0, stream>>>(Fk, FyB, Fw0B, FzFg, eta, G, totK, FxB);
        zg(EiH, EiL, FxB, mid, N3);
        c2r(mid, zsp, 3*G);
        int totC = G*3*65536;
        crop_kernel<<<(totC+255)/256, 256, 0, stream>>>(zsp, outp + (size_t)g0*3*65536, totC);
        int totKC = G*2025;
        kcopy_kernel<<<(totKC+255)/256, 256, 0, stream>>>(kful, outp + 786432 + g0*2025, totKC);
    }
}

// Round 10
// 13587.810 us; speedup vs baseline: 1.3245x; 1.2966x over previous
//
#include <hip/hip_runtime.h>
#include <math.h>

#define FH 384
#define KF 193
#define KP 768    // stacked real K' = 2*FH (col pass)
#define NR 386    // real row-spectrum width = 2*KF

typedef __attribute__((ext_vector_type(8))) short short8;
typedef __attribute__((ext_vector_type(4))) float f32x4;

static __device__ __forceinline__ float softt(float v, float b) {
    return copysignf(fmaxf(fabsf(v) - b, 0.f), v);
}
static __device__ __forceinline__ unsigned short bf16_rn(float v) {
    unsigned u = __float_as_uint(v);
    unsigned r = (u + 0x7FFFu + ((u >> 16) & 1u)) >> 16;
    return (unsigned short)r;
}
static __device__ __forceinline__ float bf16_to_f(unsigned short h) {
    return __uint_as_float(((unsigned)h) << 16);
}

// ---------------- tables ----------------
__global__ void init_ef_k(float2* Ef) {
    int idx = blockIdx.x * 256 + threadIdx.x;
    if (idx >= FH * FH) return;
    int h = idx / FH, j = idx % FH;
    int m = (h * j) % FH;
    float th = (float)(6.283185307179586 / FH) * (float)m;
    float2 v; v.x = cosf(th); v.y = -sinf(th);
    Ef[idx] = v;
}

// stacked real DFT matrix for MFMA col pass (A-operand), bf16 hi/lo
__global__ void init_estack(unsigned short* __restrict__ H, unsigned short* __restrict__ L, int inv)
{
    int idx = blockIdx.x * 256 + threadIdx.x;
    if (idx >= KP * KP) return;
    int gm = idx / KP, kp = idx % KP;
    int m = gm >> 1, comp = gm & 1;
    int t = kp >> 1, ri = kp & 1;
    int mm = (m * t) % FH;
    float th = (float)(6.283185307179586 / FH) * (float)mm;
    float c = cosf(th), s = sinf(th);
    float er, ei;
    if (inv) { er = c * (1.f/FH); ei = s * (1.f/FH); }
    else     { er = c;            ei = -s; }
    float v;
    if (comp == 0) v = (ri == 0) ? er : -ei;
    else           v = (ri == 0) ? ei :  er;
    unsigned short h = bf16_rn(v);
    H[idx] = h;
    L[idx] = bf16_rn(v - bf16_to_f(h));
}

// r2c row-pass B-table, transposed: Tt[n][w], n=2*kf+ri (448 rows, zero pad)
__global__ void init_tt(unsigned short* __restrict__ H, unsigned short* __restrict__ L)
{
    int idx = blockIdx.x * 256 + threadIdx.x;
    if (idx >= 448 * FH) return;
    int n = idx / FH, w = idx % FH;
    float v = 0.f;
    if (n < NR) {
        int kf = n >> 1, ri = n & 1;
        int m = (w * kf) % FH;
        float th = (float)(6.283185307179586 / FH) * (float)m;
        v = ri ? -sinf(th) : cosf(th);
    }
    unsigned short h = bf16_rn(v);
    H[idx] = h;
    L[idx] = bf16_rn(v - bf16_to_f(h));
}

// c2r row-pass B-table, transposed: Ut[x][kp], kp=2*k+ri (416 cols, zero pad)
__global__ void init_ut(unsigned short* __restrict__ H, unsigned short* __restrict__ L)
{
    int idx = blockIdx.x * 256 + threadIdx.x;
    if (idx >= FH * 416) return;
    int x = idx / 416, kp = idx % 416;
    float v = 0.f;
    if (kp < NR) {
        int k = kp >> 1, ri = kp & 1;
        float ck = (k == 0 || k == FH/2) ? (1.f/FH) : (2.f/FH);
        int m = (k * x) % FH;
        float th = (float)(6.283185307179586 / FH) * (float)m;
        v = ri ? -ck*sinf(th) : ck*cosf(th);
    }
    unsigned short h = bf16_rn(v);
    H[idx] = h;
    L[idx] = bf16_rn(v - bf16_to_f(h));
}

// ---------------- w0 centering ----------------
__global__ void w0c_kernel(const float* __restrict__ w0, float* __restrict__ w0c) {
    int t = threadIdx.x;
    if (t < 48) {
        float m = 0.f;
        for (int d = 0; d < 9; ++d) m += w0[t*9+d];
        m *= (1.f/9.f);
        for (int d = 0; d < 9; ++d) w0c[t*9+d] = w0[t*9+d] - m;
    }
}

// ---------------- 3x3 conv (XLA cross-correlation, SAME), blockIdx.z = image ----------------
__global__ __launch_bounds__(256) void conv3x3_kernel(
    const float* __restrict__ inp0, const float* __restrict__ w,
    float* __restrict__ outp0, int Cin, int flip,
    size_t inImgStride, size_t outImgStride)
{
    const float* inp  = inp0  + (size_t)blockIdx.z * inImgStride;
    float*       outp = outp0 + (size_t)blockIdx.z * outImgStride;
    __shared__ float tile[18][19];
    __shared__ float wl[16*16*9];
    int x0 = blockIdx.x * 16, y0 = blockIdx.y * 16;
    int t = threadIdx.x;
    int tx = t & 15, ty = t >> 4;
    int nw = 16 * Cin * 9;
    for (int i = t; i < nw; i += 256) {
        int d = i % 9;
        wl[i] = flip ? w[i + 8 - 2*d] : w[i];
    }
    float acc[16];
#pragma unroll
    for (int co = 0; co < 16; ++co) acc[co] = 0.f;
    for (int ci = 0; ci < Cin; ++ci) {
        __syncthreads();
        for (int i = t; i < 18*18; i += 256) {
            int yy = i / 18, xx = i % 18;
            int gy = y0 - 1 + yy, gx = x0 - 1 + xx;
            float v = 0.f;
            if (gy >= 0 && gy < 256 && gx >= 0 && gx < 256)
                v = inp[((size_t)ci*256 + gy)*256 + gx];
            tile[yy][xx] = v;
        }
        __syncthreads();
        float v[9];
#pragma unroll
        for (int dy = 0; dy < 3; dy++)
#pragma unroll
            for (int dx = 0; dx < 3; dx++) v[dy*3+dx] = tile[ty+dy][tx+dx];
#pragma unroll
        for (int co = 0; co < 16; co++) {
            const float* wp = &wl[(co*Cin+ci)*9];
            acc[co] += v[0]*wp[0]+v[1]*wp[1]+v[2]*wp[2]
                     + v[3]*wp[3]+v[4]*wp[4]+v[5]*wp[5]
                     + v[6]*wp[6]+v[7]*wp[7]+v[8]*wp[8];
        }
    }
#pragma unroll
    for (int co = 0; co < 16; co++)
        outp[((size_t)co*256 + (y0+ty))*256 + (x0+tx)] = acc[co];
}

// ---------------- z init: circshift(22,22) of padded fy9 + soft threshold ------
__global__ void zinit_kernel(const float* __restrict__ fy9, const float* __restrict__ b0,
                             float* __restrict__ z, int total)
{
    int idx = blockIdx.x*256 + threadIdx.x;
    if (idx >= total) return;
    int x = idx % FH; int r = idx / FH; int y = r % FH; int plane = r / FH;
    int c = plane & 15;
    int Y = y + 22; if (Y >= FH) Y -= FH;
    int X = x + 22; if (X >= FH) X -= FH;
    int yy = Y - 44, xx = X - 44;
    float v = 0.f;
    if (yy >= 0 && yy < 256 && xx >= 0 && xx < 256)
        v = fy9[((size_t)plane*256 + yy)*256 + xx];
    z[idx] = softt(v, b0[c]);
}

// ---------------- MFMA row pass R2C ----------------
// grid (7, 3, B). Data staged as A-frags (hi/lo, fused softt); table = B-operand from global.
__global__ __launch_bounds__(256) void r2c_row_mfma(
    const float* __restrict__ inp, int inH, int inW, int offY, int offX,
    const float* __restrict__ thr,
    const unsigned short* __restrict__ TtH, const unsigned short* __restrict__ TtL,
    float* __restrict__ outp, int B)
{
    __shared__ unsigned short AhS[8*64*8];
    __shared__ unsigned short AlS[8*64*8];
    int col0 = blockIdx.x * 64;
    int y0   = blockIdx.y * 128;
    int plane = blockIdx.z;
    int tid = threadIdx.x;
    int wave = tid >> 6, lane = tid & 63;
    int lm = lane & 15, lq = lane >> 4;
    f32x4 acc[2][4];
#pragma unroll
    for (int mi = 0; mi < 2; ++mi)
#pragma unroll
        for (int nj = 0; nj < 4; ++nj) acc[mi][nj] = (f32x4){0.f,0.f,0.f,0.f};
    float bthr = thr ? thr[plane & 15] : 0.f;
    const float* inpP = inp + (size_t)plane*inH*inW;
    int ktlo = (offX >> 5) << 5;
    int kthi = offX + inW;
    for (int kt = ktlo; kt < kthi; kt += 32) {
        // stage 128 rows x 32 k, hi/lo, fragment order
#pragma unroll
        for (int s = 0; s < 4; ++s) {
            int slot = tid + s*256;
            int r = slot >> 3, kq = slot & 7;
            int yy = y0 + r - offY;
            float v[4];
#pragma unroll
            for (int d = 0; d < 4; ++d) {
                int xx = kt + kq*4 + d - offX;
                float t = 0.f;
                if (yy >= 0 && yy < inH && xx >= 0 && xx < inW)
                    t = inpP[(size_t)yy*inW + xx];
                if (thr) t = softt(t, bthr);
                v[d] = t;
            }
            unsigned short h0 = bf16_rn(v[0]), h1 = bf16_rn(v[1]);
            unsigned short h2 = bf16_rn(v[2]), h3 = bf16_rn(v[3]);
            unsigned short l0 = bf16_rn(v[0] - bf16_to_f(h0));
            unsigned short l1 = bf16_rn(v[1] - bf16_to_f(h1));
            unsigned short l2 = bf16_rn(v[2] - bf16_to_f(h2));
            unsigned short l3 = bf16_rn(v[3] - bf16_to_f(h3));
            int base = ((r >> 4)*64 + (r & 15) + 16*(kq >> 1))*8 + (kq & 1)*4;
            uint2 hp, lp;
            hp.x = (unsigned)h0 | ((unsigned)h1 << 16);
            hp.y = (unsigned)h2 | ((unsigned)h3 << 16);
            lp.x = (unsigned)l0 | ((unsigned)l1 << 16);
            lp.y = (unsigned)l2 | ((unsigned)l3 << 16);
            *(uint2*)&AhS[base] = hp;
            *(uint2*)&AlS[base] = lp;
        }
        __syncthreads();
        short8 Ah[2], Al[2];
#pragma unroll
        for (int mi = 0; mi < 2; ++mi) {
            Ah[mi] = *(const short8*)&AhS[((wave*2 + mi)*64 + lane)*8];
            Al[mi] = *(const short8*)&AlS[((wave*2 + mi)*64 + lane)*8];
        }
#pragma unroll
        for (int nj = 0; nj < 4; ++nj) {
            size_t toff = (size_t)(col0 + nj*16 + lm)*FH + kt + lq*8;
            short8 Bh = *(const short8*)(TtH + toff);
            short8 Bl = *(const short8*)(TtL + toff);
#pragma unroll
            for (int mi = 0; mi < 2; ++mi) {
                acc[mi][nj] = __builtin_amdgcn_mfma_f32_16x16x32_bf16(Ah[mi], Bh, acc[mi][nj], 0, 0, 0);
                acc[mi][nj] = __builtin_amdgcn_mfma_f32_16x16x32_bf16(Ah[mi], Bl, acc[mi][nj], 0, 0, 0);
                acc[mi][nj] = __builtin_amdgcn_mfma_f32_16x16x32_bf16(Al[mi], Bh, acc[mi][nj], 0, 0, 0);
            }
        }
        __syncthreads();
    }
#pragma unroll
    for (int mi = 0; mi < 2; ++mi) {
#pragma unroll
        for (int nj = 0; nj < 4; ++nj) {
            int n = col0 + nj*16 + lm;
            if (n < NR) {
#pragma unroll
                for (int rr = 0; rr < 4; ++rr) {
                    int y = y0 + wave*32 + mi*16 + lq*4 + rr;
                    outp[((size_t)y*B + plane)*NR + n] = acc[mi][nj][rr];
                }
            }
        }
    }
}

// ---------------- MFMA row pass C2R ----------------
// grid (6, 3, B). A' = real view of spectrum rows (386 wide); Ut padded to 416.
__global__ __launch_bounds__(256) void c2r_row_mfma(
    const float* __restrict__ Aflat,
    const unsigned short* __restrict__ UtH, const unsigned short* __restrict__ UtL,
    float* __restrict__ outp, int B)
{
    __shared__ unsigned short AhS[8*64*8];
    __shared__ unsigned short AlS[8*64*8];
    int col0 = blockIdx.x * 64;
    int y0   = blockIdx.y * 128;
    int plane = blockIdx.z;
    int tid = threadIdx.x;
    int wave = tid >> 6, lane = tid & 63;
    int lm = lane & 15, lq = lane >> 4;
    f32x4 acc[2][4];
#pragma unroll
    for (int mi = 0; mi < 2; ++mi)
#pragma unroll
        for (int nj = 0; nj < 4; ++nj) acc[mi][nj] = (f32x4){0.f,0.f,0.f,0.f};
    for (int kt = 0; kt < 416; kt += 32) {
#pragma unroll
        for (int s = 0; s < 4; ++s) {
            int slot = tid + s*256;
            int r = slot >> 3, kq = slot & 7;
            size_t rowb = ((size_t)(y0 + r)*B + plane)*NR;
            float v[4];
#pragma unroll
            for (int d = 0; d < 4; ++d) {
                int kp = kt + kq*4 + d;
                v[d] = (kp < NR) ? Aflat[rowb + kp] : 0.f;
            }
            unsigned short h0 = bf16_rn(v[0]), h1 = bf16_rn(v[1]);
            unsigned short h2 = bf16_rn(v[2]), h3 = bf16_rn(v[3]);
            unsigned short l0 = bf16_rn(v[0] - bf16_to_f(h0));
            unsigned short l1 = bf16_rn(v[1] - bf16_to_f(h1));
            unsigned short l2 = bf16_rn(v[2] - bf16_to_f(h2));
            unsigned short l3 = bf16_rn(v[3] - bf16_to_f(h3));
            int base = ((r >> 4)*64 + (r & 15) + 16*(kq >> 1))*8 + (kq & 1)*4;
            uint2 hp, lp;
            hp.x = (unsigned)h0 | ((unsigned)h1 << 16);
            hp.y = (unsigned)h2 | ((unsigned)h3 << 16);
            lp.x = (unsigned)l0 | ((unsigned)l1 << 16);
            lp.y = (unsigned)l2 | ((unsigned)l3 << 16);
            *(uint2*)&AhS[base] = hp;
            *(uint2*)&AlS[base] = lp;
        }
        __syncthreads();
        short8 Ah[2], Al[2];
#pragma unroll
        for (int mi = 0; mi < 2; ++mi) {
            Ah[mi] = *(const short8*)&AhS[((wave*2 + mi)*64 + lane)*8];
            Al[mi] = *(const short8*)&AlS[((wave*2 + mi)*64 + lane)*8];
        }
#pragma unroll
        for (int nj = 0; nj < 4; ++nj) {
            size_t toff = (size_t)(col0 + nj*16 + lm)*416 + kt + lq*8;
            short8 Bh = *(const short8*)(UtH + toff);
            short8 Bl = *(const short8*)(UtL + toff);
#pragma unroll
            for (int mi = 0; mi < 2; ++mi) {
                acc[mi][nj] = __builtin_amdgcn_mfma_f32_16x16x32_bf16(Ah[mi], Bh, acc[mi][nj], 0, 0, 0);
                acc[mi][nj] = __builtin_amdgcn_mfma_f32_16x16x32_bf16(Ah[mi], Bl, acc[mi][nj], 0, 0, 0);
                acc[mi][nj] = __builtin_amdgcn_mfma_f32_16x16x32_bf16(Al[mi], Bh, acc[mi][nj], 0, 0, 0);
            }
        }
        __syncthreads();
    }
#pragma unroll
    for (int mi = 0; mi < 2; ++mi) {
#pragma unroll
        for (int nj = 0; nj < 4; ++nj) {
            int x = col0 + nj*16 + lm;
#pragma unroll
            for (int rr = 0; rr < 4; ++rr) {
                int y = y0 + wave*32 + mi*16 + lq*4 + rr;
                outp[((size_t)plane*FH + y)*FH + x] = acc[mi][nj][rr];
            }
        }
    }
}

// ---------------- MFMA col pass: C = E·B (complex), stacked-real bf16x3 ----------------
__global__ __launch_bounds__(256) void zgemm_col_mfma(
    const unsigned short* __restrict__ EH, const unsigned short* __restrict__ EL,
    const float2* __restrict__ Bm, float* __restrict__ Cm, int N)
{
    __shared__ unsigned short BhS[4*64*8];
    __shared__ unsigned short BlS[4*64*8];
    int col0 = blockIdx.x * 64;
    int row0 = blockIdx.y * 128;
    int tid = threadIdx.x;
    int wave = tid >> 6, lane = tid & 63;
    int lm = lane & 15, lq = lane >> 4;
    f32x4 acc[2][4];
#pragma unroll
    for (int mi = 0; mi < 2; ++mi)
#pragma unroll
        for (int nj = 0; nj < 4; ++nj) acc[mi][nj] = (f32x4){0.f,0.f,0.f,0.f};
    int arow0 = row0 + wave*32 + lm;
    for (int kt = 0; kt < KP; kt += 32) {
        int tbase = kt >> 1;
#pragma unroll
        for (int s = 0; s < 2; ++s) {
            int slot = tid + s*256;
            int pair = slot >> 6;
            int n    = slot & 63;
            int gn   = col0 + n;
            int t0   = tbase + pair*2;
            float2 v0, v1;
            v0.x = v0.y = v1.x = v1.y = 0.f;
            if (gn < N) {
                v0 = Bm[(size_t)t0*N + gn];
                v1 = Bm[(size_t)(t0+1)*N + gn];
            }
            unsigned short h0 = bf16_rn(v0.x), h1 = bf16_rn(v0.y);
            unsigned short h2 = bf16_rn(v1.x), h3 = bf16_rn(v1.y);
            unsigned short l0 = bf16_rn(v0.x - bf16_to_f(h0));
            unsigned short l1 = bf16_rn(v0.y - bf16_to_f(h1));
            unsigned short l2 = bf16_rn(v1.x - bf16_to_f(h2));
            unsigned short l3 = bf16_rn(v1.y - bf16_to_f(h3));
            int ntile = n >> 4, n0 = n & 15;
            int lrow  = (pair >> 1)*16 + n0;
            int base  = (ntile*64 + lrow)*8 + (pair & 1)*4;
            uint2 hp, lp;
            hp.x = (unsigned)h0 | ((unsigned)h1 << 16);
            hp.y = (unsigned)h2 | ((unsigned)h3 << 16);
            lp.x = (unsigned)l0 | ((unsigned)l1 << 16);
            lp.y = (unsigned)l2 | ((unsigned)l3 << 16);
            *(uint2*)&BhS[base] = hp;
            *(uint2*)&BlS[base] = lp;
        }
        __syncthreads();
        short8 Ah[2], Al[2];
#pragma unroll
        for (int mi = 0; mi < 2; ++mi) {
            size_t aoff = (size_t)(arow0 + mi*16)*KP + kt + lq*8;
            Ah[mi] = *(const short8*)(EH + aoff);
            Al[mi] = *(const short8*)(EL + aoff);
        }
#pragma unroll
        for (int nj = 0; nj < 4; ++nj) {
            short8 Bh = *(const short8*)&BhS[(nj*64 + lane)*8];
            short8 Bl = *(const short8*)&BlS[(nj*64 + lane)*8];
#pragma unroll
            for (int mi = 0; mi < 2; ++mi) {
                acc[mi][nj] = __builtin_amdgcn_mfma_f32_16x16x32_bf16(Ah[mi], Bh, acc[mi][nj], 0, 0, 0);
                acc[mi][nj] = __builtin_amdgcn_mfma_f32_16x16x32_bf16(Ah[mi], Bl, acc[mi][nj], 0, 0, 0);
                acc[mi][nj] = __builtin_amdgcn_mfma_f32_16x16x32_bf16(Al[mi], Bh, acc[mi][nj], 0, 0, 0);
            }
        }
        __syncthreads();
    }
#pragma unroll
    for (int mi = 0; mi < 2; ++mi) {
#pragma unroll
        for (int nj = 0; nj < 4; ++nj) {
            int coln = col0 + nj*16 + lm;
            if (coln < N) {
#pragma unroll
                for (int r = 0; r < 4; ++r) {
                    int row = row0 + wave*32 + mi*16 + lq*4 + r;
                    Cm[((size_t)(row >> 1)*N + coln)*2 + (row & 1)] = acc[mi][nj][r];
                }
            }
        }
    }
}

// ---------------- elementwise frequency-domain updates (G images) ----------------
__global__ void fg_kernel(const float2* __restrict__ Ffy, const float2* __restrict__ Fz,
                          const float2* __restrict__ Fk, const float* __restrict__ zetas,
                          int L, int total, float2* __restrict__ Fg)
{
    int idx = blockIdx.x*256 + threadIdx.x;
    if (idx >= total) return;
    int k = idx % KF; int r = idx / KF;
    int c = r & 15; int hi = r >> 4;
    float zeta = 10.f * zetas[L*16 + c];
    float2 fk = Fk[(size_t)hi*KF + k];
    float2 fy = Ffy[idx];
    float2 fz = Fz[idx];
    float nx = zeta*(fk.x*fy.x + fk.y*fy.y) + fz.x;
    float ny = zeta*(fk.x*fy.y - fk.y*fy.x) + fz.y;
    float den = zeta*(fk.x*fk.x + fk.y*fk.y) + 1.f + 1e-8f;
    float inv = 1.f/den;
    float2 o; o.x = nx*inv; o.y = ny*inv;
    Fg[idx] = o;
}

__global__ void knum_kernel(const float2* __restrict__ Fz, const float2* __restrict__ Ffy,
                            const float2* __restrict__ Fk, const float* __restrict__ kprox,
                            int L, int total, float2* __restrict__ outk)
{
    int idx = blockIdx.x*256 + threadIdx.x;
    if (idx >= total) return;
    int k = idx % KF; int r = idx / KF;
    float zk = kprox[L];
    float s1x = 0.f, s1y = 0.f, s2 = 0.f;
    for (int c = 0; c < 16; ++c) {
        size_t bi = ((size_t)r*16 + c)*KF + k;
        float2 fz = Fz[bi], fy = Ffy[bi];
        s1x += fz.x*fy.x + fz.y*fy.y;
        s1y += fz.x*fy.y - fz.y*fy.x;
        s2  += fz.x*fz.x + fz.y*fz.y;
    }
    float2 fk = Fk[idx];
    float nx = zk*s1x + fk.x, ny = zk*s1y + fk.y;
    float den = zk*s2 + 1.f + 1e-8f;
    float inv = 1.f/den;
    float2 o; o.x = nx*inv; o.y = ny*inv;
    outk[idx] = o;
}

// ---------------- kernel (blur-kernel) update ----------------
__device__ __forceinline__ void lse_comb(float& m, float& s, float m2, float s2)
{
    if (m2 > m) { s = s * expf(m - m2) + s2; m = m2; }
    else        { s = s + s2 * expf(m2 - m); }
}

__global__ __launch_bounds__(256) void lse_part_kernel(const float* __restrict__ kraw0,
                                                       float2* __restrict__ parts)
{
    int img = blockIdx.y;
    const float* kraw = kraw0 + (size_t)img*FH*FH;
    int b = blockIdx.x, t = threadIdx.x;
    float m = -1e30f, s = 0.f;
    for (int i = b*256 + t; i < FH*FH; i += 64*256) {
        float v = 100.f * kraw[i];
        lse_comb(m, s, v, 1.f);
    }
    __shared__ float sm[256], ss[256];
    sm[t] = m; ss[t] = s;
    __syncthreads();
    for (int st = 128; st > 0; st >>= 1) {
        if (t < st) {
            float mm = sm[t], sc = ss[t];
            lse_comb(mm, sc, sm[t+st], ss[t+st]);
            sm[t] = mm; ss[t] = sc;
        }
        __syncthreads();
    }
    if (t == 0) { float2 o; o.x = sm[0]; o.y = ss[0]; parts[img*64 + b] = o; }
}

__global__ void lse_final_kernel(const float2* __restrict__ parts, float* __restrict__ kmaxB)
{
    int img = blockIdx.x;
    int t = threadIdx.x;
    __shared__ float sm[64], ss[64];
    float2 p = parts[img*64 + t];
    sm[t] = p.x; ss[t] = p.y;
    __syncthreads();
    for (int st = 32; st > 0; st >>= 1) {
        if (t < st) {
            float mm = sm[t], sc = ss[t];
            lse_comb(mm, sc, sm[t+st], ss[t+st]);
            sm[t] = mm; ss[t] = sc;
        }
        __syncthreads();
    }
    if (t == 0) kmaxB[img] = (sm[0] + logf(ss[0])) * 0.01f;
}

__global__ void zero_kernel(float* __restrict__ p, int n)
{
    int i = blockIdx.x*256 + threadIdx.x;
    if (i < n) p[i] = 0.f;
}

__global__ void kdelta_kernel(float* __restrict__ kful, int G)
{
    int t = threadIdx.x;
    if (t < G) kful[(size_t)t*FH*FH + 22*FH + 22] = 1.f;
}

__global__ __launch_bounds__(256) void knew_kernel(const float* __restrict__ kraw0,
    const float* __restrict__ kmax, const float* __restrict__ kb, int L,
    float* __restrict__ kful0)
{
    int img = blockIdx.x;
    const float* kraw = kraw0 + (size_t)img*FH*FH;
    float*       kful = kful0 + (size_t)img*FH*FH;
    int t = threadIdx.x;
    float thr = 0.01f * kb[L] * kmax[img];
    float vs[8]; float loc = 0.f;
#pragma unroll
    for (int ii = 0; ii < 8; ++ii) {
        int i = t + ii*256;
        float v = 0.f;
        if (i < 45*45) {
            int y = i/45, x = i - y*45;
            v = fmaxf(kraw[y*FH + x] - thr, 0.f);
        }
        vs[ii] = v; loc += v;
    }
    __shared__ float sr[256];
    sr[t] = loc; __syncthreads();
    for (int st = 128; st > 0; st >>= 1) { if (t < st) sr[t] += sr[t+st]; __syncthreads(); }
    float den = sr[0] + 1e-8f;
#pragma unroll
    for (int ii = 0; ii < 8; ++ii) {
        int i = t + ii*256;
        if (i < 45*45) {
            int y = i/45, x = i - y*45;
            float v = vs[ii] + ((y == 22 && x == 22) ? 1e-8f : 0.f);
            kful[y*FH + x] = v / den;
        }
    }
}

// ---------------- Fw0 (direct 9-term DFT of shifted 3x3), image-independent ----------------
__global__ void fw0_kernel(const float* __restrict__ w0c, const float2* __restrict__ Ef,
                           float2* __restrict__ Fw0)
{
    int idx = blockIdx.x*256 + threadIdx.x;
    if (idx >= 48*FH*KF) return;
    int k = idx % KF; int r = idx / KF;
    int c = r & 15; int r2 = r >> 4;
    int ci = r2 % 3; int h = r2 / 3;
    float accx = 0.f, accy = 0.f;
#pragma unroll
    for (int ky = 0; ky < 3; ++ky) {
        int a1 = ky - 1; if (a1 < 0) a1 += FH;
        float2 e1 = Ef[h*FH + a1];
#pragma unroll
        for (int kx = 0; kx < 3; ++kx) {
            int a2 = kx - 1; if (a2 < 0) a2 += FH;
            float2 e2 = Ef[k*FH + a2];
            float wv = w0c[((c*3 + ci)*3 + ky)*3 + kx];
            float tr = e1.x*e2.x - e1.y*e2.y;
            float ti = e1.x*e2.y + e1.y*e2.x;
            accx += wv*tr; accy += wv*ti;
        }
    }
    float2 o; o.x = accx; o.y = accy;
    Fw0[idx] = o;
}

// ---------------- final per-bin 3x3 Hermitian Wiener solve (G images) ----------------
__global__ void wiener_kernel(const float2* __restrict__ Fk, const float2* __restrict__ Fy,
    const float2* __restrict__ Fw0, const float2* __restrict__ Fg2,
    const float* __restrict__ eta, int G, int total, float2* __restrict__ Fx)
{
    int idx = blockIdx.x*256 + threadIdx.x;
    if (idx >= total) return;
    int k = idx % KF; int r = idx / KF;
    int h = r / G;
    float2 fk = Fk[idx];
    float fksq = fk.x*fk.x + fk.y*fk.y;
    float2 fyr = Fy[((size_t)3*r + 0)*KF + k];
    float2 fyg = Fy[((size_t)3*r + 1)*KF + k];
    float2 fyb = Fy[((size_t)3*r + 2)*KF + k];
    float Crr = fksq, Cgg = fksq, Cbb = fksq;
    float2 Crg, Crb, Cgb;
    Crg.x = Crg.y = Crb.x = Crb.y = Cgb.x = Cgb.y = 0.f;
    float2 Br, Bg, Bb;
    Br.x = fk.x*fyr.x + fk.y*fyr.y; Br.y = fk.x*fyr.y - fk.y*fyr.x;
    Bg.x = fk.x*fyg.x + fk.y*fyg.y; Bg.y = fk.x*fyg.y - fk.y*fyg.x;
    Bb.x = fk.x*fyb.x + fk.y*fyb.y; Bb.y = fk.x*fyb.y - fk.y*fyb.x;
    for (int c = 0; c < 16; ++c) {
        float es = 10.f * eta[c];
        float2 wr = Fw0[((size_t)h*48 +  0 + c)*KF + k];
        float2 wg = Fw0[((size_t)h*48 + 16 + c)*KF + k];
        float2 wb = Fw0[((size_t)h*48 + 32 + c)*KF + k];
        float2 g  = Fg2[((size_t)r*16 + c)*KF + k];
        Crr += es*(wr.x*wr.x + wr.y*wr.y);
        Cgg += es*(wg.x*wg.x + wg.y*wg.y);
        Cbb += es*(wb.x*wb.x + wb.y*wb.y);
        Crg.x += es*(wr.x*wg.x + wr.y*wg.y); Crg.y += es*(wr.x*wg.y - wr.y*wg.x);
        Crb.x += es*(wr.x*wb.x + wr.y*wb.y); Crb.y += es*(wr.x*wb.y - wr.y*wb.x);
        Cgb.x += es*(wg.x*wb.x + wg.y*wb.y); Cgb.y += es*(wg.x*wb.y - wg.y*wb.x);
        Br.x += es*(wr.x*g.x + wr.y*g.y); Br.y += es*(wr.x*g.y - wr.y*g.x);
        Bg.x += es*(wg.x*g.x + wg.y*g.y); Bg.y += es*(wg.x*g.y - wg.y*g.x);
        Bb.x += es*(wb.x*g.x + wb.y*g.y); Bb.y += es*(wb.x*g.y - wb.y*g.x);
    }
    float Crg_sq = Crg.x*Crg.x + Crg.y*Crg.y;
    float Crb_sq = Crb.x*Crb.x + Crb.y*Crb.y;
    float Cgb_sq = Cgb.x*Cgb.x + Cgb.y*Cgb.y;
    float Irr = Cgg*Cbb - Cgb_sq;
    float Igg = Crr*Cbb - Crb_sq;
    float Ibb = Crr*Cgg - Crg_sq;
    float2 Irg, Irb, Igb;
    Irg.x = (Cgb.x*Crb.x + Cgb.y*Crb.y) - Cbb*Crg.x;
    Irg.y = (Cgb.x*Crb.y - Cgb.y*Crb.x) - Cbb*Crg.y;
    Irb.x = (Crg.x*Cgb.x - Crg.y*Cgb.y) - Cgg*Crb.x;
    Irb.y = (Crg.x*Cgb.y + Crg.y*Cgb.x) - Cgg*Crb.y;
    Igb.x = (Crg.x*Crb.x + Crg.y*Crb.y) - Crr*Cgb.x;
    Igb.y = (Crg.x*Crb.y - Crg.y*Crb.x) - Crr*Cgb.y;
    float tx_ = Crg.x*Cgb.x - Crg.y*Cgb.y;
    float ty_ = Crg.x*Cgb.y + Crg.y*Cgb.x;
    float den = Crr*Irr - Cgg*Crb_sq - Cbb*Crg_sq + 2.f*(tx_*Crb.x + ty_*Crb.y) + 1e-8f;
    float inv = 1.f/den;
    float2 o;
    o.x = (Irr*Br.x + (Irg.x*Bg.x - Irg.y*Bg.y) + (Irb.x*Bb.x - Irb.y*Bb.y))*inv;
    o.y = (Irr*Br.y + (Irg.x*Bg.y + Irg.y*Bg.x) + (Irb.x*Bb.y + Irb.y*Bb.x))*inv;
    Fx[((size_t)3*r + 0)*KF + k] = o;
    o.x = ((Irg.x*Br.x + Irg.y*Br.y) + Igg*Bg.x + (Igb.x*Bb.x - Igb.y*Bb.y))*inv;
    o.y = ((Irg.x*Br.y - Irg.y*Br.x) + Igg*Bg.y + (Igb.x*Bb.y + Igb.y*Bb.x))*inv;
    Fx[((size_t)3*r + 1)*KF + k] = o;
    o.x = ((Irb.x*Br.x + Irb.y*Br.y) + (Igb.x*Bg.x + Igb.y*Bg.y) + Ibb*Bb.x)*inv;
    o.y = ((Irb.x*Br.y - Irb.y*Br.x) + (Igb.x*Bg.y - Igb.y*Bg.x) + Ibb*Bb.y)*inv;
    Fx[((size_t)3*r + 2)*KF + k] = o;
}

// ---------------- output assembly ----------------
__global__ void crop_kernel(const float* __restrict__ sp, float* __restrict__ outp, int total)
{
    int idx = blockIdx.x*256 + threadIdx.x;
    if (idx >= total) return;
    int x = idx & 255; int r = idx >> 8; int y = r & 255; int plane = r >> 8;
    outp[idx] = sp[((size_t)plane*FH + (y+22))*FH + (x+22)];
}

__global__ void kcopy_kernel(const float* __restrict__ kful, float* __restrict__ outp, int total)
{
    int idx = blockIdx.x*256 + threadIdx.x;
    if (idx >= total) return;
    int rem = idx % 2025; int img = idx / 2025;
    int x = rem % 45; int y = rem / 45;
    outp[idx] = kful[(size_t)img*FH*FH + y*FH + x];
}

// =====================================================================
extern "C" void kernel_launch(void* const* d_in, const int* in_sizes, int n_in,
                              void* d_out, int out_size, void* d_ws, size_t ws_size,
                              hipStream_t stream)
{
    (void)in_sizes; (void)n_in; (void)out_size;
    const float* blurred = (const float*)d_in[0];
    const float* w0      = (const float*)d_in[1];
    const float* wsw     = (const float*)d_in[2];
    const float* biases  = (const float*)d_in[3];
    const float* kbias   = (const float*)d_in[4];
    const float* kprox   = (const float*)d_in[5];
    const float* zetas   = (const float*)d_in[6];
    const float* eta     = (const float*)d_in[7];
    float* outp = (float*)d_out;

    auto al = [](size_t b) { return (b + 255) & ~(size_t)255; };
    auto need = [&](int G) -> size_t {
        size_t s = 0;
        s += al((size_t)FH*FH*8);                 // Ef
        s += 4*al((size_t)KP*KP*2);               // EfH/L, EiH/L
        s += 2*al((size_t)448*FH*2);              // Tt
        s += 2*al((size_t)FH*416*2);              // Ut
        s += al(432*4);                           // w0c
        s += al((size_t)10*G*16*65536*4);         // fyN
        s += al((size_t)G*16*FH*FH*4);            // zsp
        s += 3*al((size_t)G*16*FH*KF*8);          // mid, FzFg, Ffy
        s += 3*al((size_t)G*FH*KF*8);             // Fk, kfA, kfB
        s += 2*al((size_t)G*FH*FH*4);             // kraw, kful
        s += 2*al((size_t)G*3*FH*KF*8);           // FyB, FxB
        s += al((size_t)G*64*8) + al(256);        // lseP, kmax
        return s;
    };
    int G = 4;
    while (G > 1 && need(G) > ws_size) G >>= 1;

    char* base = (char*)d_ws;
    size_t off = 0;
    auto alloc = [&](size_t bytes) -> void* {
        void* p = (void*)(base + off);
        off += (bytes + 255) & ~(size_t)255;
        return p;
    };
    float2* Ef   = (float2*)alloc((size_t)FH*FH*8);
    unsigned short* EfH = (unsigned short*)alloc((size_t)KP*KP*2);
    unsigned short* EfL = (unsigned short*)alloc((size_t)KP*KP*2);
    unsigned short* EiH = (unsigned short*)alloc((size_t)KP*KP*2);
    unsigned short* EiL = (unsigned short*)alloc((size_t)KP*KP*2);
    unsigned short* TtH = (unsigned short*)alloc((size_t)448*FH*2);
    unsigned short* TtL = (unsigned short*)alloc((size_t)448*FH*2);
    unsigned short* UtH = (unsigned short*)alloc((size_t)FH*416*2);
    unsigned short* UtL = (unsigned short*)alloc((size_t)FH*416*2);
    float*  w0cB = (float*)alloc(432*4);
    float*  fyN  = (float*)alloc((size_t)10*G*16*65536*4);
    float*  zsp  = (float*)alloc((size_t)G*16*FH*FH*4);
    float2* mid  = (float2*)alloc((size_t)G*16*FH*KF*8);
    float2* FzFg = (float2*)alloc((size_t)G*16*FH*KF*8);
    float2* Ffy  = (float2*)alloc((size_t)G*16*FH*KF*8);
    float2* Fk   = (float2*)alloc((size_t)G*FH*KF*8);
    float2* kfA  = (float2*)alloc((size_t)G*FH*KF*8);
    float2* kfB  = (float2*)alloc((size_t)G*FH*KF*8);
    float*  kraw = (float*)alloc((size_t)G*FH*FH*4);
    float*  kful = (float*)alloc((size_t)G*FH*FH*4);
    float2* FyB  = (float2*)alloc((size_t)G*3*FH*KF*8);
    float2* FxB  = (float2*)alloc((size_t)G*3*FH*KF*8);
    float2* lseP = (float2*)alloc((size_t)G*64*8);
    float*  kmaxB= (float*)alloc(256);
    // Fw0 (28.45 MB) overlays fyN (>= 41.9 MB even at G=1) — dead by final stage
    float2* Fw0B = (float2*)fyN;

    // tables + weight prep (image-independent)
    init_ef_k<<<(FH*FH+255)/256, 256, 0, stream>>>(Ef);
    init_estack<<<(KP*KP+255)/256, 256, 0, stream>>>(EfH, EfL, 0);
    init_estack<<<(KP*KP+255)/256, 256, 0, stream>>>(EiH, EiL, 1);
    init_tt<<<(448*FH+255)/256, 256, 0, stream>>>(TtH, TtL);
    init_ut<<<(FH*416+255)/256, 256, 0, stream>>>(UtH, UtL);
    w0c_kernel<<<1, 64, 0, stream>>>(w0, w0cB);

    auto zg = [&](const unsigned short* EH, const unsigned short* EL,
                  const float2* Bm, float2* Cm, int Ncols) {
        zgemm_col_mfma<<<dim3((Ncols+63)/64, (2*FH)/128), 256, 0, stream>>>(
            EH, EL, Bm, (float*)Cm, Ncols);
    };
    auto r2c = [&](const float* inp, int inH, int inW, int oY, int oX,
                   const float* thr, float2* o, int B) {
        r2c_row_mfma<<<dim3(7, 3, B), 256, 0, stream>>>(
            inp, inH, inW, oY, oX, thr, TtH, TtL, (float*)o, B);
    };
    auto c2r = [&](const float2* Ain, float* o, int B) {
        c2r_row_mfma<<<dim3(6, 3, B), 256, 0, stream>>>(
            (const float*)Ain, UtH, UtL, o, B);
    };

    const size_t IMG16 = (size_t)16*65536;
    const size_t LAY   = (size_t)G*IMG16;

    for (int g0 = 0; g0 < 4; g0 += G) {
        const float* img = blurred + (size_t)g0*3*65536;

        // forward conv chain
        conv3x3_kernel<<<dim3(16,16,G), 256, 0, stream>>>(
            img, w0cB, fyN, 3, 1, (size_t)3*65536, IMG16);
        for (int l = 1; l < 10; ++l)
            conv3x3_kernel<<<dim3(16,16,G), 256, 0, stream>>>(
                fyN + (size_t)(l-1)*LAY, wsw + (size_t)(l-1)*2304,
                fyN + (size_t)l*LAY, 16, 0, IMG16, IMG16);

        // z init (circshift + threshold b0), Fz
        int totZ = G*16*FH*FH;
        zinit_kernel<<<(totZ+255)/256, 256, 0, stream>>>(fyN + 9*LAY, biases, zsp, totZ);
        r2c(zsp, FH, FH, 0, 0, nullptr, mid, G*16);
        zg(EfH, EfL, mid, FzFg, G*16*KF);

        // k init = delta
        zero_kernel<<<(G*FH*FH+255)/256, 256, 0, stream>>>(kful, G*FH*FH);
        kdelta_kernel<<<1, 64, 0, stream>>>(kful, G);

        int totS = G*16*FH*KF;
        int totK = G*FH*KF;
        for (int it = 0; it < 10; ++it) {
            int Lfy = 9 - it;
            r2c(fyN + (size_t)Lfy*LAY, 256, 256, 44, 44, nullptr, mid, G*16);
            zg(EfH, EfL, mid, Ffy, G*16*KF);
            r2c(kful, FH, FH, 0, 0, nullptr, mid, G);
            zg(EfH, EfL, mid, Fk, G*KF);
            fg_kernel<<<(totS+255)/256, 256, 0, stream>>>(Ffy, FzFg, Fk, zetas, it, totS, FzFg);
            zg(EiH, EiL, FzFg, mid, G*16*KF);
            c2r(mid, zsp, G*16);                    // zsp = irfft(Fg) PRE-threshold
            r2c(zsp, FH, FH, 0, 0, biases + (it+1)*16, mid, G*16);  // fused soft-threshold
            zg(EfH, EfL, mid, FzFg, G*16*KF);       // Fz_new
            knum_kernel<<<(totK+255)/256, 256, 0, stream>>>(FzFg, Ffy, Fk, kprox, it, totK, kfA);
            zg(EiH, EiL, kfA, kfB, G*KF);
            c2r(kfB, kraw, G);
            lse_part_kernel<<<dim3(64,G), 256, 0, stream>>>(kraw, lseP);
            lse_final_kernel<<<G, 64, 0, stream>>>(lseP, kmaxB);
            knew_kernel<<<G, 256, 0, stream>>>(kraw, kmaxB, kbias, it, kful);
        }

        // ---- final stage ----
        r2c(img, 256, 256, 44, 44, nullptr, mid, 3*G);
        zg(EfH, EfL, mid, FyB, 3*G*KF);
        r2c(kful, FH, FH, 0, 0, nullptr, mid, G);
        zg(EfH, EfL, mid, Fk, G*KF);
        // Fg2 = rfft(softt(zsp, b_final))
        r2c(zsp, FH, FH, 0, 0, biases + 11*16, mid, G*16);
        zg(EfH, EfL, mid, FzFg, G*16*KF);
        fw0_kernel<<<(48*FH*KF+255)/256, 256, 0, stream>>>(w0cB, Ef, Fw0B);
        wiener_kernel<<<(totK+255)/256, 256, 0, stream>>>(Fk, FyB, Fw0B, FzFg, eta, G, totK, FxB);
        zg(EiH, EiL, FxB, mid, 3*G*KF);
        c2r(mid, zsp, 3*G);
        int totC = G*3*65536;
        crop_kernel<<<(totC+255)/256, 256, 0, stream>>>(zsp, outp + (size_t)g0*3*65536, totC);
        int totKC = G*2025;
        kcopy_kernel<<<(totKC+255)/256, 256, 0, stream>>>(kful, outp + 786432 + g0*2025, totKC);
    }
}

// Round 11
// 11375.870 us; speedup vs baseline: 1.5820x; 1.1944x over previous
//
#include <hip/hip_runtime.h>
#include <math.h>

#define FH 384
#define KF 193
#define KP 768    // stacked real K' = 2*FH (col pass)
#define NR 386    // real row-spectrum width = 2*KF

typedef __attribute__((ext_vector_type(8))) short short8;
typedef __attribute__((ext_vector_type(4))) float f32x4;
typedef unsigned int u32;

static __device__ __forceinline__ float softt(float v, float b) {
    return copysignf(fmaxf(fabsf(v) - b, 0.f), v);
}
static __device__ __forceinline__ unsigned short bf16_rn(float v) {
    u32 u = __float_as_uint(v);
    u32 r = (u + 0x7FFFu + ((u >> 16) & 1u)) >> 16;
    return (unsigned short)r;
}
static __device__ __forceinline__ float bf16_to_f(unsigned short h) {
    return __uint_as_float(((u32)h) << 16);
}
// complex spectra stored as uint2: .x = H-word (bf16 re | bf16 im<<16), .y = L-word
static __device__ __forceinline__ float2 ldc(const uint2* __restrict__ S, size_t i) {
    uint2 u = S[i];
    float2 r;
    r.x = __uint_as_float((u.x & 0xffffu) << 16) + __uint_as_float((u.y & 0xffffu) << 16);
    r.y = __uint_as_float(u.x & 0xffff0000u) + __uint_as_float(u.y & 0xffff0000u);
    return r;
}
static __device__ __forceinline__ uint2 packc(float re, float im) {
    unsigned short hr = bf16_rn(re), hi = bf16_rn(im);
    unsigned short lr = bf16_rn(re - bf16_to_f(hr)), li = bf16_rn(im - bf16_to_f(hi));
    uint2 o; o.x = (u32)hr | ((u32)hi << 16); o.y = (u32)lr | ((u32)li << 16);
    return o;
}

// ---------------- tables ----------------
__global__ void init_ef_k(float2* Ef) {
    int idx = blockIdx.x * 256 + threadIdx.x;
    if (idx >= FH * FH) return;
    int h = idx / FH, j = idx % FH;
    int m = (h * j) % FH;
    float th = (float)(6.283185307179586 / FH) * (float)m;
    float2 v; v.x = cosf(th); v.y = -sinf(th);
    Ef[idx] = v;
}

// stacked real DFT matrix for MFMA col pass (A-operand), bf16 hi/lo
__global__ void init_estack(unsigned short* __restrict__ H, unsigned short* __restrict__ L, int inv)
{
    int idx = blockIdx.x * 256 + threadIdx.x;
    if (idx >= KP * KP) return;
    int gm = idx / KP, kp = idx % KP;
    int m = gm >> 1, comp = gm & 1;
    int t = kp >> 1, ri = kp & 1;
    int mm = (m * t) % FH;
    float th = (float)(6.283185307179586 / FH) * (float)mm;
    float c = cosf(th), s = sinf(th);
    float er, ei;
    if (inv) { er = c * (1.f/FH); ei = s * (1.f/FH); }
    else     { er = c;            ei = -s; }
    float v;
    if (comp == 0) v = (ri == 0) ? er : -ei;
    else           v = (ri == 0) ? ei :  er;
    unsigned short h = bf16_rn(v);
    H[idx] = h;
    L[idx] = bf16_rn(v - bf16_to_f(h));
}

// r2c row-pass B-table, transposed: Tt[n][w], n=2*kf+ri (448 rows, zero pad)
__global__ void init_tt(unsigned short* __restrict__ H, unsigned short* __restrict__ L)
{
    int idx = blockIdx.x * 256 + threadIdx.x;
    if (idx >= 448 * FH) return;
    int n = idx / FH, w = idx % FH;
    float v = 0.f;
    if (n < NR) {
        int kf = n >> 1, ri = n & 1;
        int m = (w * kf) % FH;
        float th = (float)(6.283185307179586 / FH) * (float)m;
        v = ri ? -sinf(th) : cosf(th);
    }
    unsigned short h = bf16_rn(v);
    H[idx] = h;
    L[idx] = bf16_rn(v - bf16_to_f(h));
}

// c2r row-pass B-table, transposed: Ut[x][kp], kp=2*k+ri (416 cols, zero pad)
__global__ void init_ut(unsigned short* __restrict__ H, unsigned short* __restrict__ L)
{
    int idx = blockIdx.x * 256 + threadIdx.x;
    if (idx >= FH * 416) return;
    int x = idx / 416, kp = idx % 416;
    float v = 0.f;
    if (kp < NR) {
        int k = kp >> 1, ri = kp & 1;
        float ck = (k == 0 || k == FH/2) ? (1.f/FH) : (2.f/FH);
        int m = (k * x) % FH;
        float th = (float)(6.283185307179586 / FH) * (float)m;
        v = ri ? -ck*sinf(th) : ck*cosf(th);
    }
    unsigned short h = bf16_rn(v);
    H[idx] = h;
    L[idx] = bf16_rn(v - bf16_to_f(h));
}

// ---------------- w0 centering ----------------
__global__ void w0c_kernel(const float* __restrict__ w0, float* __restrict__ w0c) {
    int t = threadIdx.x;
    if (t < 48) {
        float m = 0.f;
        for (int d = 0; d < 9; ++d) m += w0[t*9+d];
        m *= (1.f/9.f);
        for (int d = 0; d < 9; ++d) w0c[t*9+d] = w0[t*9+d] - m;
    }
}

// ---------------- 3x3 conv (XLA cross-correlation, SAME), blockIdx.z = image ----------------
__global__ __launch_bounds__(256) void conv3x3_kernel(
    const float* __restrict__ inp0, const float* __restrict__ w,
    float* __restrict__ outp0, int Cin, int flip,
    size_t inImgStride, size_t outImgStride)
{
    const float* inp  = inp0  + (size_t)blockIdx.z * inImgStride;
    float*       outp = outp0 + (size_t)blockIdx.z * outImgStride;
    __shared__ float tile[18][19];
    __shared__ float wl[16*16*9];
    int x0 = blockIdx.x * 16, y0 = blockIdx.y * 16;
    int t = threadIdx.x;
    int tx = t & 15, ty = t >> 4;
    int nw = 16 * Cin * 9;
    for (int i = t; i < nw; i += 256) {
        int d = i % 9;
        wl[i] = flip ? w[i + 8 - 2*d] : w[i];
    }
    float acc[16];
#pragma unroll
    for (int co = 0; co < 16; ++co) acc[co] = 0.f;
    for (int ci = 0; ci < Cin; ++ci) {
        __syncthreads();
        for (int i = t; i < 18*18; i += 256) {
            int yy = i / 18, xx = i % 18;
            int gy = y0 - 1 + yy, gx = x0 - 1 + xx;
            float v = 0.f;
            if (gy >= 0 && gy < 256 && gx >= 0 && gx < 256)
                v = inp[((size_t)ci*256 + gy)*256 + gx];
            tile[yy][xx] = v;
        }
        __syncthreads();
        float v[9];
#pragma unroll
        for (int dy = 0; dy < 3; dy++)
#pragma unroll
            for (int dx = 0; dx < 3; dx++) v[dy*3+dx] = tile[ty+dy][tx+dx];
#pragma unroll
        for (int co = 0; co < 16; co++) {
            const float* wp = &wl[(co*Cin+ci)*9];
            acc[co] += v[0]*wp[0]+v[1]*wp[1]+v[2]*wp[2]
                     + v[3]*wp[3]+v[4]*wp[4]+v[5]*wp[5]
                     + v[6]*wp[6]+v[7]*wp[7]+v[8]*wp[8];
        }
    }
#pragma unroll
    for (int co = 0; co < 16; co++)
        outp[((size_t)co*256 + (y0+ty))*256 + (x0+tx)] = acc[co];
}

// ---------------- z init: circshift(22,22) of padded fy9 + soft threshold ------
__global__ void zinit_kernel(const float* __restrict__ fy9, const float* __restrict__ b0,
                             float* __restrict__ z, int total)
{
    int idx = blockIdx.x*256 + threadIdx.x;
    if (idx >= total) return;
    int x = idx % FH; int r = idx / FH; int y = r % FH; int plane = r / FH;
    int c = plane & 15;
    int Y = y + 22; if (Y >= FH) Y -= FH;
    int X = x + 22; if (X >= FH) X -= FH;
    int yy = Y - 44, xx = X - 44;
    float v = 0.f;
    if (yy >= 0 && yy < 256 && xx >= 0 && xx < 256)
        v = fy9[((size_t)plane*256 + yy)*256 + xx];
    z[idx] = softt(v, b0[c]);
}

// ---------------- MFMA row pass R2C ----------------
// grid (7, 3, B). fp32 spatial in (fused softt); out = uint2 spectra [(y*B+plane)*KF+k]
__global__ __launch_bounds__(256) void r2c_row_mfma(
    const float* __restrict__ inp, int inH, int inW, int offY, int offX,
    const float* __restrict__ thr,
    const unsigned short* __restrict__ TtH, const unsigned short* __restrict__ TtL,
    uint2* __restrict__ outp, int B)
{
    __shared__ unsigned short AhS[8*64*8];
    __shared__ unsigned short AlS[8*64*8];
    int col0 = blockIdx.x * 64;
    int y0   = blockIdx.y * 128;
    int plane = blockIdx.z;
    int tid = threadIdx.x;
    int wave = tid >> 6, lane = tid & 63;
    int lm = lane & 15, lq = lane >> 4;
    f32x4 acc[2][4];
#pragma unroll
    for (int mi = 0; mi < 2; ++mi)
#pragma unroll
        for (int nj = 0; nj < 4; ++nj) acc[mi][nj] = (f32x4){0.f,0.f,0.f,0.f};
    float bthr = thr ? thr[plane & 15] : 0.f;
    const float* inpP = inp + (size_t)plane*inH*inW;
    int ktlo = (offX >> 5) << 5;
    int kthi = offX + inW;
    for (int kt = ktlo; kt < kthi; kt += 32) {
#pragma unroll
        for (int s = 0; s < 4; ++s) {
            int slot = tid + s*256;
            int r = slot >> 3, kq = slot & 7;
            int yy = y0 + r - offY;
            float v[4];
#pragma unroll
            for (int d = 0; d < 4; ++d) {
                int xx = kt + kq*4 + d - offX;
                float t = 0.f;
                if (yy >= 0 && yy < inH && xx >= 0 && xx < inW)
                    t = inpP[(size_t)yy*inW + xx];
                if (thr) t = softt(t, bthr);
                v[d] = t;
            }
            unsigned short h0 = bf16_rn(v[0]), h1 = bf16_rn(v[1]);
            unsigned short h2 = bf16_rn(v[2]), h3 = bf16_rn(v[3]);
            unsigned short l0 = bf16_rn(v[0] - bf16_to_f(h0));
            unsigned short l1 = bf16_rn(v[1] - bf16_to_f(h1));
            unsigned short l2 = bf16_rn(v[2] - bf16_to_f(h2));
            unsigned short l3 = bf16_rn(v[3] - bf16_to_f(h3));
            int base = ((r >> 4)*64 + (r & 15) + 16*(kq >> 1))*8 + (kq & 1)*4;
            uint2 hp, lp;
            hp.x = (u32)h0 | ((u32)h1 << 16);
            hp.y = (u32)h2 | ((u32)h3 << 16);
            lp.x = (u32)l0 | ((u32)l1 << 16);
            lp.y = (u32)l2 | ((u32)l3 << 16);
            *(uint2*)&AhS[base] = hp;
            *(uint2*)&AlS[base] = lp;
        }
        __syncthreads();
        short8 Ah[2], Al[2];
#pragma unroll
        for (int mi = 0; mi < 2; ++mi) {
            Ah[mi] = *(const short8*)&AhS[((wave*2 + mi)*64 + lane)*8];
            Al[mi] = *(const short8*)&AlS[((wave*2 + mi)*64 + lane)*8];
        }
#pragma unroll
        for (int nj = 0; nj < 4; ++nj) {
            size_t toff = (size_t)(col0 + nj*16 + lm)*FH + kt + lq*8;
            short8 Bh = *(const short8*)(TtH + toff);
            short8 Bl = *(const short8*)(TtL + toff);
#pragma unroll
            for (int mi = 0; mi < 2; ++mi) {
                acc[mi][nj] = __builtin_amdgcn_mfma_f32_16x16x32_bf16(Ah[mi], Bh, acc[mi][nj], 0, 0, 0);
                acc[mi][nj] = __builtin_amdgcn_mfma_f32_16x16x32_bf16(Ah[mi], Bl, acc[mi][nj], 0, 0, 0);
                acc[mi][nj] = __builtin_amdgcn_mfma_f32_16x16x32_bf16(Al[mi], Bh, acc[mi][nj], 0, 0, 0);
            }
        }
        __syncthreads();
    }
    // epilogue: pair re/im across lane^1, emit packed H/L uint2
#pragma unroll
    for (int mi = 0; mi < 2; ++mi) {
#pragma unroll
        for (int nj = 0; nj < 4; ++nj) {
            int n = col0 + nj*16 + lm;
            int k = n >> 1;
            unsigned short h[4], l[4];
#pragma unroll
            for (int rr = 0; rr < 4; ++rr) {
                float v = acc[mi][nj][rr];
                h[rr] = bf16_rn(v);
                l[rr] = bf16_rn(v - bf16_to_f(h[rr]));
            }
            u32 hx = (u32)h[0] | ((u32)h[1]<<16), hy = (u32)h[2] | ((u32)h[3]<<16);
            u32 lx = (u32)l[0] | ((u32)l[1]<<16), ly = (u32)l[2] | ((u32)l[3]<<16);
            u32 phx = __shfl_xor((int)hx, 1), phy = __shfl_xor((int)hy, 1);
            u32 plx = __shfl_xor((int)lx, 1), ply = __shfl_xor((int)ly, 1);
            if (((lm & 1) == 0) && k < KF) {
                int ybase = y0 + wave*32 + mi*16 + lq*4;
                u32 H[4], L[4];
                H[0] = (hx & 0xffffu) | (phx << 16);
                H[1] = (hx >> 16)     | (phx & 0xffff0000u);
                H[2] = (hy & 0xffffu) | (phy << 16);
                H[3] = (hy >> 16)     | (phy & 0xffff0000u);
                L[0] = (lx & 0xffffu) | (plx << 16);
                L[1] = (lx >> 16)     | (plx & 0xffff0000u);
                L[2] = (ly & 0xffffu) | (ply << 16);
                L[3] = (ly >> 16)     | (ply & 0xffff0000u);
#pragma unroll
                for (int rr = 0; rr < 4; ++rr) {
                    uint2 o; o.x = H[rr]; o.y = L[rr];
                    outp[((size_t)(ybase+rr)*B + plane)*KF + k] = o;
                }
            }
        }
    }
}

// ---------------- MFMA row pass C2R ----------------
// grid (6, 3, B). uint2 spectra in [(y*B+plane)*KF+k]; fp32 spatial out.
__global__ __launch_bounds__(256) void c2r_row_mfma(
    const uint2* __restrict__ Ain,
    const unsigned short* __restrict__ UtH, const unsigned short* __restrict__ UtL,
    float* __restrict__ outp, int B)
{
    __shared__ unsigned short AhS[8*64*8];
    __shared__ unsigned short AlS[8*64*8];
    int col0 = blockIdx.x * 64;
    int y0   = blockIdx.y * 128;
    int plane = blockIdx.z;
    int tid = threadIdx.x;
    int wave = tid >> 6, lane = tid & 63;
    int lm = lane & 15, lq = lane >> 4;
    f32x4 acc[2][4];
#pragma unroll
    for (int mi = 0; mi < 2; ++mi)
#pragma unroll
        for (int nj = 0; nj < 4; ++nj) acc[mi][nj] = (f32x4){0.f,0.f,0.f,0.f};
    for (int kt = 0; kt < 416; kt += 32) {
#pragma unroll
        for (int s = 0; s < 4; ++s) {
            int slot = tid + s*256;
            int r = slot >> 3, kq = slot & 7;
            size_t rowb = ((size_t)(y0 + r)*B + plane)*KF;
            int k0 = (kt + kq*4) >> 1;
            uint2 u0, u1;
            u0.x = u0.y = u1.x = u1.y = 0u;
            if (k0 < KF)     u0 = Ain[rowb + k0];
            if (k0 + 1 < KF) u1 = Ain[rowb + k0 + 1];
            int base = ((r >> 4)*64 + (r & 15) + 16*(kq >> 1))*8 + (kq & 1)*4;
            uint2 hp, lp;
            hp.x = u0.x; hp.y = u1.x;
            lp.x = u0.y; lp.y = u1.y;
            *(uint2*)&AhS[base] = hp;
            *(uint2*)&AlS[base] = lp;
        }
        __syncthreads();
        short8 Ah[2], Al[2];
#pragma unroll
        for (int mi = 0; mi < 2; ++mi) {
            Ah[mi] = *(const short8*)&AhS[((wave*2 + mi)*64 + lane)*8];
            Al[mi] = *(const short8*)&AlS[((wave*2 + mi)*64 + lane)*8];
        }
#pragma unroll
        for (int nj = 0; nj < 4; ++nj) {
            size_t toff = (size_t)(col0 + nj*16 + lm)*416 + kt + lq*8;
            short8 Bh = *(const short8*)(UtH + toff);
            short8 Bl = *(const short8*)(UtL + toff);
#pragma unroll
            for (int mi = 0; mi < 2; ++mi) {
                acc[mi][nj] = __builtin_amdgcn_mfma_f32_16x16x32_bf16(Ah[mi], Bh, acc[mi][nj], 0, 0, 0);
                acc[mi][nj] = __builtin_amdgcn_mfma_f32_16x16x32_bf16(Ah[mi], Bl, acc[mi][nj], 0, 0, 0);
                acc[mi][nj] = __builtin_amdgcn_mfma_f32_16x16x32_bf16(Al[mi], Bh, acc[mi][nj], 0, 0, 0);
            }
        }
        __syncthreads();
    }
#pragma unroll
    for (int mi = 0; mi < 2; ++mi) {
#pragma unroll
        for (int nj = 0; nj < 4; ++nj) {
            int x = col0 + nj*16 + lm;
#pragma unroll
            for (int rr = 0; rr < 4; ++rr) {
                int y = y0 + wave*32 + mi*16 + lq*4 + rr;
                outp[((size_t)plane*FH + y)*FH + x] = acc[mi][nj][rr];
            }
        }
    }
}

// ---------------- MFMA col pass: C = E·B (complex), stacked-real bf16x3 ----------------
// B and C are uint2 spectra (pre-split H/L) — staging has zero conversions.
__global__ __launch_bounds__(256) void zgemm_col_mfma(
    const unsigned short* __restrict__ EH, const unsigned short* __restrict__ EL,
    const uint2* __restrict__ Bm, uint2* __restrict__ Cm, int N)
{
    __shared__ unsigned short BhS[4*64*8];
    __shared__ unsigned short BlS[4*64*8];
    int col0 = blockIdx.x * 64;
    int row0 = blockIdx.y * 128;
    int tid = threadIdx.x;
    int wave = tid >> 6, lane = tid & 63;
    int lm = lane & 15, lq = lane >> 4;
    f32x4 acc[2][4];
#pragma unroll
    for (int mi = 0; mi < 2; ++mi)
#pragma unroll
        for (int nj = 0; nj < 4; ++nj) acc[mi][nj] = (f32x4){0.f,0.f,0.f,0.f};
    int arow0 = row0 + wave*32 + lm;
    for (int kt = 0; kt < KP; kt += 32) {
        int tbase = kt >> 1;
#pragma unroll
        for (int s = 0; s < 2; ++s) {
            int slot = tid + s*256;
            int pair = slot >> 6;
            int n    = slot & 63;
            int gn   = col0 + n;
            int t0   = tbase + pair*2;
            uint2 u0, u1;
            u0.x = u0.y = u1.x = u1.y = 0u;
            if (gn < N) {
                u0 = Bm[(size_t)t0*N + gn];
                u1 = Bm[(size_t)(t0+1)*N + gn];
            }
            int ntile = n >> 4, n0 = n & 15;
            int lrow  = (pair >> 1)*16 + n0;
            int base  = (ntile*64 + lrow)*8 + (pair & 1)*4;
            uint2 hp, lp;
            hp.x = u0.x; hp.y = u1.x;
            lp.x = u0.y; lp.y = u1.y;
            *(uint2*)&BhS[base] = hp;
            *(uint2*)&BlS[base] = lp;
        }
        __syncthreads();
        short8 Ah[2], Al[2];
#pragma unroll
        for (int mi = 0; mi < 2; ++mi) {
            size_t aoff = (size_t)(arow0 + mi*16)*KP + kt + lq*8;
            Ah[mi] = *(const short8*)(EH + aoff);
            Al[mi] = *(const short8*)(EL + aoff);
        }
#pragma unroll
        for (int nj = 0; nj < 4; ++nj) {
            short8 Bh = *(const short8*)&BhS[(nj*64 + lane)*8];
            short8 Bl = *(const short8*)&BlS[(nj*64 + lane)*8];
#pragma unroll
            for (int mi = 0; mi < 2; ++mi) {
                acc[mi][nj] = __builtin_amdgcn_mfma_f32_16x16x32_bf16(Ah[mi], Bh, acc[mi][nj], 0, 0, 0);
                acc[mi][nj] = __builtin_amdgcn_mfma_f32_16x16x32_bf16(Ah[mi], Bl, acc[mi][nj], 0, 0, 0);
                acc[mi][nj] = __builtin_amdgcn_mfma_f32_16x16x32_bf16(Al[mi], Bh, acc[mi][nj], 0, 0, 0);
            }
        }
        __syncthreads();
    }
    // epilogue: rows r0..r0+3 = (re,im,re,im) of h0,h0+1 — pack directly
#pragma unroll
    for (int mi = 0; mi < 2; ++mi) {
#pragma unroll
        for (int nj = 0; nj < 4; ++nj) {
            int coln = col0 + nj*16 + lm;
            if (coln < N) {
                int r0 = row0 + wave*32 + mi*16 + lq*4;
                int h0 = r0 >> 1;
                Cm[(size_t)h0*N + coln]       = packc(acc[mi][nj][0], acc[mi][nj][1]);
                Cm[(size_t)(h0+1)*N + coln]   = packc(acc[mi][nj][2], acc[mi][nj][3]);
            }
        }
    }
}

// ---------------- elementwise frequency-domain updates (uint2 spectra) ----------------
__global__ void fg_kernel(const uint2* __restrict__ Ffy, uint2* __restrict__ Fz,
                          const uint2* __restrict__ Fk, const float* __restrict__ zetas,
                          int L, int total)
{
    int idx = blockIdx.x*256 + threadIdx.x;
    if (idx >= total) return;
    int k = idx % KF; int r = idx / KF;
    int c = r & 15; int hi = r >> 4;
    float zeta = 10.f * zetas[L*16 + c];
    float2 fk = ldc(Fk, (size_t)hi*KF + k);
    float2 fy = ldc(Ffy, idx);
    float2 fz = ldc(Fz, idx);
    float nx = zeta*(fk.x*fy.x + fk.y*fy.y) + fz.x;
    float ny = zeta*(fk.x*fy.y - fk.y*fy.x) + fz.y;
    float den = zeta*(fk.x*fk.x + fk.y*fk.y) + 1.f + 1e-8f;
    float inv = 1.f/den;
    Fz[idx] = packc(nx*inv, ny*inv);
}

__global__ void knum_kernel(const uint2* __restrict__ Fz, const uint2* __restrict__ Ffy,
                            const uint2* __restrict__ Fk, const float* __restrict__ kprox,
                            int L, int total, uint2* __restrict__ outk)
{
    int idx = blockIdx.x*256 + threadIdx.x;
    if (idx >= total) return;
    int k = idx % KF; int r = idx / KF;
    float zk = kprox[L];
    float s1x = 0.f, s1y = 0.f, s2 = 0.f;
    for (int c = 0; c < 16; ++c) {
        size_t bi = ((size_t)r*16 + c)*KF + k;
        float2 fz = ldc(Fz, bi), fy = ldc(Ffy, bi);
        s1x += fz.x*fy.x + fz.y*fy.y;
        s1y += fz.x*fy.y - fz.y*fy.x;
        s2  += fz.x*fz.x + fz.y*fz.y;
    }
    float2 fk = ldc(Fk, idx);
    float nx = zk*s1x + fk.x, ny = zk*s1y + fk.y;
    float den = zk*s2 + 1.f + 1e-8f;
    float inv = 1.f/den;
    outk[idx] = packc(nx*inv, ny*inv);
}

// ---------------- kernel (blur-kernel) update ----------------
__device__ __forceinline__ void lse_comb(float& m, float& s, float m2, float s2)
{
    if (m2 > m) { s = s * expf(m - m2) + s2; m = m2; }
    else        { s = s + s2 * expf(m2 - m); }
}

__global__ __launch_bounds__(256) void lse_part_kernel(const float* __restrict__ kraw0,
                                                       float2* __restrict__ parts)
{
    int img = blockIdx.y;
    const float* kraw = kraw0 + (size_t)img*FH*FH;
    int b = blockIdx.x, t = threadIdx.x;
    float m = -1e30f, s = 0.f;
    for (int i = b*256 + t; i < FH*FH; i += 64*256) {
        float v = 100.f * kraw[i];
        lse_comb(m, s, v, 1.f);
    }
    __shared__ float sm[256], ss[256];
    sm[t] = m; ss[t] = s;
    __syncthreads();
    for (int st = 128; st > 0; st >>= 1) {
        if (t < st) {
            float mm = sm[t], sc = ss[t];
            lse_comb(mm, sc, sm[t+st], ss[t+st]);
            sm[t] = mm; ss[t] = sc;
        }
        __syncthreads();
    }
    if (t == 0) { float2 o; o.x = sm[0]; o.y = ss[0]; parts[img*64 + b] = o; }
}

__global__ void lse_final_kernel(const float2* __restrict__ parts, float* __restrict__ kmaxB)
{
    int img = blockIdx.x;
    int t = threadIdx.x;
    __shared__ float sm[64], ss[64];
    float2 p = parts[img*64 + t];
    sm[t] = p.x; ss[t] = p.y;
    __syncthreads();
    for (int st = 32; st > 0; st >>= 1) {
        if (t < st) {
            float mm = sm[t], sc = ss[t];
            lse_comb(mm, sc, sm[t+st], ss[t+st]);
            sm[t] = mm; ss[t] = sc;
        }
        __syncthreads();
    }
    if (t == 0) kmaxB[img] = (sm[0] + logf(ss[0])) * 0.01f;
}

__global__ void zero_kernel(float* __restrict__ p, int n)
{
    int i = blockIdx.x*256 + threadIdx.x;
    if (i < n) p[i] = 0.f;
}

__global__ void kdelta_kernel(float* __restrict__ kful, int G)
{
    int t = threadIdx.x;
    if (t < G) kful[(size_t)t*FH*FH + 22*FH + 22] = 1.f;
}

__global__ __launch_bounds__(256) void knew_kernel(const float* __restrict__ kraw0,
    const float* __restrict__ kmax, const float* __restrict__ kb, int L,
    float* __restrict__ kful0)
{
    int img = blockIdx.x;
    const float* kraw = kraw0 + (size_t)img*FH*FH;
    float*       kful = kful0 + (size_t)img*FH*FH;
    int t = threadIdx.x;
    float thr = 0.01f * kb[L] * kmax[img];
    float vs[8]; float loc = 0.f;
#pragma unroll
    for (int ii = 0; ii < 8; ++ii) {
        int i = t + ii*256;
        float v = 0.f;
        if (i < 45*45) {
            int y = i/45, x = i - y*45;
            v = fmaxf(kraw[y*FH + x] - thr, 0.f);
        }
        vs[ii] = v; loc += v;
    }
    __shared__ float sr[256];
    sr[t] = loc; __syncthreads();
    for (int st = 128; st > 0; st >>= 1) { if (t < st) sr[t] += sr[t+st]; __syncthreads(); }
    float den = sr[0] + 1e-8f;
#pragma unroll
    for (int ii = 0; ii < 8; ++ii) {
        int i = t + ii*256;
        if (i < 45*45) {
            int y = i/45, x = i - y*45;
            float v = vs[ii] + ((y == 22 && x == 22) ? 1e-8f : 0.f);
            kful[y*FH + x] = v / den;
        }
    }
}

// ---------------- Fw0 (direct 9-term DFT of shifted 3x3), image-independent ----------------
__global__ void fw0_kernel(const float* __restrict__ w0c, const float2* __restrict__ Ef,
                           float2* __restrict__ Fw0)
{
    int idx = blockIdx.x*256 + threadIdx.x;
    if (idx >= 48*FH*KF) return;
    int k = idx % KF; int r = idx / KF;
    int c = r & 15; int r2 = r >> 4;
    int ci = r2 % 3; int h = r2 / 3;
    float accx = 0.f, accy = 0.f;
#pragma unroll
    for (int ky = 0; ky < 3; ++ky) {
        int a1 = ky - 1; if (a1 < 0) a1 += FH;
        float2 e1 = Ef[h*FH + a1];
#pragma unroll
        for (int kx = 0; kx < 3; ++kx) {
            int a2 = kx - 1; if (a2 < 0) a2 += FH;
            float2 e2 = Ef[k*FH + a2];
            float wv = w0c[((c*3 + ci)*3 + ky)*3 + kx];
            float tr = e1.x*e2.x - e1.y*e2.y;
            float ti = e1.x*e2.y + e1.y*e2.x;
            accx += wv*tr; accy += wv*ti;
        }
    }
    float2 o; o.x = accx; o.y = accy;
    Fw0[idx] = o;
}

// ---------------- final per-bin 3x3 Hermitian Wiener solve (uint2 spectra) ----------------
__global__ void wiener_kernel(const uint2* __restrict__ Fk, const uint2* __restrict__ Fy,
    const float2* __restrict__ Fw0, const uint2* __restrict__ Fg2,
    const float* __restrict__ eta, int G, int total, uint2* __restrict__ Fx)
{
    int idx = blockIdx.x*256 + threadIdx.x;
    if (idx >= total) return;
    int k = idx % KF; int r = idx / KF;
    int h = r / G;
    float2 fk = ldc(Fk, idx);
    float fksq = fk.x*fk.x + fk.y*fk.y;
    float2 fyr = ldc(Fy, ((size_t)3*r + 0)*KF + k);
    float2 fyg = ldc(Fy, ((size_t)3*r + 1)*KF + k);
    float2 fyb = ldc(Fy, ((size_t)3*r + 2)*KF + k);
    float Crr = fksq, Cgg = fksq, Cbb = fksq;
    float2 Crg, Crb, Cgb;
    Crg.x = Crg.y = Crb.x = Crb.y = Cgb.x = Cgb.y = 0.f;
    float2 Br, Bg, Bb;
    Br.x = fk.x*fyr.x + fk.y*fyr.y; Br.y = fk.x*fyr.y - fk.y*fyr.x;
    Bg.x = fk.x*fyg.x + fk.y*fyg.y; Bg.y = fk.x*fyg.y - fk.y*fyg.x;
    Bb.x = fk.x*fyb.x + fk.y*fyb.y; Bb.y = fk.x*fyb.y - fk.y*fyb.x;
    for (int c = 0; c < 16; ++c) {
        float es = 10.f * eta[c];
        float2 wr = Fw0[((size_t)h*48 +  0 + c)*KF + k];
        float2 wg = Fw0[((size_t)h*48 + 16 + c)*KF + k];
        float2 wb = Fw0[((size_t)h*48 + 32 + c)*KF + k];
        float2 g  = ldc(Fg2, ((size_t)r*16 + c)*KF + k);
        Crr += es*(wr.x*wr.x + wr.y*wr.y);
        Cgg += es*(wg.x*wg.x + wg.y*wg.y);
        Cbb += es*(wb.x*wb.x + wb.y*wb.y);
        Crg.x += es*(wr.x*wg.x + wr.y*wg.y); Crg.y += es*(wr.x*wg.y - wr.y*wg.x);
        Crb.x += es*(wr.x*wb.x + wr.y*wb.y); Crb.y += es*(wr.x*wb.y - wr.y*wb.x);
        Cgb.x += es*(wg.x*wb.x + wg.y*wb.y); Cgb.y += es*(wg.x*wb.y - wg.y*wb.x);
        Br.x += es*(wr.x*g.x + wr.y*g.y); Br.y += es*(wr.x*g.y - wr.y*g.x);
        Bg.x += es*(wg.x*g.x + wg.y*g.y); Bg.y += es*(wg.x*g.y - wg.y*g.x);
        Bb.x += es*(wb.x*g.x + wb.y*g.y); Bb.y += es*(wb.x*g.y - wb.y*g.x);
    }
    float Crg_sq = Crg.x*Crg.x + Crg.y*Crg.y;
    float Crb_sq = Crb.x*Crb.x + Crb.y*Crb.y;
    float Cgb_sq = Cgb.x*Cgb.x + Cgb.y*Cgb.y;
    float Irr = Cgg*Cbb - Cgb_sq;
    float Igg = Crr*Cbb - Crb_sq;
    float Ibb = Crr*Cgg - Crg_sq;
    float2 Irg, Irb, Igb;
    Irg.x = (Cgb.x*Crb.x + Cgb.y*Crb.y) - Cbb*Crg.x;
    Irg.y = (Cgb.x*Crb.y - Cgb.y*Crb.x) - Cbb*Crg.y;
    Irb.x = (Crg.x*Cgb.x - Crg.y*Cgb.y) - Cgg*Crb.x;
    Irb.y = (Crg.x*Cgb.y + Crg.y*Cgb.x) - Cgg*Crb.y;
    Igb.x = (Crg.x*Crb.x + Crg.y*Crb.y) - Crr*Cgb.x;
    Igb.y = (Crg.x*Crb.y - Crg.y*Crb.x) - Crr*Cgb.y;
    float tx_ = Crg.x*Cgb.x - Crg.y*Cgb.y;
    float ty_ = Crg.x*Cgb.y + Crg.y*Cgb.x;
    float den = Crr*Irr - Cgg*Crb_sq - Cbb*Crg_sq + 2.f*(tx_*Crb.x + ty_*Crb.y) + 1e-8f;
    float inv = 1.f/den;
    float ox, oy;
    ox = (Irr*Br.x + (Irg.x*Bg.x - Irg.y*Bg.y) + (Irb.x*Bb.x - Irb.y*Bb.y))*inv;
    oy = (Irr*Br.y + (Irg.x*Bg.y + Irg.y*Bg.x) + (Irb.x*Bb.y + Irb.y*Bb.x))*inv;
    Fx[((size_t)3*r + 0)*KF + k] = packc(ox, oy);
    ox = ((Irg.x*Br.x + Irg.y*Br.y) + Igg*Bg.x + (Igb.x*Bb.x - Igb.y*Bb.y))*inv;
    oy = ((Irg.x*Br.y - Irg.y*Br.x) + Igg*Bg.y + (Igb.x*Bb.y + Igb.y*Bb.x))*inv;
    Fx[((size_t)3*r + 1)*KF + k] = packc(ox, oy);
    ox = ((Irb.x*Br.x + Irb.y*Br.y) + (Igb.x*Bg.x + Igb.y*Bg.y) + Ibb*Bb.x)*inv;
    oy = ((Irb.x*Br.y - Irb.y*Br.x) + (Igb.x*Bg.y - Igb.y*Bg.x) + Ibb*Bb.y)*inv;
    Fx[((size_t)3*r + 2)*KF + k] = packc(ox, oy);
}

// ---------------- output assembly ----------------
__global__ void crop_kernel(const float* __restrict__ sp, float* __restrict__ outp, int total)
{
    int idx = blockIdx.x*256 + threadIdx.x;
    if (idx >= total) return;
    int x = idx & 255; int r = idx >> 8; int y = r & 255; int plane = r >> 8;
    outp[idx] = sp[((size_t)plane*FH + (y+22))*FH + (x+22)];
}

__global__ void kcopy_kernel(const float* __restrict__ kful, float* __restrict__ outp, int total)
{
    int idx = blockIdx.x*256 + threadIdx.x;
    if (idx >= total) return;
    int rem = idx % 2025; int img = idx / 2025;
    int x = rem % 45; int y = rem / 45;
    outp[idx] = kful[(size_t)img*FH*FH + y*FH + x];
}

// =====================================================================
extern "C" void kernel_launch(void* const* d_in, const int* in_sizes, int n_in,
                              void* d_out, int out_size, void* d_ws, size_t ws_size,
                              hipStream_t stream)
{
    (void)in_sizes; (void)n_in; (void)out_size;
    const float* blurred = (const float*)d_in[0];
    const float* w0      = (const float*)d_in[1];
    const float* wsw     = (const float*)d_in[2];
    const float* biases  = (const float*)d_in[3];
    const float* kbias   = (const float*)d_in[4];
    const float* kprox   = (const float*)d_in[5];
    const float* zetas   = (const float*)d_in[6];
    const float* eta     = (const float*)d_in[7];
    float* outp = (float*)d_out;

    auto al = [](size_t b) { return (b + 255) & ~(size_t)255; };
    auto need = [&](int G) -> size_t {
        size_t s = 0;
        s += al((size_t)FH*FH*8);                 // Ef
        s += 4*al((size_t)KP*KP*2);               // EfH/L, EiH/L
        s += 2*al((size_t)448*FH*2);              // Tt
        s += 2*al((size_t)FH*416*2);              // Ut
        s += al(432*4);                           // w0c
        s += al((size_t)10*G*16*65536*4);         // fyN
        s += al((size_t)G*16*FH*FH*4);            // zsp
        s += 3*al((size_t)G*16*FH*KF*8);          // mid, FzFg, Ffy (uint2)
        s += 3*al((size_t)G*FH*KF*8);             // Fk, kfA, kfB
        s += 2*al((size_t)G*FH*FH*4);             // kraw, kful
        s += 2*al((size_t)G*3*FH*KF*8);           // FyB, FxB
        s += al((size_t)G*64*8) + al(256);        // lseP, kmax
        return s;
    };
    int G = 4;
    while (G > 1 && need(G) > ws_size) G >>= 1;

    char* base = (char*)d_ws;
    size_t off = 0;
    auto alloc = [&](size_t bytes) -> void* {
        void* p = (void*)(base + off);
        off += (bytes + 255) & ~(size_t)255;
        return p;
    };
    float2* Ef   = (float2*)alloc((size_t)FH*FH*8);
    unsigned short* EfH = (unsigned short*)alloc((size_t)KP*KP*2);
    unsigned short* EfL = (unsigned short*)alloc((size_t)KP*KP*2);
    unsigned short* EiH = (unsigned short*)alloc((size_t)KP*KP*2);
    unsigned short* EiL = (unsigned short*)alloc((size_t)KP*KP*2);
    unsigned short* TtH = (unsigned short*)alloc((size_t)448*FH*2);
    unsigned short* TtL = (unsigned short*)alloc((size_t)448*FH*2);
    unsigned short* UtH = (unsigned short*)alloc((size_t)FH*416*2);
    unsigned short* UtL = (unsigned short*)alloc((size_t)FH*416*2);
    float*  w0cB = (float*)alloc(432*4);
    float*  fyN  = (float*)alloc((size_t)10*G*16*65536*4);
    float*  zsp  = (float*)alloc((size_t)G*16*FH*FH*4);
    uint2*  mid  = (uint2*)alloc((size_t)G*16*FH*KF*8);
    uint2*  FzFg = (uint2*)alloc((size_t)G*16*FH*KF*8);
    uint2*  Ffy  = (uint2*)alloc((size_t)G*16*FH*KF*8);
    uint2*  Fk   = (uint2*)alloc((size_t)G*FH*KF*8);
    uint2*  kfA  = (uint2*)alloc((size_t)G*FH*KF*8);
    uint2*  kfB  = (uint2*)alloc((size_t)G*FH*KF*8);
    float*  kraw = (float*)alloc((size_t)G*FH*FH*4);
    float*  kful = (float*)alloc((size_t)G*FH*FH*4);
    uint2*  FyB  = (uint2*)alloc((size_t)G*3*FH*KF*8);
    uint2*  FxB  = (uint2*)alloc((size_t)G*3*FH*KF*8);
    float2* lseP = (float2*)alloc((size_t)G*64*8);
    float*  kmaxB= (float*)alloc(256);
    // Fw0 (28.45 MB) overlays fyN (>= 41.9 MB even at G=1) — dead by final stage
    float2* Fw0B = (float2*)fyN;

    // tables + weight prep (image-independent)
    init_ef_k<<<(FH*FH+255)/256, 256, 0, stream>>>(Ef);
    init_estack<<<(KP*KP+255)/256, 256, 0, stream>>>(EfH, EfL, 0);
    init_estack<<<(KP*KP+255)/256, 256, 0, stream>>>(EiH, EiL, 1);
    init_tt<<<(448*FH+255)/256, 256, 0, stream>>>(TtH, TtL);
    init_ut<<<(FH*416+255)/256, 256, 0, stream>>>(UtH, UtL);
    w0c_kernel<<<1, 64, 0, stream>>>(w0, w0cB);

    auto zg = [&](const unsigned short* EH, const unsigned short* EL,
                  const uint2* Bm, uint2* Cm, int Ncols) {
        zgemm_col_mfma<<<dim3((Ncols+63)/64, (2*FH)/128), 256, 0, stream>>>(
            EH, EL, Bm, Cm, Ncols);
    };
    auto r2c = [&](const float* inp, int inH, int inW, int oY, int oX,
                   const float* thr, uint2* o, int B) {
        r2c_row_mfma<<<dim3(7, 3, B), 256, 0, stream>>>(
            inp, inH, inW, oY, oX, thr, TtH, TtL, o, B);
    };
    auto c2r = [&](const uint2* Ain, float* o, int B) {
        c2r_row_mfma<<<dim3(6, 3, B), 256, 0, stream>>>(
            Ain, UtH, UtL, o, B);
    };

    const size_t IMG16 = (size_t)16*65536;
    const size_t LAY   = (size_t)G*IMG16;

    for (int g0 = 0; g0 < 4; g0 += G) {
        const float* img = blurred + (size_t)g0*3*65536;

        // forward conv chain
        conv3x3_kernel<<<dim3(16,16,G), 256, 0, stream>>>(
            img, w0cB, fyN, 3, 1, (size_t)3*65536, IMG16);
        for (int l = 1; l < 10; ++l)
            conv3x3_kernel<<<dim3(16,16,G), 256, 0, stream>>>(
                fyN + (size_t)(l-1)*LAY, wsw + (size_t)(l-1)*2304,
                fyN + (size_t)l*LAY, 16, 0, IMG16, IMG16);

        // z init (circshift + threshold b0), Fz
        int totZ = G*16*FH*FH;
        zinit_kernel<<<(totZ+255)/256, 256, 0, stream>>>(fyN + 9*LAY, biases, zsp, totZ);
        r2c(zsp, FH, FH, 0, 0, nullptr, mid, G*16);
        zg(EfH, EfL, mid, FzFg, G*16*KF);

        // k init = delta
        zero_kernel<<<(G*FH*FH+255)/256, 256, 0, stream>>>(kful, G*FH*FH);
        kdelta_kernel<<<1, 64, 0, stream>>>(kful, G);

        int totS = G*16*FH*KF;
        int totK = G*FH*KF;
        for (int it = 0; it < 10; ++it) {
            int Lfy = 9 - it;
            r2c(fyN + (size_t)Lfy*LAY, 256, 256, 44, 44, nullptr, mid, G*16);
            zg(EfH, EfL, mid, Ffy, G*16*KF);
            r2c(kful, FH, FH, 0, 0, nullptr, mid, G);
            zg(EfH, EfL, mid, Fk, G*KF);
            fg_kernel<<<(totS+255)/256, 256, 0, stream>>>(Ffy, FzFg, Fk, zetas, it, totS);
            zg(EiH, EiL, FzFg, mid, G*16*KF);
            c2r(mid, zsp, G*16);                    // zsp = irfft(Fg) PRE-threshold
            r2c(zsp, FH, FH, 0, 0, biases + (it+1)*16, mid, G*16);  // fused soft-threshold
            zg(EfH, EfL, mid, FzFg, G*16*KF);       // Fz_new
            knum_kernel<<<(totK+255)/256, 256, 0, stream>>>(FzFg, Ffy, Fk, kprox, it, totK, kfA);
            zg(EiH, EiL, kfA, kfB, G*KF);
            c2r(kfB, kraw, G);
            lse_part_kernel<<<dim3(64,G), 256, 0, stream>>>(kraw, lseP);
            lse_final_kernel<<<G, 64, 0, stream>>>(lseP, kmaxB);
            knew_kernel<<<G, 256, 0, stream>>>(kraw, kmaxB, kbias, it, kful);
        }

        // ---- final stage ----
        r2c(img, 256, 256, 44, 44, nullptr, mid, 3*G);
        zg(EfH, EfL, mid, FyB, 3*G*KF);
        r2c(kful, FH, FH, 0, 0, nullptr, mid, G);
        zg(EfH, EfL, mid, Fk, G*KF);
        // Fg2 = rfft(softt(zsp, b_final))
        r2c(zsp, FH, FH, 0, 0, biases + 11*16, mid, G*16);
        zg(EfH, EfL, mid, FzFg, G*16*KF);
        fw0_kernel<<<(48*FH*KF+255)/256, 256, 0, stream>>>(w0cB, Ef, Fw0B);
        wiener_kernel<<<(totK+255)/256, 256, 0, stream>>>(Fk, FyB, Fw0B, FzFg, eta, G, totK, FxB);
        zg(EiH, EiL, FxB, mid, 3*G*KF);
        c2r(mid, zsp, 3*G);
        int totC = G*3*65536;
        crop_kernel<<<(totC+255)/256, 256, 0, stream>>>(zsp, outp + (size_t)g0*3*65536, totC);
        int totKC = G*2025;
        kcopy_kernel<<<(totKC+255)/256, 256, 0, stream>>>(kful, outp + 786432 + g0*2025, totKC);
    }
}

// Round 12
// 10801.718 us; speedup vs baseline: 1.6661x; 1.0532x over previous
//
#include <hip/hip_runtime.h>
#include <math.h>

#define FH 384
#define KF 193
#define KP 768    // stacked real K' = 2*FH (col pass)
#define NR 386    // real row-spectrum width = 2*KF
#define SPW 147456

typedef __attribute__((ext_vector_type(8))) short short8;
typedef __attribute__((ext_vector_type(4))) float f32x4;
typedef unsigned int u32;
typedef unsigned short u16;

static __device__ __forceinline__ float softt(float v, float b) {
    return copysignf(fmaxf(fabsf(v) - b, 0.f), v);
}
static __device__ __forceinline__ u16 bf16_rn(float v) {
    u32 u = __float_as_uint(v);
    u32 r = (u + 0x7FFFu + ((u >> 16) & 1u)) >> 16;
    return (u16)r;
}
static __device__ __forceinline__ float bf16_to_f(u16 h) {
    return __uint_as_float(((u32)h) << 16);
}
// complex spectra stored as uint2: .x = H-word (bf16 re | bf16 im<<16), .y = L-word
static __device__ __forceinline__ float2 ldc(const uint2* __restrict__ S, size_t i) {
    uint2 u = S[i];
    float2 r;
    r.x = __uint_as_float((u.x & 0xffffu) << 16) + __uint_as_float((u.y & 0xffffu) << 16);
    r.y = __uint_as_float(u.x & 0xffff0000u) + __uint_as_float(u.y & 0xffff0000u);
    return r;
}
static __device__ __forceinline__ uint2 packc(float re, float im) {
    u16 hr = bf16_rn(re), hi = bf16_rn(im);
    u16 lr = bf16_rn(re - bf16_to_f(hr)), li = bf16_rn(im - bf16_to_f(hi));
    uint2 o; o.x = (u32)hr | ((u32)hi << 16); o.y = (u32)lr | ((u32)li << 16);
    return o;
}

// ---------------- tables ----------------
__global__ void init_ef_k(float2* Ef) {
    int idx = blockIdx.x * 256 + threadIdx.x;
    if (idx >= FH * FH) return;
    int h = idx / FH, j = idx % FH;
    int m = (h * j) % FH;
    float th = (float)(6.283185307179586 / FH) * (float)m;
    float2 v; v.x = cosf(th); v.y = -sinf(th);
    Ef[idx] = v;
}

__global__ void init_estack(u16* __restrict__ H, u16* __restrict__ L, int inv)
{
    int idx = blockIdx.x * 256 + threadIdx.x;
    if (idx >= KP * KP) return;
    int gm = idx / KP, kp = idx % KP;
    int m = gm >> 1, comp = gm & 1;
    int t = kp >> 1, ri = kp & 1;
    int mm = (m * t) % FH;
    float th = (float)(6.283185307179586 / FH) * (float)mm;
    float c = cosf(th), s = sinf(th);
    float er, ei;
    if (inv) { er = c * (1.f/FH); ei = s * (1.f/FH); }
    else     { er = c;            ei = -s; }
    float v;
    if (comp == 0) v = (ri == 0) ? er : -ei;
    else           v = (ri == 0) ? ei :  er;
    u16 h = bf16_rn(v);
    H[idx] = h;
    L[idx] = bf16_rn(v - bf16_to_f(h));
}

__global__ void init_tt(u16* __restrict__ H, u16* __restrict__ L)
{
    int idx = blockIdx.x * 256 + threadIdx.x;
    if (idx >= 448 * FH) return;
    int n = idx / FH, w = idx % FH;
    float v = 0.f;
    if (n < NR) {
        int kf = n >> 1, ri = n & 1;
        int m = (w * kf) % FH;
        float th = (float)(6.283185307179586 / FH) * (float)m;
        v = ri ? -sinf(th) : cosf(th);
    }
    u16 h = bf16_rn(v);
    H[idx] = h;
    L[idx] = bf16_rn(v - bf16_to_f(h));
}

__global__ void init_ut(u16* __restrict__ H, u16* __restrict__ L)
{
    int idx = blockIdx.x * 256 + threadIdx.x;
    if (idx >= FH * 416) return;
    int x = idx / 416, kp = idx % 416;
    float v = 0.f;
    if (kp < NR) {
        int k = kp >> 1, ri = kp & 1;
        float ck = (k == 0 || k == FH/2) ? (1.f/FH) : (2.f/FH);
        int m = (k * x) % FH;
        float th = (float)(6.283185307179586 / FH) * (float)m;
        v = ri ? -ck*sinf(th) : ck*cosf(th);
    }
    u16 h = bf16_rn(v);
    H[idx] = h;
    L[idx] = bf16_rn(v - bf16_to_f(h));
}

// ---------------- w0 centering ----------------
__global__ void w0c_kernel(const float* __restrict__ w0, float* __restrict__ w0c) {
    int t = threadIdx.x;
    if (t < 48) {
        float m = 0.f;
        for (int d = 0; d < 9; ++d) m += w0[t*9+d];
        m *= (1.f/9.f);
        for (int d = 0; d < 9; ++d) w0c[t*9+d] = w0[t*9+d] - m;
    }
}

// ---------------- 3x3 conv: input fp32 (first) or split H/L; output split H/L ----------------
__global__ __launch_bounds__(256) void conv3x3_kernel(
    const float* __restrict__ inpF0, const u16* __restrict__ inH0, const u16* __restrict__ inL0,
    const float* __restrict__ w,
    u16* __restrict__ outH0, u16* __restrict__ outL0, int Cin, int flip,
    size_t inImgStride)
{
    size_t iofs = (size_t)blockIdx.z * inImgStride;
    const float* inF = inpF0 ? inpF0 + iofs : nullptr;
    const u16*   iH  = inH0 ? inH0 + iofs : nullptr;
    const u16*   iL  = inL0 ? inL0 + iofs : nullptr;
    u16* oH = outH0 + (size_t)blockIdx.z * 16*65536;
    u16* oL = outL0 + (size_t)blockIdx.z * 16*65536;
    __shared__ float tile[18][19];
    __shared__ float wl[16*16*9];
    int x0 = blockIdx.x * 16, y0 = blockIdx.y * 16;
    int t = threadIdx.x;
    int tx = t & 15, ty = t >> 4;
    int nw = 16 * Cin * 9;
    for (int i = t; i < nw; i += 256) {
        int d = i % 9;
        wl[i] = flip ? w[i + 8 - 2*d] : w[i];
    }
    float acc[16];
#pragma unroll
    for (int co = 0; co < 16; ++co) acc[co] = 0.f;
    for (int ci = 0; ci < Cin; ++ci) {
        __syncthreads();
        for (int i = t; i < 18*18; i += 256) {
            int yy = i / 18, xx = i % 18;
            int gy = y0 - 1 + yy, gx = x0 - 1 + xx;
            float v = 0.f;
            if (gy >= 0 && gy < 256 && gx >= 0 && gx < 256) {
                size_t ii = ((size_t)ci*256 + gy)*256 + gx;
                v = inF ? inF[ii] : (bf16_to_f(iH[ii]) + bf16_to_f(iL[ii]));
            }
            tile[yy][xx] = v;
        }
        __syncthreads();
        float v[9];
#pragma unroll
        for (int dy = 0; dy < 3; dy++)
#pragma unroll
            for (int dx = 0; dx < 3; dx++) v[dy*3+dx] = tile[ty+dy][tx+dx];
#pragma unroll
        for (int co = 0; co < 16; co++) {
            const float* wp = &wl[(co*Cin+ci)*9];
            acc[co] += v[0]*wp[0]+v[1]*wp[1]+v[2]*wp[2]
                     + v[3]*wp[3]+v[4]*wp[4]+v[5]*wp[5]
                     + v[6]*wp[6]+v[7]*wp[7]+v[8]*wp[8];
        }
    }
#pragma unroll
    for (int co = 0; co < 16; co++) {
        size_t o = ((size_t)co*256 + (y0+ty))*256 + (x0+tx);
        u16 h = bf16_rn(acc[co]);
        oH[o] = h;
        oL[o] = bf16_rn(acc[co] - bf16_to_f(h));
    }
}

// ---------------- z init: circshift(22,22) of padded split fy9 + soft threshold ------
__global__ void zinit_kernel(const u16* __restrict__ fy9H, const u16* __restrict__ fy9L,
                             const float* __restrict__ b0, float* __restrict__ z, int total)
{
    int idx = blockIdx.x*256 + threadIdx.x;
    if (idx >= total) return;
    int x = idx % FH; int r = idx / FH; int y = r % FH; int plane = r / FH;
    int c = plane & 15;
    int Y = y + 22; if (Y >= FH) Y -= FH;
    int X = x + 22; if (X >= FH) X -= FH;
    int yy = Y - 44, xx = X - 44;
    float v = 0.f;
    if (yy >= 0 && yy < 256 && xx >= 0 && xx < 256) {
        size_t ii = ((size_t)plane*256 + yy)*256 + xx;
        v = bf16_to_f(fy9H[ii]) + bf16_to_f(fy9L[ii]);
    }
    z[idx] = softt(v, b0[c]);
}

// ---------------- MFMA row pass R2C (fp32 source, fused softt) ----------------
__global__ __launch_bounds__(256) void r2c_row_mfma(
    const float* __restrict__ inp, int inH, int inW, int offY, int offX,
    const float* __restrict__ thr,
    const u16* __restrict__ TtH, const u16* __restrict__ TtL,
    uint2* __restrict__ outp, int B)
{
    __shared__ u16 AhS[8*64*8];
    __shared__ u16 AlS[8*64*8];
    int col0 = blockIdx.x * 64;
    int y0   = blockIdx.y * 128;
    int plane = blockIdx.z;
    int tid = threadIdx.x;
    int wave = tid >> 6, lane = tid & 63;
    int lm = lane & 15, lq = lane >> 4;
    f32x4 acc[2][4];
#pragma unroll
    for (int mi = 0; mi < 2; ++mi)
#pragma unroll
        for (int nj = 0; nj < 4; ++nj) acc[mi][nj] = (f32x4){0.f,0.f,0.f,0.f};
    float bthr = thr ? thr[plane & 15] : 0.f;
    const float* inpP = inp + (size_t)plane*inH*inW;
    int ktlo = (offX >> 5) << 5;
    int kthi = offX + inW;
    for (int kt = ktlo; kt < kthi; kt += 32) {
#pragma unroll
        for (int s = 0; s < 4; ++s) {
            int slot = tid + s*256;
            int r = slot >> 3, kq = slot & 7;
            int yy = y0 + r - offY;
            float v[4];
#pragma unroll
            for (int d = 0; d < 4; ++d) {
                int xx = kt + kq*4 + d - offX;
                float t = 0.f;
                if (yy >= 0 && yy < inH && xx >= 0 && xx < inW)
                    t = inpP[(size_t)yy*inW + xx];
                if (thr) t = softt(t, bthr);
                v[d] = t;
            }
            u16 h0 = bf16_rn(v[0]), h1 = bf16_rn(v[1]);
            u16 h2 = bf16_rn(v[2]), h3 = bf16_rn(v[3]);
            u16 l0 = bf16_rn(v[0] - bf16_to_f(h0));
            u16 l1 = bf16_rn(v[1] - bf16_to_f(h1));
            u16 l2 = bf16_rn(v[2] - bf16_to_f(h2));
            u16 l3 = bf16_rn(v[3] - bf16_to_f(h3));
            int base = ((r >> 4)*64 + (r & 15) + 16*(kq >> 1))*8 + (kq & 1)*4;
            uint2 hp, lp;
            hp.x = (u32)h0 | ((u32)h1 << 16);
            hp.y = (u32)h2 | ((u32)h3 << 16);
            lp.x = (u32)l0 | ((u32)l1 << 16);
            lp.y = (u32)l2 | ((u32)l3 << 16);
            *(uint2*)&AhS[base] = hp;
            *(uint2*)&AlS[base] = lp;
        }
        __syncthreads();
        short8 Ah[2], Al[2];
#pragma unroll
        for (int mi = 0; mi < 2; ++mi) {
            Ah[mi] = *(const short8*)&AhS[((wave*2 + mi)*64 + lane)*8];
            Al[mi] = *(const short8*)&AlS[((wave*2 + mi)*64 + lane)*8];
        }
#pragma unroll
        for (int nj = 0; nj < 4; ++nj) {
            size_t toff = (size_t)(col0 + nj*16 + lm)*FH + kt + lq*8;
            short8 Bh = *(const short8*)(TtH + toff);
            short8 Bl = *(const short8*)(TtL + toff);
#pragma unroll
            for (int mi = 0; mi < 2; ++mi) {
                acc[mi][nj] = __builtin_amdgcn_mfma_f32_16x16x32_bf16(Ah[mi], Bh, acc[mi][nj], 0, 0, 0);
                acc[mi][nj] = __builtin_amdgcn_mfma_f32_16x16x32_bf16(Ah[mi], Bl, acc[mi][nj], 0, 0, 0);
                acc[mi][nj] = __builtin_amdgcn_mfma_f32_16x16x32_bf16(Al[mi], Bh, acc[mi][nj], 0, 0, 0);
            }
        }
        __syncthreads();
    }
#pragma unroll
    for (int mi = 0; mi < 2; ++mi) {
#pragma unroll
        for (int nj = 0; nj < 4; ++nj) {
            int n = col0 + nj*16 + lm;
            int k = n >> 1;
            u16 h[4], l[4];
#pragma unroll
            for (int rr = 0; rr < 4; ++rr) {
                float v = acc[mi][nj][rr];
                h[rr] = bf16_rn(v);
                l[rr] = bf16_rn(v - bf16_to_f(h[rr]));
            }
            u32 hx = (u32)h[0] | ((u32)h[1]<<16), hy = (u32)h[2] | ((u32)h[3]<<16);
            u32 lx = (u32)l[0] | ((u32)l[1]<<16), ly = (u32)l[2] | ((u32)l[3]<<16);
            u32 phx = __shfl_xor((int)hx, 1), phy = __shfl_xor((int)hy, 1);
            u32 plx = __shfl_xor((int)lx, 1), ply = __shfl_xor((int)ly, 1);
            if (((lm & 1) == 0) && k < KF) {
                int ybase = y0 + wave*32 + mi*16 + lq*4;
                u32 H[4], L[4];
                H[0] = (hx & 0xffffu) | (phx << 16);
                H[1] = (hx >> 16)     | (phx & 0xffff0000u);
                H[2] = (hy & 0xffffu) | (phy << 16);
                H[3] = (hy >> 16)     | (phy & 0xffff0000u);
                L[0] = (lx & 0xffffu) | (plx << 16);
                L[1] = (lx >> 16)     | (plx & 0xffff0000u);
                L[2] = (ly & 0xffffu) | (ply << 16);
                L[3] = (ly >> 16)     | (ply & 0xffff0000u);
#pragma unroll
                for (int rr = 0; rr < 4; ++rr) {
                    uint2 o; o.x = H[rr]; o.y = L[rr];
                    outp[((size_t)(ybase+rr)*B + plane)*KF + k] = o;
                }
            }
        }
    }
}

// ---------------- MFMA row pass R2C (pre-split H/L source, zero-conversion staging) --------
// window offsets are multiples of 4 -> every 4-elem group fully in or out of range.
__global__ __launch_bounds__(256) void r2c_row_mfma_s(
    const u16* __restrict__ Hs, const u16* __restrict__ Ls,
    int inH, int inW, int offY, int offX,
    const u16* __restrict__ TtH, const u16* __restrict__ TtL,
    uint2* __restrict__ outp, int B)
{
    __shared__ u16 AhS[8*64*8];
    __shared__ u16 AlS[8*64*8];
    int col0 = blockIdx.x * 64;
    int y0   = blockIdx.y * 128;
    int plane = blockIdx.z;
    int tid = threadIdx.x;
    int wave = tid >> 6, lane = tid & 63;
    int lm = lane & 15, lq = lane >> 4;
    f32x4 acc[2][4];
#pragma unroll
    for (int mi = 0; mi < 2; ++mi)
#pragma unroll
        for (int nj = 0; nj < 4; ++nj) acc[mi][nj] = (f32x4){0.f,0.f,0.f,0.f};
    const u16* hP = Hs + (size_t)plane*inH*inW;
    const u16* lP = Ls + (size_t)plane*inH*inW;
    int ktlo = (offX >> 5) << 5;
    int kthi = offX + inW;
    for (int kt = ktlo; kt < kthi; kt += 32) {
#pragma unroll
        for (int s = 0; s < 4; ++s) {
            int slot = tid + s*256;
            int r = slot >> 3, kq = slot & 7;
            int yy = y0 + r - offY;
            int xx0 = kt + kq*4 - offX;
            uint2 hp, lp;
            hp.x = hp.y = lp.x = lp.y = 0u;
            if (yy >= 0 && yy < inH && xx0 >= 0 && xx0 + 4 <= inW) {
                size_t o = (size_t)yy*inW + xx0;
                hp = *(const uint2*)(hP + o);
                lp = *(const uint2*)(lP + o);
            }
            int base = ((r >> 4)*64 + (r & 15) + 16*(kq >> 1))*8 + (kq & 1)*4;
            *(uint2*)&AhS[base] = hp;
            *(uint2*)&AlS[base] = lp;
        }
        __syncthreads();
        short8 Ah[2], Al[2];
#pragma unroll
        for (int mi = 0; mi < 2; ++mi) {
            Ah[mi] = *(const short8*)&AhS[((wave*2 + mi)*64 + lane)*8];
            Al[mi] = *(const short8*)&AlS[((wave*2 + mi)*64 + lane)*8];
        }
#pragma unroll
        for (int nj = 0; nj < 4; ++nj) {
            size_t toff = (size_t)(col0 + nj*16 + lm)*FH + kt + lq*8;
            short8 Bh = *(const short8*)(TtH + toff);
            short8 Bl = *(const short8*)(TtL + toff);
#pragma unroll
            for (int mi = 0; mi < 2; ++mi) {
                acc[mi][nj] = __builtin_amdgcn_mfma_f32_16x16x32_bf16(Ah[mi], Bh, acc[mi][nj], 0, 0, 0);
                acc[mi][nj] = __builtin_amdgcn_mfma_f32_16x16x32_bf16(Ah[mi], Bl, acc[mi][nj], 0, 0, 0);
                acc[mi][nj] = __builtin_amdgcn_mfma_f32_16x16x32_bf16(Al[mi], Bh, acc[mi][nj], 0, 0, 0);
            }
        }
        __syncthreads();
    }
#pragma unroll
    for (int mi = 0; mi < 2; ++mi) {
#pragma unroll
        for (int nj = 0; nj < 4; ++nj) {
            int n = col0 + nj*16 + lm;
            int k = n >> 1;
            u16 h[4], l[4];
#pragma unroll
            for (int rr = 0; rr < 4; ++rr) {
                float v = acc[mi][nj][rr];
                h[rr] = bf16_rn(v);
                l[rr] = bf16_rn(v - bf16_to_f(h[rr]));
            }
            u32 hx = (u32)h[0] | ((u32)h[1]<<16), hy = (u32)h[2] | ((u32)h[3]<<16);
            u32 lx = (u32)l[0] | ((u32)l[1]<<16), ly = (u32)l[2] | ((u32)l[3]<<16);
            u32 phx = __shfl_xor((int)hx, 1), phy = __shfl_xor((int)hy, 1);
            u32 plx = __shfl_xor((int)lx, 1), ply = __shfl_xor((int)ly, 1);
            if (((lm & 1) == 0) && k < KF) {
                int ybase = y0 + wave*32 + mi*16 + lq*4;
                u32 H[4], L[4];
                H[0] = (hx & 0xffffu) | (phx << 16);
                H[1] = (hx >> 16)     | (phx & 0xffff0000u);
                H[2] = (hy & 0xffffu) | (phy << 16);
                H[3] = (hy >> 16)     | (phy & 0xffff0000u);
                L[0] = (lx & 0xffffu) | (plx << 16);
                L[1] = (lx >> 16)     | (plx & 0xffff0000u);
                L[2] = (ly & 0xffffu) | (ply << 16);
                L[3] = (ly >> 16)     | (ply & 0xffff0000u);
#pragma unroll
                for (int rr = 0; rr < 4; ++rr) {
                    uint2 o; o.x = H[rr]; o.y = L[rr];
                    outp[((size_t)(ybase+rr)*B + plane)*KF + k] = o;
                }
            }
        }
    }
}

// ---------------- MFMA row pass C2R (+ optional fused softt-split side-output) ----------
__global__ __launch_bounds__(256) void c2r_row_mfma(
    const uint2* __restrict__ Ain,
    const u16* __restrict__ UtH, const u16* __restrict__ UtL,
    float* __restrict__ outp, const float* __restrict__ thr,
    u16* __restrict__ spH, u16* __restrict__ spL, int B)
{
    __shared__ u16 AhS[8*64*8];
    __shared__ u16 AlS[8*64*8];
    int col0 = blockIdx.x * 64;
    int y0   = blockIdx.y * 128;
    int plane = blockIdx.z;
    int tid = threadIdx.x;
    int wave = tid >> 6, lane = tid & 63;
    int lm = lane & 15, lq = lane >> 4;
    f32x4 acc[2][4];
#pragma unroll
    for (int mi = 0; mi < 2; ++mi)
#pragma unroll
        for (int nj = 0; nj < 4; ++nj) acc[mi][nj] = (f32x4){0.f,0.f,0.f,0.f};
    for (int kt = 0; kt < 416; kt += 32) {
#pragma unroll
        for (int s = 0; s < 4; ++s) {
            int slot = tid + s*256;
            int r = slot >> 3, kq = slot & 7;
            size_t rowb = ((size_t)(y0 + r)*B + plane)*KF;
            int k0 = (kt + kq*4) >> 1;
            uint2 u0, u1;
            u0.x = u0.y = u1.x = u1.y = 0u;
            if (k0 < KF)     u0 = Ain[rowb + k0];
            if (k0 + 1 < KF) u1 = Ain[rowb + k0 + 1];
            int base = ((r >> 4)*64 + (r & 15) + 16*(kq >> 1))*8 + (kq & 1)*4;
            uint2 hp, lp;
            hp.x = u0.x; hp.y = u1.x;
            lp.x = u0.y; lp.y = u1.y;
            *(uint2*)&AhS[base] = hp;
            *(uint2*)&AlS[base] = lp;
        }
        __syncthreads();
        short8 Ah[2], Al[2];
#pragma unroll
        for (int mi = 0; mi < 2; ++mi) {
            Ah[mi] = *(const short8*)&AhS[((wave*2 + mi)*64 + lane)*8];
            Al[mi] = *(const short8*)&AlS[((wave*2 + mi)*64 + lane)*8];
        }
#pragma unroll
        for (int nj = 0; nj < 4; ++nj) {
            size_t toff = (size_t)(col0 + nj*16 + lm)*416 + kt + lq*8;
            short8 Bh = *(const short8*)(UtH + toff);
            short8 Bl = *(const short8*)(UtL + toff);
#pragma unroll
            for (int mi = 0; mi < 2; ++mi) {
                acc[mi][nj] = __builtin_amdgcn_mfma_f32_16x16x32_bf16(Ah[mi], Bh, acc[mi][nj], 0, 0, 0);
                acc[mi][nj] = __builtin_amdgcn_mfma_f32_16x16x32_bf16(Ah[mi], Bl, acc[mi][nj], 0, 0, 0);
                acc[mi][nj] = __builtin_amdgcn_mfma_f32_16x16x32_bf16(Al[mi], Bh, acc[mi][nj], 0, 0, 0);
            }
        }
        __syncthreads();
    }
    float bthr = thr ? thr[plane & 15] : 0.f;
#pragma unroll
    for (int mi = 0; mi < 2; ++mi) {
#pragma unroll
        for (int nj = 0; nj < 4; ++nj) {
            int x = col0 + nj*16 + lm;
#pragma unroll
            for (int rr = 0; rr < 4; ++rr) {
                int y = y0 + wave*32 + mi*16 + lq*4 + rr;
                float v = acc[mi][nj][rr];
                outp[((size_t)plane*FH + y)*FH + x] = v;
                if (spH) {
                    float sv = softt(v, bthr);
                    u16 h = bf16_rn(sv);
                    size_t d = (size_t)plane*SPW + (size_t)y*FH + x;
                    spH[d] = h;
                    spL[d] = bf16_rn(sv - bf16_to_f(h));
                }
            }
        }
    }
}

// ---------------- MFMA col pass: C = E·B (complex), stacked-real bf16x3 ----------------
__global__ __launch_bounds__(256) void zgemm_col_mfma(
    const u16* __restrict__ EH, const u16* __restrict__ EL,
    const uint2* __restrict__ Bm, uint2* __restrict__ Cm, int N)
{
    __shared__ u16 BhS[4*64*8];
    __shared__ u16 BlS[4*64*8];
    int col0 = blockIdx.x * 64;
    int row0 = blockIdx.y * 128;
    int tid = threadIdx.x;
    int wave = tid >> 6, lane = tid & 63;
    int lm = lane & 15, lq = lane >> 4;
    f32x4 acc[2][4];
#pragma unroll
    for (int mi = 0; mi < 2; ++mi)
#pragma unroll
        for (int nj = 0; nj < 4; ++nj) acc[mi][nj] = (f32x4){0.f,0.f,0.f,0.f};
    int arow0 = row0 + wave*32 + lm;
    for (int kt = 0; kt < KP; kt += 32) {
        int tbase = kt >> 1;
#pragma unroll
        for (int s = 0; s < 2; ++s) {
            int slot = tid + s*256;
            int pair = slot >> 6;
            int n    = slot & 63;
            int gn   = col0 + n;
            int t0   = tbase + pair*2;
            uint2 u0, u1;
            u0.x = u0.y = u1.x = u1.y = 0u;
            if (gn < N) {
                u0 = Bm[(size_t)t0*N + gn];
                u1 = Bm[(size_t)(t0+1)*N + gn];
            }
            int ntile = n >> 4, n0 = n & 15;
            int lrow  = (pair >> 1)*16 + n0;
            int base  = (ntile*64 + lrow)*8 + (pair & 1)*4;
            uint2 hp, lp;
            hp.x = u0.x; hp.y = u1.x;
            lp.x = u0.y; lp.y = u1.y;
            *(uint2*)&BhS[base] = hp;
            *(uint2*)&BlS[base] = lp;
        }
        __syncthreads();
        short8 Ah[2], Al[2];
#pragma unroll
        for (int mi = 0; mi < 2; ++mi) {
            size_t aoff = (size_t)(arow0 + mi*16)*KP + kt + lq*8;
            Ah[mi] = *(const short8*)(EH + aoff);
            Al[mi] = *(const short8*)(EL + aoff);
        }
#pragma unroll
        for (int nj = 0; nj < 4; ++nj) {
            short8 Bh = *(const short8*)&BhS[(nj*64 + lane)*8];
            short8 Bl = *(const short8*)&BlS[(nj*64 + lane)*8];
#pragma unroll
            for (int mi = 0; mi < 2; ++mi) {
                acc[mi][nj] = __builtin_amdgcn_mfma_f32_16x16x32_bf16(Ah[mi], Bh, acc[mi][nj], 0, 0, 0);
                acc[mi][nj] = __builtin_amdgcn_mfma_f32_16x16x32_bf16(Ah[mi], Bl, acc[mi][nj], 0, 0, 0);
                acc[mi][nj] = __builtin_amdgcn_mfma_f32_16x16x32_bf16(Al[mi], Bh, acc[mi][nj], 0, 0, 0);
            }
        }
        __syncthreads();
    }
#pragma unroll
    for (int mi = 0; mi < 2; ++mi) {
#pragma unroll
        for (int nj = 0; nj < 4; ++nj) {
            int coln = col0 + nj*16 + lm;
            if (coln < N) {
                int r0 = row0 + wave*32 + mi*16 + lq*4;
                int h0 = r0 >> 1;
                Cm[(size_t)h0*N + coln]       = packc(acc[mi][nj][0], acc[mi][nj][1]);
                Cm[(size_t)(h0+1)*N + coln]   = packc(acc[mi][nj][2], acc[mi][nj][3]);
            }
        }
    }
}

// ---------------- elementwise frequency-domain updates (uint2 spectra) ----------------
__global__ void fg_kernel(const uint2* __restrict__ Ffy, uint2* __restrict__ Fz,
                          const uint2* __restrict__ Fk, const float* __restrict__ zetas,
                          int L, int total)
{
    int idx = blockIdx.x*256 + threadIdx.x;
    if (idx >= total) return;
    int k = idx % KF; int r = idx / KF;
    int c = r & 15; int hi = r >> 4;
    float zeta = 10.f * zetas[L*16 + c];
    float2 fk = ldc(Fk, (size_t)hi*KF + k);
    float2 fy = ldc(Ffy, idx);
    float2 fz = ldc(Fz, idx);
    float nx = zeta*(fk.x*fy.x + fk.y*fy.y) + fz.x;
    float ny = zeta*(fk.x*fy.y - fk.y*fy.x) + fz.y;
    float den = zeta*(fk.x*fk.x + fk.y*fk.y) + 1.f + 1e-8f;
    float inv = 1.f/den;
    Fz[idx] = packc(nx*inv, ny*inv);
}

__global__ void knum_kernel(const uint2* __restrict__ Fz, const uint2* __restrict__ Ffy,
                            const uint2* __restrict__ Fk, const float* __restrict__ kprox,
                            int L, int total, uint2* __restrict__ outk)
{
    int idx = blockIdx.x*256 + threadIdx.x;
    if (idx >= total) return;
    int k = idx % KF; int r = idx / KF;
    float zk = kprox[L];
    float s1x = 0.f, s1y = 0.f, s2 = 0.f;
    for (int c = 0; c < 16; ++c) {
        size_t bi = ((size_t)r*16 + c)*KF + k;
        float2 fz = ldc(Fz, bi), fy = ldc(Ffy, bi);
        s1x += fz.x*fy.x + fz.y*fy.y;
        s1y += fz.x*fy.y - fz.y*fy.x;
        s2  += fz.x*fz.x + fz.y*fz.y;
    }
    float2 fk = ldc(Fk, idx);
    float nx = zk*s1x + fk.x, ny = zk*s1y + fk.y;
    float den = zk*s2 + 1.f + 1e-8f;
    float inv = 1.f/den;
    outk[idx] = packc(nx*inv, ny*inv);
}

// ---------------- kernel (blur-kernel) update ----------------
__device__ __forceinline__ void lse_comb(float& m, float& s, float m2, float s2)
{
    if (m2 > m) { s = s * expf(m - m2) + s2; m = m2; }
    else        { s = s + s2 * expf(m2 - m); }
}

__global__ __launch_bounds__(256) void lse_part_kernel(const float* __restrict__ kraw0,
                                                       float2* __restrict__ parts)
{
    int img = blockIdx.y;
    const float* kraw = kraw0 + (size_t)img*FH*FH;
    int b = blockIdx.x, t = threadIdx.x;
    float m = -1e30f, s = 0.f;
    for (int i = b*256 + t; i < FH*FH; i += 64*256) {
        float v = 100.f * kraw[i];
        lse_comb(m, s, v, 1.f);
    }
    __shared__ float sm[256], ss[256];
    sm[t] = m; ss[t] = s;
    __syncthreads();
    for (int st = 128; st > 0; st >>= 1) {
        if (t < st) {
            float mm = sm[t], sc = ss[t];
            lse_comb(mm, sc, sm[t+st], ss[t+st]);
            sm[t] = mm; ss[t] = sc;
        }
        __syncthreads();
    }
    if (t == 0) { float2 o; o.x = sm[0]; o.y = ss[0]; parts[img*64 + b] = o; }
}

__global__ void lse_final_kernel(const float2* __restrict__ parts, float* __restrict__ kmaxB)
{
    int img = blockIdx.x;
    int t = threadIdx.x;
    __shared__ float sm[64], ss[64];
    float2 p = parts[img*64 + t];
    sm[t] = p.x; ss[t] = p.y;
    __syncthreads();
    for (int st = 32; st > 0; st >>= 1) {
        if (t < st) {
            float mm = sm[t], sc = ss[t];
            lse_comb(mm, sc, sm[t+st], ss[t+st]);
            sm[t] = mm; ss[t] = sc;
        }
        __syncthreads();
    }
    if (t == 0) kmaxB[img] = (sm[0] + logf(ss[0])) * 0.01f;
}

__global__ void zero_kernel(float* __restrict__ p, int n)
{
    int i = blockIdx.x*256 + threadIdx.x;
    if (i < n) p[i] = 0.f;
}

__global__ void kdelta_kernel(float* __restrict__ kful, int G)
{
    int t = threadIdx.x;
    if (t < G) kful[(size_t)t*FH*FH + 22*FH + 22] = 1.f;
}

__global__ __launch_bounds__(256) void knew_kernel(const float* __restrict__ kraw0,
    const float* __restrict__ kmax, const float* __restrict__ kb, int L,
    float* __restrict__ kful0)
{
    int img = blockIdx.x;
    const float* kraw = kraw0 + (size_t)img*FH*FH;
    float*       kful = kful0 + (size_t)img*FH*FH;
    int t = threadIdx.x;
    float thr = 0.01f * kb[L] * kmax[img];
    float vs[8]; float loc = 0.f;
#pragma unroll
    for (int ii = 0; ii < 8; ++ii) {
        int i = t + ii*256;
        float v = 0.f;
        if (i < 45*45) {
            int y = i/45, x = i - y*45;
            v = fmaxf(kraw[y*FH + x] - thr, 0.f);
        }
        vs[ii] = v; loc += v;
    }
    __shared__ float sr[256];
    sr[t] = loc; __syncthreads();
    for (int st = 128; st > 0; st >>= 1) { if (t < st) sr[t] += sr[t+st]; __syncthreads(); }
    float den = sr[0] + 1e-8f;
#pragma unroll
    for (int ii = 0; ii < 8; ++ii) {
        int i = t + ii*256;
        if (i < 45*45) {
            int y = i/45, x = i - y*45;
            float v = vs[ii] + ((y == 22 && x == 22) ? 1e-8f : 0.f);
            kful[y*FH + x] = v / den;
        }
    }
}

// ---------------- Fw0 (direct 9-term DFT of shifted 3x3), image-independent ----------------
__global__ void fw0_kernel(const float* __restrict__ w0c, const float2* __restrict__ Ef,
                           float2* __restrict__ Fw0)
{
    int idx = blockIdx.x*256 + threadIdx.x;
    if (idx >= 48*FH*KF) return;
    int k = idx % KF; int r = idx / KF;
    int c = r & 15; int r2 = r >> 4;
    int ci = r2 % 3; int h = r2 / 3;
    float accx = 0.f, accy = 0.f;
#pragma unroll
    for (int ky = 0; ky < 3; ++ky) {
        int a1 = ky - 1; if (a1 < 0) a1 += FH;
        float2 e1 = Ef[h*FH + a1];
#pragma unroll
        for (int kx = 0; kx < 3; ++kx) {
            int a2 = kx - 1; if (a2 < 0) a2 += FH;
            float2 e2 = Ef[k*FH + a2];
            float wv = w0c[((c*3 + ci)*3 + ky)*3 + kx];
            float tr = e1.x*e2.x - e1.y*e2.y;
            float ti = e1.x*e2.y + e1.y*e2.x;
            accx += wv*tr; accy += wv*ti;
        }
    }
    float2 o; o.x = accx; o.y = accy;
    Fw0[idx] = o;
}

// ---------------- final per-bin 3x3 Hermitian Wiener solve (uint2 spectra) ----------------
__global__ void wiener_kernel(const uint2* __restrict__ Fk, const uint2* __restrict__ Fy,
    const float2* __restrict__ Fw0, const uint2* __restrict__ Fg2,
    const float* __restrict__ eta, int G, int total, uint2* __restrict__ Fx)
{
    int idx = blockIdx.x*256 + threadIdx.x;
    if (idx >= total) return;
    int k = idx % KF; int r = idx / KF;
    int h = r / G;
    float2 fk = ldc(Fk, idx);
    float fksq = fk.x*fk.x + fk.y*fk.y;
    float2 fyr = ldc(Fy, ((size_t)3*r + 0)*KF + k);
    float2 fyg = ldc(Fy, ((size_t)3*r + 1)*KF + k);
    float2 fyb = ldc(Fy, ((size_t)3*r + 2)*KF + k);
    float Crr = fksq, Cgg = fksq, Cbb = fksq;
    float2 Crg, Crb, Cgb;
    Crg.x = Crg.y = Crb.x = Crb.y = Cgb.x = Cgb.y = 0.f;
    float2 Br, Bg, Bb;
    Br.x = fk.x*fyr.x + fk.y*fyr.y; Br.y = fk.x*fyr.y - fk.y*fyr.x;
    Bg.x = fk.x*fyg.x + fk.y*fyg.y; Bg.y = fk.x*fyg.y - fk.y*fyg.x;
    Bb.x = fk.x*fyb.x + fk.y*fyb.y; Bb.y = fk.x*fyb.y - fk.y*fyb.x;
    for (int c = 0; c < 16; ++c) {
        float es = 10.f * eta[c];
        float2 wr = Fw0[((size_t)h*48 +  0 + c)*KF + k];
        float2 wg = Fw0[((size_t)h*48 + 16 + c)*KF + k];
        float2 wb = Fw0[((size_t)h*48 + 32 + c)*KF + k];
        float2 g  = ldc(Fg2, ((size_t)r*16 + c)*KF + k);
        Crr += es*(wr.x*wr.x + wr.y*wr.y);
        Cgg += es*(wg.x*wg.x + wg.y*wg.y);
        Cbb += es*(wb.x*wb.x + wb.y*wb.y);
        Crg.x += es*(wr.x*wg.x + wr.y*wg.y); Crg.y += es*(wr.x*wg.y - wr.y*wg.x);
        Crb.x += es*(wr.x*wb.x + wr.y*wb.y); Crb.y += es*(wr.x*wb.y - wr.y*wb.x);
        Cgb.x += es*(wg.x*wb.x + wg.y*wb.y); Cgb.y += es*(wg.x*wb.y - wg.y*wb.x);
        Br.x += es*(wr.x*g.x + wr.y*g.y); Br.y += es*(wr.x*g.y - wr.y*g.x);
        Bg.x += es*(wg.x*g.x + wg.y*g.y); Bg.y += es*(wg.x*g.y - wg.y*g.x);
        Bb.x += es*(wb.x*g.x + wb.y*g.y); Bb.y += es*(wb.x*g.y - wb.y*g.x);
    }
    float Crg_sq = Crg.x*Crg.x + Crg.y*Crg.y;
    float Crb_sq = Crb.x*Crb.x + Crb.y*Crb.y;
    float Cgb_sq = Cgb.x*Cgb.x + Cgb.y*Cgb.y;
    float Irr = Cgg*Cbb - Cgb_sq;
    float Igg = Crr*Cbb - Crb_sq;
    float Ibb = Crr*Cgg - Crg_sq;
    float2 Irg, Irb, Igb;
    Irg.x = (Cgb.x*Crb.x + Cgb.y*Crb.y) - Cbb*Crg.x;
    Irg.y = (Cgb.x*Crb.y - Cgb.y*Crb.x) - Cbb*Crg.y;
    Irb.x = (Crg.x*Cgb.x - Crg.y*Cgb.y) - Cgg*Crb.x;
    Irb.y = (Crg.x*Cgb.y + Crg.y*Cgb.x) - Cgg*Crb.y;
    Igb.x = (Crg.x*Crb.x + Crg.y*Crb.y) - Crr*Cgb.x;
    Igb.y = (Crg.x*Crb.y - Crg.y*Crb.x) - Crr*Cgb.y;
    float tx_ = Crg.x*Cgb.x - Crg.y*Cgb.y;
    float ty_ = Crg.x*Cgb.y + Crg.y*Cgb.x;
    float den = Crr*Irr - Cgg*Crb_sq - Cbb*Crg_sq + 2.f*(tx_*Crb.x + ty_*Crb.y) + 1e-8f;
    float inv = 1.f/den;
    float ox, oy;
    ox = (Irr*Br.x + (Irg.x*Bg.x - Irg.y*Bg.y) + (Irb.x*Bb.x - Irb.y*Bb.y))*inv;
    oy = (Irr*Br.y + (Irg.x*Bg.y + Irg.y*Bg.x) + (Irb.x*Bb.y + Irb.y*Bb.x))*inv;
    Fx[((size_t)3*r + 0)*KF + k] = packc(ox, oy);
    ox = ((Irg.x*Br.x + Irg.y*Br.y) + Igg*Bg.x + (Igb.x*Bb.x - Igb.y*Bb.y))*inv;
    oy = ((Irg.x*Br.y - Irg.y*Br.x) + Igg*Bg.y + (Igb.x*Bb.y + Igb.y*Bb.x))*inv;
    Fx[((size_t)3*r + 1)*KF + k] = packc(ox, oy);
    ox = ((Irb.x*Br.x + Irb.y*Br.y) + (Igb.x*Bg.x + Igb.y*Bg.y) + Ibb*Bb.x)*inv;
    oy = ((Irb.x*Br.y - Irb.y*Br.x) + (Igb.x*Bg.y - Igb.y*Bg.x) + Ibb*Bb.y)*inv;
    Fx[((size_t)3*r + 2)*KF + k] = packc(ox, oy);
}

// ---------------- output assembly ----------------
__global__ void crop_kernel(const float* __restrict__ sp, float* __restrict__ outp, int total)
{
    int idx = blockIdx.x*256 + threadIdx.x;
    if (idx >= total) return;
    int x = idx & 255; int r = idx >> 8; int y = r & 255; int plane = r >> 8;
    outp[idx] = sp[((size_t)plane*FH + (y+22))*FH + (x+22)];
}

__global__ void kcopy_kernel(const float* __restrict__ kful, float* __restrict__ outp, int total)
{
    int idx = blockIdx.x*256 + threadIdx.x;
    if (idx >= total) return;
    int rem = idx % 2025; int img = idx / 2025;
    int x = rem % 45; int y = rem / 45;
    outp[idx] = kful[(size_t)img*FH*FH + y*FH + x];
}

// =====================================================================
extern "C" void kernel_launch(void* const* d_in, const int* in_sizes, int n_in,
                              void* d_out, int out_size, void* d_ws, size_t ws_size,
                              hipStream_t stream)
{
    (void)in_sizes; (void)n_in; (void)out_size;
    const float* blurred = (const float*)d_in[0];
    const float* w0      = (const float*)d_in[1];
    const float* wsw     = (const float*)d_in[2];
    const float* biases  = (const float*)d_in[3];
    const float* kbias   = (const float*)d_in[4];
    const float* kprox   = (const float*)d_in[5];
    const float* zetas   = (const float*)d_in[6];
    const float* eta     = (const float*)d_in[7];
    float* outp = (float*)d_out;

    auto al = [](size_t b) { return (b + 255) & ~(size_t)255; };
    auto need = [&](int G) -> size_t {
        size_t s = 0;
        s += al((size_t)FH*FH*8);                 // Ef
        s += 4*al((size_t)KP*KP*2);               // EfH/L, EiH/L
        s += 2*al((size_t)448*FH*2);              // Tt
        s += 2*al((size_t)FH*416*2);              // Ut
        s += al(432*4);                           // w0c
        s += 2*al((size_t)10*G*16*65536*2);       // fyH, fyL (split checkpoints)
        s += al((size_t)G*16*FH*FH*4);            // zsp fp32
        s += 2*al((size_t)G*16*SPW*2);            // zspSH, zspSL
        s += 3*al((size_t)G*16*FH*KF*8);          // mid, FzFg, Ffy (uint2)
        s += 3*al((size_t)G*FH*KF*8);             // Fk, kfA, kfB
        s += 2*al((size_t)G*FH*FH*4);             // kraw, kful
        s += 2*al((size_t)G*3*FH*KF*8);           // FyB, FxB
        s += al((size_t)G*64*8) + al(256);        // lseP, kmax
        return s;
    };
    int G = 4;
    while (G > 1 && need(G) > ws_size) G >>= 1;

    char* base = (char*)d_ws;
    size_t off = 0;
    auto alloc = [&](size_t bytes) -> void* {
        void* p = (void*)(base + off);
        off += (bytes + 255) & ~(size_t)255;
        return p;
    };
    float2* Ef   = (float2*)alloc((size_t)FH*FH*8);
    u16* EfH = (u16*)alloc((size_t)KP*KP*2);
    u16* EfL = (u16*)alloc((size_t)KP*KP*2);
    u16* EiH = (u16*)alloc((size_t)KP*KP*2);
    u16* EiL = (u16*)alloc((size_t)KP*KP*2);
    u16* TtH = (u16*)alloc((size_t)448*FH*2);
    u16* TtL = (u16*)alloc((size_t)448*FH*2);
    u16* UtH = (u16*)alloc((size_t)FH*416*2);
    u16* UtL = (u16*)alloc((size_t)FH*416*2);
    float*  w0cB = (float*)alloc(432*4);
    u16*    fyH  = (u16*)alloc((size_t)10*G*16*65536*2);
    u16*    fyL  = (u16*)alloc((size_t)10*G*16*65536*2);
    float*  zsp  = (float*)alloc((size_t)G*16*FH*FH*4);
    u16*    zspSH= (u16*)alloc((size_t)G*16*SPW*2);
    u16*    zspSL= (u16*)alloc((size_t)G*16*SPW*2);
    uint2*  mid  = (uint2*)alloc((size_t)G*16*FH*KF*8);
    uint2*  FzFg = (uint2*)alloc((size_t)G*16*FH*KF*8);
    uint2*  Ffy  = (uint2*)alloc((size_t)G*16*FH*KF*8);
    uint2*  Fk   = (uint2*)alloc((size_t)G*FH*KF*8);
    uint2*  kfA  = (uint2*)alloc((size_t)G*FH*KF*8);
    uint2*  kfB  = (uint2*)alloc((size_t)G*FH*KF*8);
    float*  kraw = (float*)alloc((size_t)G*FH*FH*4);
    float*  kful = (float*)alloc((size_t)G*FH*FH*4);
    uint2*  FyB  = (uint2*)alloc((size_t)G*3*FH*KF*8);
    uint2*  FxB  = (uint2*)alloc((size_t)G*3*FH*KF*8);
    float2* lseP = (float2*)alloc((size_t)G*64*8);
    float*  kmaxB= (float*)alloc(256);
    // Fw0 (28.45 MB) overlays fyH (+ spills into fyL region if G==1) — dead by final stage
    float2* Fw0B = (float2*)fyH;

    // tables + weight prep (image-independent)
    init_ef_k<<<(FH*FH+255)/256, 256, 0, stream>>>(Ef);
    init_estack<<<(KP*KP+255)/256, 256, 0, stream>>>(EfH, EfL, 0);
    init_estack<<<(KP*KP+255)/256, 256, 0, stream>>>(EiH, EiL, 1);
    init_tt<<<(448*FH+255)/256, 256, 0, stream>>>(TtH, TtL);
    init_ut<<<(FH*416+255)/256, 256, 0, stream>>>(UtH, UtL);
    w0c_kernel<<<1, 64, 0, stream>>>(w0, w0cB);

    auto zg = [&](const u16* EH, const u16* EL, const uint2* Bm, uint2* Cm, int Ncols) {
        zgemm_col_mfma<<<dim3((Ncols+63)/64, (2*FH)/128), 256, 0, stream>>>(
            EH, EL, Bm, Cm, Ncols);
    };
    auto r2c = [&](const float* inp, int inH, int inW, int oY, int oX,
                   const float* thr, uint2* o, int B) {
        r2c_row_mfma<<<dim3(7, 3, B), 256, 0, stream>>>(
            inp, inH, inW, oY, oX, thr, TtH, TtL, o, B);
    };
    auto r2cs = [&](const u16* Hs, const u16* Ls, int inH, int inW, int oY, int oX,
                    uint2* o, int B) {
        r2c_row_mfma_s<<<dim3(7, 3, B), 256, 0, stream>>>(
            Hs, Ls, inH, inW, oY, oX, TtH, TtL, o, B);
    };
    auto c2r = [&](const uint2* Ain, float* o, int B,
                   const float* thr, u16* sH, u16* sL) {
        c2r_row_mfma<<<dim3(6, 3, B), 256, 0, stream>>>(
            Ain, UtH, UtL, o, thr, sH, sL, B);
    };

    const size_t CKL = (size_t)G*16*65536;   // one split ck layer (u16 elements)

    for (int g0 = 0; g0 < 4; g0 += G) {
        const float* img = blurred + (size_t)g0*3*65536;

        // forward conv chain: split checkpoints, reconstruct hi+lo as input
        conv3x3_kernel<<<dim3(16,16,G), 256, 0, stream>>>(
            img, nullptr, nullptr, w0cB, fyH, fyL, 3, 1, (size_t)3*65536);
        for (int l = 1; l < 10; ++l)
            conv3x3_kernel<<<dim3(16,16,G), 256, 0, stream>>>(
                nullptr, fyH + (size_t)(l-1)*CKL, fyL + (size_t)(l-1)*CKL,
                wsw + (size_t)(l-1)*2304,
                fyH + (size_t)l*CKL, fyL + (size_t)l*CKL, 16, 0, (size_t)16*65536);

        // z init (circshift + threshold b0), Fz
        int totZ = G*16*FH*FH;
        zinit_kernel<<<(totZ+255)/256, 256, 0, stream>>>(
            fyH + 9*CKL, fyL + 9*CKL, biases, zsp, totZ);
        r2c(zsp, FH, FH, 0, 0, nullptr, mid, G*16);
        zg(EfH, EfL, mid, FzFg, G*16*KF);

        // k init = delta
        zero_kernel<<<(G*FH*FH+255)/256, 256, 0, stream>>>(kful, G*FH*FH);
        kdelta_kernel<<<1, 64, 0, stream>>>(kful, G);

        int totS = G*16*FH*KF;
        int totK = G*FH*KF;
        for (int it = 0; it < 10; ++it) {
            int Lfy = 9 - it;
            r2cs(fyH + (size_t)Lfy*CKL, fyL + (size_t)Lfy*CKL, 256, 256, 44, 44, mid, G*16);
            zg(EfH, EfL, mid, Ffy, G*16*KF);
            r2c(kful, FH, FH, 0, 0, nullptr, mid, G);
            zg(EfH, EfL, mid, Fk, G*KF);
            fg_kernel<<<(totS+255)/256, 256, 0, stream>>>(Ffy, FzFg, Fk, zetas, it, totS);
            zg(EiH, EiL, FzFg, mid, G*16*KF);
            // zsp = irfft(Fg) PRE-threshold; side-output = softt-split for next r2c
            c2r(mid, zsp, G*16, biases + (it+1)*16, zspSH, zspSL);
            r2cs(zspSH, zspSL, FH, FH, 0, 0, mid, G*16);   // pre-split, no conversions
            zg(EfH, EfL, mid, FzFg, G*16*KF);              // Fz_new
            knum_kernel<<<(totK+255)/256, 256, 0, stream>>>(FzFg, Ffy, Fk, kprox, it, totK, kfA);
            zg(EiH, EiL, kfA, kfB, G*KF);
            c2r(kfB, kraw, G, nullptr, nullptr, nullptr);
            lse_part_kernel<<<dim3(64,G), 256, 0, stream>>>(kraw, lseP);
            lse_final_kernel<<<G, 64, 0, stream>>>(lseP, kmaxB);
            knew_kernel<<<G, 256, 0, stream>>>(kraw, kmaxB, kbias, it, kful);
        }

        // ---- final stage (fyH/fyL dead; Fw0 overlay live) ----
        r2c(img, 256, 256, 44, 44, nullptr, mid, 3*G);
        zg(EfH, EfL, mid, FyB, 3*G*KF);
        r2c(kful, FH, FH, 0, 0, nullptr, mid, G);
        zg(EfH, EfL, mid, Fk, G*KF);
        // Fg2 = rfft(softt(zsp, b_final)) — from fp32 zsp with fused threshold
        r2c(zsp, FH, FH, 0, 0, biases + 11*16, mid, G*16);
        zg(EfH, EfL, mid, FzFg, G*16*KF);
        fw0_kernel<<<(48*FH*KF+255)/256, 256, 0, stream>>>(w0cB, Ef, Fw0B);
        wiener_kernel<<<(totK+255)/256, 256, 0, stream>>>(Fk, FyB, Fw0B, FzFg, eta, G, totK, FxB);
        zg(EiH, EiL, FxB, mid, 3*G*KF);
        c2r(mid, zsp, 3*G, nullptr, nullptr, nullptr);
        int totC = G*3*65536;
        crop_kernel<<<(totC+255)/256, 256, 0, stream>>>(zsp, outp + (size_t)g0*3*65536, totC);
        int totKC = G*2025;
        kcopy_kernel<<<(totKC+255)/256, 256, 0, stream>>>(kful, outp + 786432 + g0*2025, totKC);
    }
}